// Round 7
// baseline (2768.306 us; speedup 1.0000x reference)
//
#include <hip/hip_runtime.h>
#include <math.h>

// MetalWallQEQ: reciprocal-space Ewald QEQ for metal-wall charges.
// Round 7: NIT back to 150 (round 6 showed 100 iters -> absmax 0.109, k≈2500);
// projected single-RHS CG kept. A-build: 128x128 tiles, 8x8 acc/thread
// (2x arithmetic intensity), 16-k LDS chunks, fully co-resident grid.

#define NA 4096
#define NM 2048
#define METAL_Z 79
#define KH 7812          // (25^3-1)/2 half k-points
#define KHP 7936         // padded to 62*128 (pad entries have w=0)
#define KQ8 (KHP/8)      // 992 k per abuild K-slice
#define NIT 150          // fixed CG iterations (graph-friendly)
#define NBLK_CG 256      // persistent CG grid: 1 block/CU, co-resident
#define TWO_PI 6.283185307179586f

// ---- workspace byte offsets (total ~17.7 MB) ----
#define OFF_CONSTS 0        // [0..8]=invT(cell) row-major, [9]=pref=4pi/V, [10]=J
#define OFF_SUMS   256      // scratch
#define OFF_FLAGS  512      // 256 ints: CG barrier flags (zeroed per call)
#define OFF_KTAB   4096     // KHP * {gx,gy,gz,w} floats
#define OFF_FRAC   131072   // NA * {fx,fy,fz,0} fractional coords
#define OFF_MLIST  196608   // NM ints: metal position -> atom index
#define OFF_POSOF  204800   // NA ints: atom -> metal position (metal only)
#define OFF_SRW    221184   // KHP floats: w*Re S(k)
#define OFF_SIW    252928   // KHP floats: w*Im S(k)
#define OFF_BPART  284672   // 62*NM floats: field partials
#define OFF_B      792576   // NM floats (unused scratch)
#define OFF_VEC    800768   // x (2048), pad, r (at +4096)
#define OFF_WBUF   833536   // [parity][NM] w exchange (16KB)
#define OFF_PBUF   849920   // [parity][512 gd | 512 mu] partials (8KB)
#define OFF_A      917504   // NM*NM floats (A + J on diagonal)

__device__ __forceinline__ void sc_frac(float u, float& s, float& c) {
    // u is phase in REVOLUTIONS; v_sin/v_cos take revolutions directly.
    float t = u - floorf(u);
    s = __builtin_amdgcn_sinf(t);
    c = __builtin_amdgcn_cosf(t);
}

__device__ __forceinline__ float2 ld_f2_agent(const float* p) {
    unsigned long long v = __hip_atomic_load((unsigned long long*)p,
        __ATOMIC_RELAXED, __HIP_MEMORY_SCOPE_AGENT);
    union { unsigned long long u; float2 f; } cv; cv.u = v; return cv.f;
}
__device__ __forceinline__ void st_f2_agent(float* p, float a, float b) {
    union { unsigned long long u; float2 f; } cv; cv.f = make_float2(a, b);
    __hip_atomic_store((unsigned long long*)p, cv.u,
        __ATOMIC_RELAXED, __HIP_MEMORY_SCOPE_AGENT);
}

// -------- setup: cell inverse, fractional coords, metal scan, zero flags --------
__global__ void k_setup(const float* __restrict__ pos, const float* __restrict__ cell,
                        const float* __restrict__ Jraw, const int* __restrict__ an,
                        float* __restrict__ wsf) {
    int tid = threadIdx.x;
    __shared__ float sM[9];
    __shared__ int sc[256];
    if (tid == 0) {
        float c00=cell[0],c01=cell[1],c02=cell[2];
        float c10=cell[3],c11=cell[4],c12=cell[5];
        float c20=cell[6],c21=cell[7],c22=cell[8];
        float det = c00*(c11*c22-c12*c21) - c01*(c10*c22-c12*c20) + c02*(c10*c21-c11*c20);
        float i00 =  (c11*c22 - c12*c21)/det;
        float i01 = -(c01*c22 - c02*c21)/det;
        float i02 =  (c01*c12 - c02*c11)/det;
        float i10 = -(c10*c22 - c12*c20)/det;
        float i11 =  (c00*c22 - c02*c20)/det;
        float i12 = -(c00*c12 - c02*c10)/det;
        float i20 =  (c10*c21 - c11*c20)/det;
        float i21 = -(c00*c21 - c01*c20)/det;
        float i22 =  (c00*c11 - c01*c10)/det;
        sM[0]=i00; sM[1]=i10; sM[2]=i20;
        sM[3]=i01; sM[4]=i11; sM[5]=i21;
        sM[6]=i02; sM[7]=i12; sM[8]=i22;
        float vol = fabsf(det);
        for (int m=0;m<9;m++) wsf[OFF_CONSTS/4 + m] = sM[m];
        wsf[OFF_CONSTS/4 + 9]  = 12.566370614359172f / vol;   // 4pi/V
        wsf[OFF_CONSTS/4 + 10] = Jraw[0]*Jraw[0];
    }
    __syncthreads();
    float M0=sM[0],M1=sM[1],M2=sM[2],M3=sM[3],M4=sM[4],M5=sM[5],M6=sM[6],M7=sM[7],M8=sM[8];
    for (int i=tid; i<NA; i+=256) {
        float x=pos[3*i], y=pos[3*i+1], z=pos[3*i+2];
        wsf[OFF_FRAC/4 + 4*i+0] = M0*x + M1*y + M2*z;
        wsf[OFF_FRAC/4 + 4*i+1] = M3*x + M4*y + M5*z;
        wsf[OFF_FRAC/4 + 4*i+2] = M6*x + M7*y + M8*z;
        wsf[OFF_FRAC/4 + 4*i+3] = 0.f;
    }
    ((int*)wsf)[OFF_FLAGS/4 + tid] = 0;       // CG barrier flags
    if (tid < 4) wsf[OFF_SUMS/4 + tid] = 0.f;
    // metal prefix scan (deterministic ordering == np.where order)
    int cnt = 0;
    int base_i = tid*16;
    for (int j=0;j<16;j++) cnt += (an[base_i+j]==METAL_Z) ? 1 : 0;
    sc[tid] = cnt; __syncthreads();
    for (int off=1; off<256; off<<=1) {
        int v = (tid>=off) ? sc[tid-off] : 0;
        __syncthreads();
        sc[tid] += v;
        __syncthreads();
    }
    int base = sc[tid] - cnt;
    int* mlist = (int*)wsf + OFF_MLIST/4;
    int* posof = (int*)wsf + OFF_POSOF/4;
    for (int j=0;j<16;j++) {
        int i = base_i + j;
        if (an[i]==METAL_Z) { mlist[base] = i; posof[i] = base; base++; }
    }
}

// -------- zero A, J on diagonal (abuild accumulates with atomicAdd) --------
__global__ void k_azero(float* __restrict__ wsf) {
    float J = wsf[OFF_CONSTS/4 + 10];
    float4* A4 = (float4*)(wsf + OFF_A/4);
    const int n4 = NM*NM/4;
    for (int i = blockIdx.x*256 + threadIdx.x; i < n4; i += gridDim.x*256) {
        float4 v = make_float4(0.f,0.f,0.f,0.f);
        int e = i*4;
        #pragma unroll
        for (int j=0;j<4;j++) if ((e+j) % (NM+1) == 0) ((float*)&v)[j] = J;
        A4[i] = v;
    }
}

// -------- k-table: integer triple + weight w = 2*pref*exp(-k2/2)/k2 --------
__global__ void k_ktab(float* __restrict__ wsf) {
    int k = blockIdx.x*256 + threadIdx.x;
    if (k >= KHP) return;
    float4 out;
    if (k < KH) {
        int gx = k/625 - 12;
        int rem = k%625;
        int gy = rem/25 - 12;
        int gz = rem%25 - 12;
        const float* M = wsf + OFF_CONSTS/4;
        float pref = M[9];
        float kx = TWO_PI*(gx*M[0] + gy*M[3] + gz*M[6]);
        float ky = TWO_PI*(gx*M[1] + gy*M[4] + gz*M[7]);
        float kz = TWO_PI*(gx*M[2] + gy*M[5] + gz*M[8]);
        float k2 = kx*kx + ky*ky + kz*kz;
        float kfac = __expf(-0.5f*k2) / k2;
        out = make_float4((float)gx, (float)gy, (float)gz, 2.f*pref*kfac);
    } else {
        out = make_float4(0.f, 0.f, 0.f, 0.f);
    }
    *(float4*)(wsf + OFF_KTAB/4 + 4*k) = out;
}

// -------- structure factors over electrolyte charges (metal q := 0) --------
__global__ void k_srsi(const float* __restrict__ q, const int* __restrict__ an,
                       float* __restrict__ wsf) {
    int k = blockIdx.x;
    int tid = threadIdx.x;
    float4 kt = *(const float4*)(wsf + OFF_KTAB/4 + 4*k);
    const float* frac = wsf + OFF_FRAC/4;
    float aR=0.f, aI=0.f;
    for (int i=tid; i<NA; i+=256) {
        float qa = (an[i]==METAL_Z) ? 0.f : q[i];
        float4 f = *(const float4*)(frac + 4*i);
        float u = kt.x*f.x + kt.y*f.y + kt.z*f.z;
        float s,c; sc_frac(u, s, c);
        aR += qa*c; aI += qa*s;
    }
    __shared__ float sR[256], sI[256];
    sR[tid]=aR; sI[tid]=aI; __syncthreads();
    for (int off=128; off>0; off>>=1) {
        if (tid<off) { sR[tid]+=sR[tid+off]; sI[tid]+=sI[tid+off]; }
        __syncthreads();
    }
    if (tid==0) {
        wsf[OFF_SRW/4 + k] = kt.w * sR[0];
        wsf[OFF_SIW/4 + k] = kt.w * sI[0];
    }
}

// -------- field at metal atoms (partial over k-chunks) --------
__global__ void k_field(float* __restrict__ wsf) {
    int kc = blockIdx.x;
    int m = blockIdx.y*256 + threadIdx.x;
    int atom = ((const int*)wsf)[OFF_MLIST/4 + m];
    float4 f = *(const float4*)(wsf + OFF_FRAC/4 + 4*atom);
    const float* kt = wsf + OFF_KTAB/4;
    const float* SrW = wsf + OFF_SRW/4;
    const float* SiW = wsf + OFF_SIW/4;
    float acc = 0.f;
    int k0 = kc*128;
    for (int j=0;j<128;j++) {
        int k = k0 + j;
        float4 g = *(const float4*)(kt + 4*k);
        float u = g.x*f.x + g.y*f.y + g.z*f.z;
        float s,c; sc_frac(u, s, c);
        acc = fmaf(c, SrW[k], fmaf(s, SiW[k], acc));
    }
    wsf[OFF_BPART/4 + kc*NM + m] = acc;
}

// -------- r0 = P*B = B - mean(B); B = -field (1 block x 1024) --------
__global__ void k_bfinal(float* __restrict__ wsf) {
    int tid = threadIdx.x;
    float b0 = 0.f, b1 = 0.f;
    for (int kc=0;kc<62;kc++) {
        b0 += wsf[OFF_BPART/4 + kc*NM + tid];
        b1 += wsf[OFF_BPART/4 + kc*NM + 1024 + tid];
    }
    b0 = -b0; b1 = -b1;
    __shared__ float sb[1024];
    sb[tid] = b0 + b1; __syncthreads();
    for (int off=512; off>0; off>>=1) {
        if (tid<off) sb[tid] += sb[tid+off];
        __syncthreads();
    }
    float mean = sb[0] * (1.f/NM);
    float* r = wsf + OFF_VEC/4 + 4096;
    r[tid]        = b0 - mean;
    r[1024 + tid] = b1 - mean;
}

// -------- A build: triangular 128x128 tiles, 8x8 acc/thread, K-split x8 --------
__launch_bounds__(256)
__global__ void k_abuild(float* __restrict__ wsf) {
    __shared__ float cwi[16][128], swi[16][128], cjs[16][128], sjs[16][128];
    __shared__ float4 fi[128], fj[128];
    int tid = threadIdx.x;
    int bid = blockIdx.x;       // 0..135 triangular over 16 row-tiles
    int kq  = blockIdx.y;       // 0..7 K slice
    int bi = (int)((sqrtf(8.f*bid + 1.f) - 1.f)*0.5f);
    while ((bi+1)*(bi+2)/2 <= bid) bi++;
    while (bi*(bi+1)/2 > bid) bi--;
    int bj = bid - bi*(bi+1)/2;

    const int* mlist = (const int*)wsf + OFF_MLIST/4;
    const float* frac = wsf + OFF_FRAC/4;
    const float* ktab = wsf + OFF_KTAB/4;

    if (tid < 128)  fi[tid]     = *(const float4*)(frac + 4*mlist[bi*128 + tid]);
    else            fj[tid-128] = *(const float4*)(frac + 4*mlist[bj*128 + (tid-128)]);
    __syncthreads();

    int col = tid & 127;
    int kkb = tid >> 7;       // 0..1
    float4 fir = fi[col];
    float4 fjr = fj[col];
    int ty = tid >> 4, tx = tid & 15;
    int ty8 = ty*8, tx8 = tx*8;
    float acc[8][8] = {};

    for (int k0=kq*KQ8; k0<(kq+1)*KQ8; k0+=16) {
        #pragma unroll
        for (int it=0; it<8; it++) {
            int kk = kkb + it*2;
            float4 kt = *(const float4*)(ktab + 4*(k0+kk));
            float u = kt.x*fir.x + kt.y*fir.y + kt.z*fir.z;
            float s,c; sc_frac(u, s, c);
            cwi[kk][col] = kt.w*c; swi[kk][col] = kt.w*s;
            u = kt.x*fjr.x + kt.y*fjr.y + kt.z*fjr.z;
            sc_frac(u, s, c);
            cjs[kk][col] = c; sjs[kk][col] = s;
        }
        __syncthreads();
        #pragma unroll 2
        for (int kk=0; kk<16; kk++) {
            float4 a0 = *(const float4*)&cwi[kk][ty8];
            float4 a1 = *(const float4*)&cwi[kk][ty8+4];
            float4 s0 = *(const float4*)&swi[kk][ty8];
            float4 s1 = *(const float4*)&swi[kk][ty8+4];
            float4 b0 = *(const float4*)&cjs[kk][tx8];
            float4 b1 = *(const float4*)&cjs[kk][tx8+4];
            float4 t0 = *(const float4*)&sjs[kk][tx8];
            float4 t1 = *(const float4*)&sjs[kk][tx8+4];
            float aC[8] = {a0.x,a0.y,a0.z,a0.w, a1.x,a1.y,a1.z,a1.w};
            float aS[8] = {s0.x,s0.y,s0.z,s0.w, s1.x,s1.y,s1.z,s1.w};
            float bC[8] = {b0.x,b0.y,b0.z,b0.w, b1.x,b1.y,b1.z,b1.w};
            float bS[8] = {t0.x,t0.y,t0.z,t0.w, t1.x,t1.y,t1.z,t1.w};
            #pragma unroll
            for (int a=0;a<8;a++)
                #pragma unroll
                for (int b=0;b<8;b++)
                    acc[a][b] = fmaf(aC[a], bC[b], fmaf(aS[a], bS[b], acc[a][b]));
        }
        __syncthreads();
    }

    float* A = wsf + OFF_A/4;
    int gi0 = bi*128 + ty8, gj0 = bj*128 + tx8;
    if (bi == bj) {
        #pragma unroll
        for (int a=0;a<8;a++)
            #pragma unroll
            for (int b=0;b<8;b++)
                atomicAdd(&A[(size_t)(gi0+a)*NM + gj0+b], acc[a][b]);
    } else {
        #pragma unroll
        for (int a=0;a<8;a++)
            #pragma unroll
            for (int b=0;b<8;b++) {
                float v = acc[a][b];
                atomicAdd(&A[(size_t)(gi0+a)*NM + gj0+b], v);
                atomicAdd(&A[(size_t)(gj0+b)*NM + gi0+a], v);
            }
    }
}

// -------- persistent projected CG (single RHS, 1 flag barrier/iter) --------
// 256 blocks x 256 threads. Block owns rows [bid*8,bid*8+8) (32 lanes/row) for
// the matvec; thread owns float4 chunks {4t..4t+3, 1024+4t..+3} of the vectors.
// r is replicated in LDS in every block; per-block (gamma,delta,mu) partials
// are published BEFORE the flag so the global dot-reduce overlaps the w-gather.
// Projection P = I - 11^T/n applied via w~ = w - mean(w).
__launch_bounds__(256, 1)
__global__ void k_cg(float* __restrict__ wsf) {
    const float* A = wsf + OFF_A/4;
    float* vec = wsf + OFF_VEC/4;
    float* xg = vec;                       // solution q (metal order)
    const float* rg = vec + 4096;          // initial residual r0 = P*B
    int* flags = (int*)wsf + OFF_FLAGS/4;
    float* wbuf = wsf + OFF_WBUF/4;        // [parity][NM]
    float* pbuf = wsf + OFF_PBUF/4;        // [parity][512 gd | 512 mu]

    __shared__ float rs[NM];
    __shared__ float wrow[8];
    __shared__ float red[12];              // 4 waves x {g,d,mu}

    int tid = threadIdx.x, bid = blockIdx.x;
    int rl = tid >> 5, lane = tid & 31;
    int row = bid*8 + rl;
    const float* Arow = A + (size_t)row*NM;
    int ca = 4*tid;            // own chunk A: elements ca..ca+3
    int cb = 1024 + 4*tid;     // own chunk B

    for (int i=tid; i<NM/4; i+=256)
        ((float4*)rs)[i] = ((const float4*)rg)[i];
    __syncthreads();

    float sa[4]={0,0,0,0}, sb[4]={0,0,0,0};   // own s chunks
    float pr=0.f, xr=0.f;                     // own-row p/x (tid<8)
    float gp=1.f, ap=1.f;

    for (int iter=0; iter<NIT; ++iter) {
        int par = iter & 1;
        float* wb = wbuf + par*NM;
        float* pa = pbuf + par*1024;
        // ---- w_own = A_own * r, 32 lanes per row ----
        float acc=0.f;
        #pragma unroll 8
        for (int c=lane*4; c<NM; c+=128) {
            float4 a = *(const float4*)(Arow + c);
            float4 u = *(const float4*)(rs + c);
            acc += a.x*u.x + a.y*u.y + a.z*u.z + a.w*u.w;
        }
        #pragma unroll
        for (int off=1; off<32; off<<=1) acc += __shfl_xor(acc, off);
        if (lane == 0) {
            wrow[rl] = acc;
            __hip_atomic_store(wb + row, acc, __ATOMIC_RELAXED, __HIP_MEMORY_SCOPE_AGENT);
        }
        float rrow = (tid<8) ? rs[bid*8+tid] : 0.f;   // stable own-row r
        __syncthreads();   // (A) wrow ready; all w stores drained (vmcnt0)
        // ---- pre-barrier block partials (own 8 rows) + flag release ----
        if (tid == 0) {
            float gb=0.f, db=0.f, mb=0.f;
            #pragma unroll
            for (int j=0;j<8;j++) {
                float rv = rs[bid*8+j];
                gb = fmaf(rv,rv,gb); db = fmaf(rv,wrow[j],db); mb += wrow[j];
            }
            st_f2_agent(pa + 2*bid, gb, db);
            st_f2_agent(pa + 512 + 2*bid, mb, 0.f);
            __hip_atomic_store(&flags[bid], iter+1, __ATOMIC_RELEASE, __HIP_MEMORY_SCOPE_AGENT);
        }
        // ---- poll all 256 flags (2 waves, 1 u64 each) ----
        if (tid < 128) {
            unsigned long long* f8 = (unsigned long long*)flags;
            int t = iter+1;
            for (;;) {
                unsigned long long v = __hip_atomic_load(&f8[tid], __ATOMIC_RELAXED, __HIP_MEMORY_SCOPE_AGENT);
                int ok = ((int)(v & 0xffffffffu) >= t) & ((int)(v>>32) >= t);
                if (__all(ok)) break;
                __builtin_amdgcn_s_sleep(1);
            }
        }
        __syncthreads();   // (B)
        // ---- overlap: gather own w chunks || load+reduce 256 partials ----
        float2 wa0 = ld_f2_agent(wb + ca), wa1 = ld_f2_agent(wb + ca + 2);
        float2 wb0 = ld_f2_agent(wb + cb), wb1 = ld_f2_agent(wb + cb + 2);
        float2 gd  = ld_f2_agent(pa + 2*tid);
        float2 mu2 = ld_f2_agent(pa + 512 + 2*tid);
        float g = gd.x, d = gd.y, m = mu2.x;
        #pragma unroll
        for (int off=1; off<64; off<<=1) {
            g += __shfl_xor(g,off); d += __shfl_xor(d,off); m += __shfl_xor(m,off);
        }
        if ((tid&63)==0) { int w=tid>>6; red[w*3+0]=g; red[w*3+1]=d; red[w*3+2]=m; }
        __syncthreads();   // (C)
        g = red[0]+red[3]+red[6]+red[9];
        d = red[1]+red[4]+red[7]+red[10];
        m = (red[2]+red[5]+red[8]+red[11]) * (1.f/NM);   // mean(w)
        // ---- identical scalar recurrences everywhere ----
        float b, a;
        if (iter == 0) { b=0.f; a=g/d; }
        else { b = g/gp; a = g/(d - b*g/ap); }
        gp=g; ap=a;
        // ---- p/x for own rows ----
        if (tid < 8) {
            pr = (iter==0) ? rrow : fmaf(b, pr, rrow);
            xr = (iter==0) ? a*pr : fmaf(a, pr, xr);
        }
        // ---- s and r chunk updates (w~ = w - m), write rs b128 ----
        float wv[8] = {wa0.x,wa0.y,wa1.x,wa1.y, wb0.x,wb0.y,wb1.x,wb1.y};
        float4 r4a = *(const float4*)(rs + ca);
        float4 r4b = *(const float4*)(rs + cb);
        float rr[8] = {r4a.x,r4a.y,r4a.z,r4a.w, r4b.x,r4b.y,r4b.z,r4b.w};
        float nr[8];
        #pragma unroll
        for (int j=0;j<4;j++) {
            float wt = wv[j] - m;
            float sv = (iter==0) ? wt : fmaf(b, sa[j], wt);
            sa[j]=sv; nr[j] = fmaf(-a, sv, rr[j]);
        }
        #pragma unroll
        for (int j=0;j<4;j++) {
            float wt = wv[4+j] - m;
            float sv = (iter==0) ? wt : fmaf(b, sb[j], wt);
            sb[j]=sv; nr[4+j] = fmaf(-a, sv, rr[4+j]);
        }
        *(float4*)(rs + ca) = make_float4(nr[0],nr[1],nr[2],nr[3]);
        *(float4*)(rs + cb) = make_float4(nr[4],nr[5],nr[6],nr[7]);
        __syncthreads();   // (D)
    }
    if (tid < 8) xg[bid*8+tid] = xr;
}

// -------- assemble output: metal -> x, electrolyte -> q --------
__global__ void k_out(const float* __restrict__ q, const int* __restrict__ an,
                      const float* __restrict__ wsf, float* __restrict__ out) {
    int i = blockIdx.x*256 + threadIdx.x;
    if (i >= NA) return;
    if (an[i]==METAL_Z) {
        int p = ((const int*)wsf)[OFF_POSOF/4 + i];
        out[i] = wsf[OFF_VEC/4 + p];
    } else {
        out[i] = q[i];
    }
}

extern "C" void kernel_launch(void* const* d_in, const int* in_sizes, int n_in,
                              void* d_out, int out_size, void* d_ws, size_t ws_size,
                              hipStream_t stream) {
    (void)in_sizes; (void)n_in; (void)out_size; (void)ws_size;
    const float* pos  = (const float*)d_in[0];
    const float* cell = (const float*)d_in[1];
    const float* q    = (const float*)d_in[2];
    const float* Jraw = (const float*)d_in[3];
    const int*   an   = (const int*)d_in[4];
    float* wsf = (float*)d_ws;
    float* out = (float*)d_out;

    k_setup<<<1, 256, 0, stream>>>(pos, cell, Jraw, an, wsf);
    k_azero<<<1024, 256, 0, stream>>>(wsf);
    k_ktab<<<KHP/256, 256, 0, stream>>>(wsf);
    k_srsi<<<KHP, 256, 0, stream>>>(q, an, wsf);
    k_field<<<dim3(62, 8), 256, 0, stream>>>(wsf);
    k_bfinal<<<1, 1024, 0, stream>>>(wsf);
    k_abuild<<<dim3(136, 8), 256, 0, stream>>>(wsf);
    k_cg<<<NBLK_CG, 256, 0, stream>>>(wsf);
    k_out<<<NA/256, 256, 0, stream>>>(q, an, wsf, out);
}

// Round 8
// 2756.912 us; speedup vs baseline: 1.0041x; 1.0041x over previous
//
#include <hip/hip_runtime.h>
#include <math.h>

// MetalWallQEQ: reciprocal-space Ewald QEQ for metal-wall charges.
// Round 8: abuild back to triangular 64x64 full-K tiles with PLAIN stores
// (round 7 showed K-split atomicAdd = 1.07GB RMW traffic = atomic-fabric-bound
// at 740GB/s). Native v_sin/v_cos kept. k_azero dropped. CG unchanged.

#define NA 4096
#define NM 2048
#define METAL_Z 79
#define KH 7812          // (25^3-1)/2 half k-points
#define KHP 7936         // padded to 62*128 (pad entries have w=0)
#define NIT 150          // fixed CG iterations (graph-friendly)
#define NBLK_CG 256      // persistent CG grid: 1 block/CU, co-resident
#define TWO_PI 6.283185307179586f

// ---- workspace byte offsets (total ~17.7 MB) ----
#define OFF_CONSTS 0        // [0..8]=invT(cell) row-major, [9]=pref=4pi/V, [10]=J
#define OFF_SUMS   256      // scratch
#define OFF_FLAGS  512      // 256 ints: CG barrier flags (zeroed per call)
#define OFF_KTAB   4096     // KHP * {gx,gy,gz,w} floats
#define OFF_FRAC   131072   // NA * {fx,fy,fz,0} fractional coords
#define OFF_MLIST  196608   // NM ints: metal position -> atom index
#define OFF_POSOF  204800   // NA ints: atom -> metal position (metal only)
#define OFF_SRW    221184   // KHP floats: w*Re S(k)
#define OFF_SIW    252928   // KHP floats: w*Im S(k)
#define OFF_BPART  284672   // 62*NM floats: field partials
#define OFF_B      792576   // NM floats (unused scratch)
#define OFF_VEC    800768   // x (2048), pad, r (at +4096)
#define OFF_WBUF   833536   // [parity][NM] w exchange (16KB)
#define OFF_PBUF   849920   // [parity][512 gd | 512 mu] partials (8KB)
#define OFF_A      917504   // NM*NM floats (A + J on diagonal)

__device__ __forceinline__ void sc_frac(float u, float& s, float& c) {
    // u is phase in REVOLUTIONS; v_sin/v_cos take revolutions directly.
    float t = u - floorf(u);
    s = __builtin_amdgcn_sinf(t);
    c = __builtin_amdgcn_cosf(t);
}

__device__ __forceinline__ float2 ld_f2_agent(const float* p) {
    unsigned long long v = __hip_atomic_load((unsigned long long*)p,
        __ATOMIC_RELAXED, __HIP_MEMORY_SCOPE_AGENT);
    union { unsigned long long u; float2 f; } cv; cv.u = v; return cv.f;
}
__device__ __forceinline__ void st_f2_agent(float* p, float a, float b) {
    union { unsigned long long u; float2 f; } cv; cv.f = make_float2(a, b);
    __hip_atomic_store((unsigned long long*)p, cv.u,
        __ATOMIC_RELAXED, __HIP_MEMORY_SCOPE_AGENT);
}

// -------- setup: cell inverse, fractional coords, metal scan, zero flags --------
__global__ void k_setup(const float* __restrict__ pos, const float* __restrict__ cell,
                        const float* __restrict__ Jraw, const int* __restrict__ an,
                        float* __restrict__ wsf) {
    int tid = threadIdx.x;
    __shared__ float sM[9];
    __shared__ int sc[256];
    if (tid == 0) {
        float c00=cell[0],c01=cell[1],c02=cell[2];
        float c10=cell[3],c11=cell[4],c12=cell[5];
        float c20=cell[6],c21=cell[7],c22=cell[8];
        float det = c00*(c11*c22-c12*c21) - c01*(c10*c22-c12*c20) + c02*(c10*c21-c11*c20);
        float i00 =  (c11*c22 - c12*c21)/det;
        float i01 = -(c01*c22 - c02*c21)/det;
        float i02 =  (c01*c12 - c02*c11)/det;
        float i10 = -(c10*c22 - c12*c20)/det;
        float i11 =  (c00*c22 - c02*c20)/det;
        float i12 = -(c00*c12 - c02*c10)/det;
        float i20 =  (c10*c21 - c11*c20)/det;
        float i21 = -(c00*c21 - c01*c20)/det;
        float i22 =  (c00*c11 - c01*c10)/det;
        sM[0]=i00; sM[1]=i10; sM[2]=i20;
        sM[3]=i01; sM[4]=i11; sM[5]=i21;
        sM[6]=i02; sM[7]=i12; sM[8]=i22;
        float vol = fabsf(det);
        for (int m=0;m<9;m++) wsf[OFF_CONSTS/4 + m] = sM[m];
        wsf[OFF_CONSTS/4 + 9]  = 12.566370614359172f / vol;   // 4pi/V
        wsf[OFF_CONSTS/4 + 10] = Jraw[0]*Jraw[0];
    }
    __syncthreads();
    float M0=sM[0],M1=sM[1],M2=sM[2],M3=sM[3],M4=sM[4],M5=sM[5],M6=sM[6],M7=sM[7],M8=sM[8];
    for (int i=tid; i<NA; i+=256) {
        float x=pos[3*i], y=pos[3*i+1], z=pos[3*i+2];
        wsf[OFF_FRAC/4 + 4*i+0] = M0*x + M1*y + M2*z;
        wsf[OFF_FRAC/4 + 4*i+1] = M3*x + M4*y + M5*z;
        wsf[OFF_FRAC/4 + 4*i+2] = M6*x + M7*y + M8*z;
        wsf[OFF_FRAC/4 + 4*i+3] = 0.f;
    }
    ((int*)wsf)[OFF_FLAGS/4 + tid] = 0;       // CG barrier flags
    if (tid < 4) wsf[OFF_SUMS/4 + tid] = 0.f;
    // metal prefix scan (deterministic ordering == np.where order)
    int cnt = 0;
    int base_i = tid*16;
    for (int j=0;j<16;j++) cnt += (an[base_i+j]==METAL_Z) ? 1 : 0;
    sc[tid] = cnt; __syncthreads();
    for (int off=1; off<256; off<<=1) {
        int v = (tid>=off) ? sc[tid-off] : 0;
        __syncthreads();
        sc[tid] += v;
        __syncthreads();
    }
    int base = sc[tid] - cnt;
    int* mlist = (int*)wsf + OFF_MLIST/4;
    int* posof = (int*)wsf + OFF_POSOF/4;
    for (int j=0;j<16;j++) {
        int i = base_i + j;
        if (an[i]==METAL_Z) { mlist[base] = i; posof[i] = base; base++; }
    }
}

// -------- k-table: integer triple + weight w = 2*pref*exp(-k2/2)/k2 --------
__global__ void k_ktab(float* __restrict__ wsf) {
    int k = blockIdx.x*256 + threadIdx.x;
    if (k >= KHP) return;
    float4 out;
    if (k < KH) {
        int gx = k/625 - 12;
        int rem = k%625;
        int gy = rem/25 - 12;
        int gz = rem%25 - 12;
        const float* M = wsf + OFF_CONSTS/4;
        float pref = M[9];
        float kx = TWO_PI*(gx*M[0] + gy*M[3] + gz*M[6]);
        float ky = TWO_PI*(gx*M[1] + gy*M[4] + gz*M[7]);
        float kz = TWO_PI*(gx*M[2] + gy*M[5] + gz*M[8]);
        float k2 = kx*kx + ky*ky + kz*kz;
        float kfac = __expf(-0.5f*k2) / k2;
        out = make_float4((float)gx, (float)gy, (float)gz, 2.f*pref*kfac);
    } else {
        out = make_float4(0.f, 0.f, 0.f, 0.f);
    }
    *(float4*)(wsf + OFF_KTAB/4 + 4*k) = out;
}

// -------- structure factors over electrolyte charges (metal q := 0) --------
__global__ void k_srsi(const float* __restrict__ q, const int* __restrict__ an,
                       float* __restrict__ wsf) {
    int k = blockIdx.x;
    int tid = threadIdx.x;
    float4 kt = *(const float4*)(wsf + OFF_KTAB/4 + 4*k);
    const float* frac = wsf + OFF_FRAC/4;
    float aR=0.f, aI=0.f;
    for (int i=tid; i<NA; i+=256) {
        float qa = (an[i]==METAL_Z) ? 0.f : q[i];
        float4 f = *(const float4*)(frac + 4*i);
        float u = kt.x*f.x + kt.y*f.y + kt.z*f.z;
        float s,c; sc_frac(u, s, c);
        aR += qa*c; aI += qa*s;
    }
    __shared__ float sR[256], sI[256];
    sR[tid]=aR; sI[tid]=aI; __syncthreads();
    for (int off=128; off>0; off>>=1) {
        if (tid<off) { sR[tid]+=sR[tid+off]; sI[tid]+=sI[tid+off]; }
        __syncthreads();
    }
    if (tid==0) {
        wsf[OFF_SRW/4 + k] = kt.w * sR[0];
        wsf[OFF_SIW/4 + k] = kt.w * sI[0];
    }
}

// -------- field at metal atoms (partial over k-chunks) --------
__global__ void k_field(float* __restrict__ wsf) {
    int kc = blockIdx.x;
    int m = blockIdx.y*256 + threadIdx.x;
    int atom = ((const int*)wsf)[OFF_MLIST/4 + m];
    float4 f = *(const float4*)(wsf + OFF_FRAC/4 + 4*atom);
    const float* kt = wsf + OFF_KTAB/4;
    const float* SrW = wsf + OFF_SRW/4;
    const float* SiW = wsf + OFF_SIW/4;
    float acc = 0.f;
    int k0 = kc*128;
    for (int j=0;j<128;j++) {
        int k = k0 + j;
        float4 g = *(const float4*)(kt + 4*k);
        float u = g.x*f.x + g.y*f.y + g.z*f.z;
        float s,c; sc_frac(u, s, c);
        acc = fmaf(c, SrW[k], fmaf(s, SiW[k], acc));
    }
    wsf[OFF_BPART/4 + kc*NM + m] = acc;
}

// -------- r0 = P*B = B - mean(B); B = -field (1 block x 1024) --------
__global__ void k_bfinal(float* __restrict__ wsf) {
    int tid = threadIdx.x;
    float b0 = 0.f, b1 = 0.f;
    for (int kc=0;kc<62;kc++) {
        b0 += wsf[OFF_BPART/4 + kc*NM + tid];
        b1 += wsf[OFF_BPART/4 + kc*NM + 1024 + tid];
    }
    b0 = -b0; b1 = -b1;
    __shared__ float sb[1024];
    sb[tid] = b0 + b1; __syncthreads();
    for (int off=512; off>0; off>>=1) {
        if (tid<off) sb[tid] += sb[tid+off];
        __syncthreads();
    }
    float mean = sb[0] * (1.f/NM);
    float* r = wsf + OFF_VEC/4 + 4096;
    r[tid]        = b0 - mean;
    r[1024 + tid] = b1 - mean;
}

// -------- A build: triangular 64x64 tiles, FULL K per block, plain stores --------
__launch_bounds__(256)
__global__ void k_abuild(float* __restrict__ wsf) {
    __shared__ float cwi[32][64], swi[32][64], cjs[32][64], sjs[32][64];
    __shared__ float4 fi[64], fj[64];
    int tid = threadIdx.x;
    int bid = blockIdx.x;
    int bi = (int)((sqrtf(8.f*bid + 1.f) - 1.f)*0.5f);
    while ((bi+1)*(bi+2)/2 <= bid) bi++;
    while (bi*(bi+1)/2 > bid) bi--;
    int bj = bid - bi*(bi+1)/2;

    const int* mlist = (const int*)wsf + OFF_MLIST/4;
    const float* frac = wsf + OFF_FRAC/4;
    const float* ktab = wsf + OFF_KTAB/4;
    float J = wsf[OFF_CONSTS/4 + 10];

    if (tid < 64)        fi[tid]     = *(const float4*)(frac + 4*mlist[bi*64 + tid]);
    else if (tid < 128)  fj[tid-64]  = *(const float4*)(frac + 4*mlist[bj*64 + (tid-64)]);
    __syncthreads();

    int col = tid & 63;
    int kkb = tid >> 6;       // 0..3
    float4 fir = fi[col];
    float4 fjr = fj[col];
    int ty = tid >> 4, tx = tid & 15;
    int ty4 = ty*4, tx4 = tx*4;
    float acc[4][4] = {};

    for (int k0=0; k0<KHP; k0+=32) {
        #pragma unroll
        for (int it=0; it<8; it++) {
            int kk = kkb + it*4;
            float4 kt = *(const float4*)(ktab + 4*(k0+kk));
            float u = kt.x*fir.x + kt.y*fir.y + kt.z*fir.z;
            float s,c; sc_frac(u, s, c);
            cwi[kk][col] = kt.w*c; swi[kk][col] = kt.w*s;
            u = kt.x*fjr.x + kt.y*fjr.y + kt.z*fjr.z;
            sc_frac(u, s, c);
            cjs[kk][col] = c; sjs[kk][col] = s;
        }
        __syncthreads();
        #pragma unroll 4
        for (int kk=0; kk<32; kk++) {
            float4 ac  = *(const float4*)&cwi[kk][ty4];
            float4 as2 = *(const float4*)&swi[kk][ty4];
            float4 bc  = *(const float4*)&cjs[kk][tx4];
            float4 bs  = *(const float4*)&sjs[kk][tx4];
            float aC[4] = {ac.x, ac.y, ac.z, ac.w};
            float aS[4] = {as2.x, as2.y, as2.z, as2.w};
            float bC[4] = {bc.x, bc.y, bc.z, bc.w};
            float bS[4] = {bs.x, bs.y, bs.z, bs.w};
            #pragma unroll
            for (int a=0;a<4;a++)
                #pragma unroll
                for (int b=0;b<4;b++)
                    acc[a][b] = fmaf(aC[a], bC[b], fmaf(aS[a], bS[b], acc[a][b]));
        }
        __syncthreads();
    }

    float* A = wsf + OFF_A/4;
    int gi0 = bi*64 + ty4, gj0 = bj*64 + tx4;
    #pragma unroll
    for (int a=0;a<4;a++) {
        int gi = gi0 + a;
        #pragma unroll
        for (int b=0;b<4;b++) {
            int gj = gj0 + b;
            float v = acc[a][b] + ((gi==gj) ? J : 0.f);
            A[gi*NM + gj] = v;
            A[gj*NM + gi] = v;
        }
    }
}

// -------- persistent projected CG (single RHS, 1 flag barrier/iter) --------
// 256 blocks x 256 threads. Block owns rows [bid*8,bid*8+8) (32 lanes/row) for
// the matvec; thread owns float4 chunks {4t..4t+3, 1024+4t..+3} of the vectors.
// r is replicated in LDS in every block; per-block (gamma,delta,mu) partials
// are published BEFORE the flag so the global dot-reduce overlaps the w-gather.
// Projection P = I - 11^T/n applied via w~ = w - mean(w).
__launch_bounds__(256, 1)
__global__ void k_cg(float* __restrict__ wsf) {
    const float* A = wsf + OFF_A/4;
    float* vec = wsf + OFF_VEC/4;
    float* xg = vec;                       // solution q (metal order)
    const float* rg = vec + 4096;          // initial residual r0 = P*B
    int* flags = (int*)wsf + OFF_FLAGS/4;
    float* wbuf = wsf + OFF_WBUF/4;        // [parity][NM]
    float* pbuf = wsf + OFF_PBUF/4;        // [parity][512 gd | 512 mu]

    __shared__ float rs[NM];
    __shared__ float wrow[8];
    __shared__ float red[12];              // 4 waves x {g,d,mu}

    int tid = threadIdx.x, bid = blockIdx.x;
    int rl = tid >> 5, lane = tid & 31;
    int row = bid*8 + rl;
    const float* Arow = A + (size_t)row*NM;
    int ca = 4*tid;            // own chunk A: elements ca..ca+3
    int cb = 1024 + 4*tid;     // own chunk B

    for (int i=tid; i<NM/4; i+=256)
        ((float4*)rs)[i] = ((const float4*)rg)[i];
    __syncthreads();

    float sa[4]={0,0,0,0}, sb[4]={0,0,0,0};   // own s chunks
    float pr=0.f, xr=0.f;                     // own-row p/x (tid<8)
    float gp=1.f, ap=1.f;

    for (int iter=0; iter<NIT; ++iter) {
        int par = iter & 1;
        float* wb = wbuf + par*NM;
        float* pa = pbuf + par*1024;
        // ---- w_own = A_own * r, 32 lanes per row ----
        float acc=0.f;
        #pragma unroll 8
        for (int c=lane*4; c<NM; c+=128) {
            float4 a = *(const float4*)(Arow + c);
            float4 u = *(const float4*)(rs + c);
            acc += a.x*u.x + a.y*u.y + a.z*u.z + a.w*u.w;
        }
        #pragma unroll
        for (int off=1; off<32; off<<=1) acc += __shfl_xor(acc, off);
        if (lane == 0) {
            wrow[rl] = acc;
            __hip_atomic_store(wb + row, acc, __ATOMIC_RELAXED, __HIP_MEMORY_SCOPE_AGENT);
        }
        float rrow = (tid<8) ? rs[bid*8+tid] : 0.f;   // stable own-row r
        __syncthreads();   // (A) wrow ready; all w stores drained (vmcnt0)
        // ---- pre-barrier block partials (own 8 rows) + flag release ----
        if (tid == 0) {
            float gb=0.f, db=0.f, mb=0.f;
            #pragma unroll
            for (int j=0;j<8;j++) {
                float rv = rs[bid*8+j];
                gb = fmaf(rv,rv,gb); db = fmaf(rv,wrow[j],db); mb += wrow[j];
            }
            st_f2_agent(pa + 2*bid, gb, db);
            st_f2_agent(pa + 512 + 2*bid, mb, 0.f);
            __hip_atomic_store(&flags[bid], iter+1, __ATOMIC_RELEASE, __HIP_MEMORY_SCOPE_AGENT);
        }
        // ---- poll all 256 flags (2 waves, 1 u64 each) ----
        if (tid < 128) {
            unsigned long long* f8 = (unsigned long long*)flags;
            int t = iter+1;
            for (;;) {
                unsigned long long v = __hip_atomic_load(&f8[tid], __ATOMIC_RELAXED, __HIP_MEMORY_SCOPE_AGENT);
                int ok = ((int)(v & 0xffffffffu) >= t) & ((int)(v>>32) >= t);
                if (__all(ok)) break;
                __builtin_amdgcn_s_sleep(1);
            }
        }
        __syncthreads();   // (B)
        // ---- overlap: gather own w chunks || load+reduce 256 partials ----
        float2 wa0 = ld_f2_agent(wb + ca), wa1 = ld_f2_agent(wb + ca + 2);
        float2 wb0 = ld_f2_agent(wb + cb), wb1 = ld_f2_agent(wb + cb + 2);
        float2 gd  = ld_f2_agent(pa + 2*tid);
        float2 mu2 = ld_f2_agent(pa + 512 + 2*tid);
        float g = gd.x, d = gd.y, m = mu2.x;
        #pragma unroll
        for (int off=1; off<64; off<<=1) {
            g += __shfl_xor(g,off); d += __shfl_xor(d,off); m += __shfl_xor(m,off);
        }
        if ((tid&63)==0) { int w=tid>>6; red[w*3+0]=g; red[w*3+1]=d; red[w*3+2]=m; }
        __syncthreads();   // (C)
        g = red[0]+red[3]+red[6]+red[9];
        d = red[1]+red[4]+red[7]+red[10];
        m = (red[2]+red[5]+red[8]+red[11]) * (1.f/NM);   // mean(w)
        // ---- identical scalar recurrences everywhere ----
        float b, a;
        if (iter == 0) { b=0.f; a=g/d; }
        else { b = g/gp; a = g/(d - b*g/ap); }
        gp=g; ap=a;
        // ---- p/x for own rows ----
        if (tid < 8) {
            pr = (iter==0) ? rrow : fmaf(b, pr, rrow);
            xr = (iter==0) ? a*pr : fmaf(a, pr, xr);
        }
        // ---- s and r chunk updates (w~ = w - m), write rs b128 ----
        float wv[8] = {wa0.x,wa0.y,wa1.x,wa1.y, wb0.x,wb0.y,wb1.x,wb1.y};
        float4 r4a = *(const float4*)(rs + ca);
        float4 r4b = *(const float4*)(rs + cb);
        float rr[8] = {r4a.x,r4a.y,r4a.z,r4a.w, r4b.x,r4b.y,r4b.z,r4b.w};
        float nr[8];
        #pragma unroll
        for (int j=0;j<4;j++) {
            float wt = wv[j] - m;
            float sv = (iter==0) ? wt : fmaf(b, sa[j], wt);
            sa[j]=sv; nr[j] = fmaf(-a, sv, rr[j]);
        }
        #pragma unroll
        for (int j=0;j<4;j++) {
            float wt = wv[4+j] - m;
            float sv = (iter==0) ? wt : fmaf(b, sb[j], wt);
            sb[j]=sv; nr[4+j] = fmaf(-a, sv, rr[4+j]);
        }
        *(float4*)(rs + ca) = make_float4(nr[0],nr[1],nr[2],nr[3]);
        *(float4*)(rs + cb) = make_float4(nr[4],nr[5],nr[6],nr[7]);
        __syncthreads();   // (D)
    }
    if (tid < 8) xg[bid*8+tid] = xr;
}

// -------- assemble output: metal -> x, electrolyte -> q --------
__global__ void k_out(const float* __restrict__ q, const int* __restrict__ an,
                      const float* __restrict__ wsf, float* __restrict__ out) {
    int i = blockIdx.x*256 + threadIdx.x;
    if (i >= NA) return;
    if (an[i]==METAL_Z) {
        int p = ((const int*)wsf)[OFF_POSOF/4 + i];
        out[i] = wsf[OFF_VEC/4 + p];
    } else {
        out[i] = q[i];
    }
}

extern "C" void kernel_launch(void* const* d_in, const int* in_sizes, int n_in,
                              void* d_out, int out_size, void* d_ws, size_t ws_size,
                              hipStream_t stream) {
    (void)in_sizes; (void)n_in; (void)out_size; (void)ws_size;
    const float* pos  = (const float*)d_in[0];
    const float* cell = (const float*)d_in[1];
    const float* q    = (const float*)d_in[2];
    const float* Jraw = (const float*)d_in[3];
    const int*   an   = (const int*)d_in[4];
    float* wsf = (float*)d_ws;
    float* out = (float*)d_out;

    k_setup<<<1, 256, 0, stream>>>(pos, cell, Jraw, an, wsf);
    k_ktab<<<KHP/256, 256, 0, stream>>>(wsf);
    k_srsi<<<KHP, 256, 0, stream>>>(q, an, wsf);
    k_field<<<dim3(62, 8), 256, 0, stream>>>(wsf);
    k_bfinal<<<1, 1024, 0, stream>>>(wsf);
    k_abuild<<<528, 256, 0, stream>>>(wsf);
    k_cg<<<NBLK_CG, 256, 0, stream>>>(wsf);
    k_out<<<NA/256, 256, 0, stream>>>(q, an, wsf, out);
}

// Round 10
// 2603.405 us; speedup vs baseline: 1.0633x; 1.0590x over previous
//
#include <hip/hip_runtime.h>
#include <math.h>

// MetalWallQEQ: reciprocal-space Ewald QEQ for metal-wall charges.
// Round 10: truncation REVERTED (r9: A-perturbations amplified ~100x by the
// ill-conditioned solve -> full k-set mandatory). abuild restructured:
// per-wave K-split within each 256-thread block, 8x8 acc/thread (2x fewer
// LDS insts per FMA), deterministic pairwise cross-wave reduce, plain stores.

#define NA 4096
#define NM 2048
#define METAL_Z 79
#define KH 7812          // (25^3-1)/2 half k-points
#define KHP 7936         // padded to 62*128 (pad entries have w=0)
#define KW  (KHP/4)      // 1984 k per wave in abuild
#define NIT 150          // fixed CG iterations (graph-friendly)
#define NBLK_CG 256      // persistent CG grid: 1 block/CU, co-resident
#define TWO_PI 6.283185307179586f

// ---- workspace byte offsets (total ~17.7 MB) ----
#define OFF_CONSTS 0        // [0..8]=invT(cell) row-major, [9]=pref=4pi/V, [10]=J
#define OFF_SUMS   256      // scratch
#define OFF_FLAGS  512      // 256 ints: CG barrier flags (zeroed per call)
#define OFF_KTAB   4096     // KHP * {gx,gy,gz,w} floats
#define OFF_FRAC   131072   // NA * {fx,fy,fz,0} fractional coords
#define OFF_MLIST  196608   // NM ints: metal position -> atom index
#define OFF_POSOF  204800   // NA ints: atom -> metal position (metal only)
#define OFF_SRW    221184   // KHP floats: w*Re S(k)
#define OFF_SIW    252928   // KHP floats: w*Im S(k)
#define OFF_BPART  284672   // 62*NM floats: field partials
#define OFF_B      792576   // NM floats (unused scratch)
#define OFF_VEC    800768   // x (2048), pad, r (at +4096)
#define OFF_WBUF   833536   // [parity][NM] w exchange (16KB)
#define OFF_PBUF   849920   // [parity][512 gd | 512 mu] partials (8KB)
#define OFF_A      917504   // NM*NM floats (A + J on diagonal)

__device__ __forceinline__ void sc_frac(float u, float& s, float& c) {
    // u is phase in REVOLUTIONS; v_sin/v_cos take revolutions directly.
    float t = u - floorf(u);
    s = __builtin_amdgcn_sinf(t);
    c = __builtin_amdgcn_cosf(t);
}

__device__ __forceinline__ float2 ld_f2_agent(const float* p) {
    unsigned long long v = __hip_atomic_load((unsigned long long*)p,
        __ATOMIC_RELAXED, __HIP_MEMORY_SCOPE_AGENT);
    union { unsigned long long u; float2 f; } cv; cv.u = v; return cv.f;
}
__device__ __forceinline__ void st_f2_agent(float* p, float a, float b) {
    union { unsigned long long u; float2 f; } cv; cv.f = make_float2(a, b);
    __hip_atomic_store((unsigned long long*)p, cv.u,
        __ATOMIC_RELAXED, __HIP_MEMORY_SCOPE_AGENT);
}

// -------- setup: cell inverse, fractional coords, metal scan, zero flags --------
__global__ void k_setup(const float* __restrict__ pos, const float* __restrict__ cell,
                        const float* __restrict__ Jraw, const int* __restrict__ an,
                        float* __restrict__ wsf) {
    int tid = threadIdx.x;
    __shared__ float sM[9];
    __shared__ int sc[256];
    if (tid == 0) {
        float c00=cell[0],c01=cell[1],c02=cell[2];
        float c10=cell[3],c11=cell[4],c12=cell[5];
        float c20=cell[6],c21=cell[7],c22=cell[8];
        float det = c00*(c11*c22-c12*c21) - c01*(c10*c22-c12*c20) + c02*(c10*c21-c11*c20);
        float i00 =  (c11*c22 - c12*c21)/det;
        float i01 = -(c01*c22 - c02*c21)/det;
        float i02 =  (c01*c12 - c02*c11)/det;
        float i10 = -(c10*c22 - c12*c20)/det;
        float i11 =  (c00*c22 - c02*c20)/det;
        float i12 = -(c00*c12 - c02*c10)/det;
        float i20 =  (c10*c21 - c11*c20)/det;
        float i21 = -(c00*c21 - c01*c20)/det;
        float i22 =  (c00*c11 - c01*c10)/det;
        sM[0]=i00; sM[1]=i10; sM[2]=i20;
        sM[3]=i01; sM[4]=i11; sM[5]=i21;
        sM[6]=i02; sM[7]=i12; sM[8]=i22;
        float vol = fabsf(det);
        for (int m=0;m<9;m++) wsf[OFF_CONSTS/4 + m] = sM[m];
        wsf[OFF_CONSTS/4 + 9]  = 12.566370614359172f / vol;   // 4pi/V
        wsf[OFF_CONSTS/4 + 10] = Jraw[0]*Jraw[0];
    }
    __syncthreads();
    float M0=sM[0],M1=sM[1],M2=sM[2],M3=sM[3],M4=sM[4],M5=sM[5],M6=sM[6],M7=sM[7],M8=sM[8];
    for (int i=tid; i<NA; i+=256) {
        float x=pos[3*i], y=pos[3*i+1], z=pos[3*i+2];
        wsf[OFF_FRAC/4 + 4*i+0] = M0*x + M1*y + M2*z;
        wsf[OFF_FRAC/4 + 4*i+1] = M3*x + M4*y + M5*z;
        wsf[OFF_FRAC/4 + 4*i+2] = M6*x + M7*y + M8*z;
        wsf[OFF_FRAC/4 + 4*i+3] = 0.f;
    }
    ((int*)wsf)[OFF_FLAGS/4 + tid] = 0;       // CG barrier flags
    if (tid < 4) wsf[OFF_SUMS/4 + tid] = 0.f;
    // metal prefix scan (deterministic ordering == np.where order)
    int cnt = 0;
    int base_i = tid*16;
    for (int j=0;j<16;j++) cnt += (an[base_i+j]==METAL_Z) ? 1 : 0;
    sc[tid] = cnt; __syncthreads();
    for (int off=1; off<256; off<<=1) {
        int v = (tid>=off) ? sc[tid-off] : 0;
        __syncthreads();
        sc[tid] += v;
        __syncthreads();
    }
    int base = sc[tid] - cnt;
    int* mlist = (int*)wsf + OFF_MLIST/4;
    int* posof = (int*)wsf + OFF_POSOF/4;
    for (int j=0;j<16;j++) {
        int i = base_i + j;
        if (an[i]==METAL_Z) { mlist[base] = i; posof[i] = base; base++; }
    }
}

// -------- k-table: integer triple + weight w = 2*pref*exp(-k2/2)/k2 --------
__global__ void k_ktab(float* __restrict__ wsf) {
    int k = blockIdx.x*256 + threadIdx.x;
    if (k >= KHP) return;
    float4 out;
    if (k < KH) {
        int gx = k/625 - 12;
        int rem = k%625;
        int gy = rem/25 - 12;
        int gz = rem%25 - 12;
        const float* M = wsf + OFF_CONSTS/4;
        float pref = M[9];
        float kx = TWO_PI*(gx*M[0] + gy*M[3] + gz*M[6]);
        float ky = TWO_PI*(gx*M[1] + gy*M[4] + gz*M[7]);
        float kz = TWO_PI*(gx*M[2] + gy*M[5] + gz*M[8]);
        float k2 = kx*kx + ky*ky + kz*kz;
        float kfac = __expf(-0.5f*k2) / k2;
        out = make_float4((float)gx, (float)gy, (float)gz, 2.f*pref*kfac);
    } else {
        out = make_float4(0.f, 0.f, 0.f, 0.f);
    }
    *(float4*)(wsf + OFF_KTAB/4 + 4*k) = out;
}

// -------- structure factors over electrolyte charges (metal q := 0) --------
__global__ void k_srsi(const float* __restrict__ q, const int* __restrict__ an,
                       float* __restrict__ wsf) {
    int k = blockIdx.x;
    int tid = threadIdx.x;
    float4 kt = *(const float4*)(wsf + OFF_KTAB/4 + 4*k);
    const float* frac = wsf + OFF_FRAC/4;
    float aR=0.f, aI=0.f;
    for (int i=tid; i<NA; i+=256) {
        float qa = (an[i]==METAL_Z) ? 0.f : q[i];
        float4 f = *(const float4*)(frac + 4*i);
        float u = kt.x*f.x + kt.y*f.y + kt.z*f.z;
        float s,c; sc_frac(u, s, c);
        aR += qa*c; aI += qa*s;
    }
    __shared__ float sR[256], sI[256];
    sR[tid]=aR; sI[tid]=aI; __syncthreads();
    for (int off=128; off>0; off>>=1) {
        if (tid<off) { sR[tid]+=sR[tid+off]; sI[tid]+=sI[tid+off]; }
        __syncthreads();
    }
    if (tid==0) {
        wsf[OFF_SRW/4 + k] = kt.w * sR[0];
        wsf[OFF_SIW/4 + k] = kt.w * sI[0];
    }
}

// -------- field at metal atoms (partial over k-chunks) --------
__global__ void k_field(float* __restrict__ wsf) {
    int kc = blockIdx.x;
    int m = blockIdx.y*256 + threadIdx.x;
    int atom = ((const int*)wsf)[OFF_MLIST/4 + m];
    float4 f = *(const float4*)(wsf + OFF_FRAC/4 + 4*atom);
    const float* kt = wsf + OFF_KTAB/4;
    const float* SrW = wsf + OFF_SRW/4;
    const float* SiW = wsf + OFF_SIW/4;
    float acc = 0.f;
    int k0 = kc*128;
    for (int j=0;j<128;j++) {
        int k = k0 + j;
        float4 g = *(const float4*)(kt + 4*k);
        float u = g.x*f.x + g.y*f.y + g.z*f.z;
        float s,c; sc_frac(u, s, c);
        acc = fmaf(c, SrW[k], fmaf(s, SiW[k], acc));
    }
    wsf[OFF_BPART/4 + kc*NM + m] = acc;
}

// -------- r0 = P*B = B - mean(B); B = -field (1 block x 1024) --------
__global__ void k_bfinal(float* __restrict__ wsf) {
    int tid = threadIdx.x;
    float b0 = 0.f, b1 = 0.f;
    for (int kc=0;kc<62;kc++) {
        b0 += wsf[OFF_BPART/4 + kc*NM + tid];
        b1 += wsf[OFF_BPART/4 + kc*NM + 1024 + tid];
    }
    b0 = -b0; b1 = -b1;
    __shared__ float sb[1024];
    sb[tid] = b0 + b1; __syncthreads();
    for (int off=512; off>0; off>>=1) {
        if (tid<off) sb[tid] += sb[tid+off];
        __syncthreads();
    }
    float mean = sb[0] * (1.f/NM);
    float* r = wsf + OFF_VEC/4 + 4096;
    r[tid]        = b0 - mean;
    r[1024 + tid] = b1 - mean;
}

// -------- A build: triangular 64x64 tiles, per-wave K-split, 8x8 acc --------
// 256 threads = 4 waves; wave w covers k in [w*KW,(w+1)*KW) with private LDS
// staging quadrant; lane grid 8x8 -> 8 rows x 8 cols per lane (128 FMA per
// 8 ds_read_b128). Final: pairwise deterministic reduce (w0+w1)+(w2+w3),
// wave 0 adds J on diagonal and does plain symmetric stores (no atomics).
__launch_bounds__(256)
__global__ void k_abuild(float* __restrict__ wsf) {
    __shared__ float S[8704];      // [0..8192) staging/reduce, [8192..) fi,fj
    int tid = threadIdx.x;
    int bid = blockIdx.x;
    int bi = (int)((sqrtf(8.f*bid + 1.f) - 1.f)*0.5f);
    while ((bi+1)*(bi+2)/2 <= bid) bi++;
    while (bi*(bi+1)/2 > bid) bi--;
    int bj = bid - bi*(bi+1)/2;

    const int* mlist = (const int*)wsf + OFF_MLIST/4;
    const float* frac = wsf + OFF_FRAC/4;
    const float* ktab = wsf + OFF_KTAB/4;
    float J = wsf[OFF_CONSTS/4 + 10];

    float4* fi = (float4*)(S + 8192);
    float4* fj = (float4*)(S + 8448);
    if (tid < 64)        fi[tid]    = *(const float4*)(frac + 4*mlist[bi*64 + tid]);
    else if (tid < 128)  fj[tid-64] = *(const float4*)(frac + 4*mlist[bj*64 + (tid-64)]);
    __syncthreads();

    int w = tid >> 6, lane = tid & 63;
    int ty = lane >> 3, tx = lane & 7;
    float4 fir = fi[lane], fjr = fj[lane];
    float* cw = S + w*2048;        // [8][64] w*cos_i
    float* sw = cw + 512;          // [8][64] w*sin_i
    float* cj = cw + 1024;         // [8][64] cos_j
    float* sj = cw + 1536;         // [8][64] sin_j

    float acc[8][8] = {};

    for (int k0 = w*KW; k0 < (w+1)*KW; k0 += 8) {
        #pragma unroll
        for (int kk=0; kk<8; kk++) {
            float4 kt = *(const float4*)(ktab + 4*(k0+kk));
            float u = kt.x*fir.x + kt.y*fir.y + kt.z*fir.z;
            float s,c; sc_frac(u, s, c);
            cw[kk*64+lane] = kt.w*c; sw[kk*64+lane] = kt.w*s;
            u = kt.x*fjr.x + kt.y*fjr.y + kt.z*fjr.z;
            sc_frac(u, s, c);
            cj[kk*64+lane] = c; sj[kk*64+lane] = s;
        }
        __syncthreads();
        #pragma unroll 2
        for (int kk=0; kk<8; kk++) {
            float4 a0 = *(const float4*)(cw + kk*64 + ty*8);
            float4 a1 = *(const float4*)(cw + kk*64 + ty*8 + 4);
            float4 s0 = *(const float4*)(sw + kk*64 + ty*8);
            float4 s1 = *(const float4*)(sw + kk*64 + ty*8 + 4);
            float4 b0 = *(const float4*)(cj + kk*64 + tx*8);
            float4 b1 = *(const float4*)(cj + kk*64 + tx*8 + 4);
            float4 t0 = *(const float4*)(sj + kk*64 + tx*8);
            float4 t1 = *(const float4*)(sj + kk*64 + tx*8 + 4);
            float aC[8] = {a0.x,a0.y,a0.z,a0.w, a1.x,a1.y,a1.z,a1.w};
            float aS[8] = {s0.x,s0.y,s0.z,s0.w, s1.x,s1.y,s1.z,s1.w};
            float bC[8] = {b0.x,b0.y,b0.z,b0.w, b1.x,b1.y,b1.z,b1.w};
            float bS[8] = {t0.x,t0.y,t0.z,t0.w, t1.x,t1.y,t1.z,t1.w};
            #pragma unroll
            for (int a=0;a<8;a++)
                #pragma unroll
                for (int b=0;b<8;b++)
                    acc[a][b] = fmaf(aC[a], bC[b], fmaf(aS[a], bS[b], acc[a][b]));
        }
        __syncthreads();
    }

    // ---- deterministic pairwise reduce: (w0+w1) + (w2+w3) ----
    __syncthreads();
    if (w==1) {
        #pragma unroll
        for (int i=0;i<64;i++) S[i*64+lane] = acc[i>>3][i&7];
    } else if (w==3) {
        #pragma unroll
        for (int i=0;i<64;i++) S[4096 + i*64+lane] = acc[i>>3][i&7];
    }
    __syncthreads();
    if (w==0) {
        #pragma unroll
        for (int i=0;i<64;i++) acc[i>>3][i&7] += S[i*64+lane];
    } else if (w==2) {
        #pragma unroll
        for (int i=0;i<64;i++) acc[i>>3][i&7] += S[4096 + i*64+lane];
    }
    __syncthreads();
    if (w==2) {
        #pragma unroll
        for (int i=0;i<64;i++) S[i*64+lane] = acc[i>>3][i&7];
    }
    __syncthreads();
    if (w==0) {
        #pragma unroll
        for (int i=0;i<64;i++) acc[i>>3][i&7] += S[i*64+lane];
        float* A = wsf + OFF_A/4;
        int gi0 = bi*64 + ty*8, gj0 = bj*64 + tx*8;
        #pragma unroll
        for (int a=0;a<8;a++) {
            int gi = gi0 + a;
            #pragma unroll
            for (int b=0;b<8;b++) {
                int gj = gj0 + b;
                float v = acc[a][b] + ((gi==gj) ? J : 0.f);
                A[gi*NM + gj] = v;
                A[gj*NM + gi] = v;
            }
        }
    }
}

// -------- persistent projected CG (single RHS, 1 flag barrier/iter) --------
__launch_bounds__(256, 1)
__global__ void k_cg(float* __restrict__ wsf) {
    const float* A = wsf + OFF_A/4;
    float* vec = wsf + OFF_VEC/4;
    float* xg = vec;                       // solution q (metal order)
    const float* rg = vec + 4096;          // initial residual r0 = P*B
    int* flags = (int*)wsf + OFF_FLAGS/4;
    float* wbuf = wsf + OFF_WBUF/4;        // [parity][NM]
    float* pbuf = wsf + OFF_PBUF/4;        // [parity][512 gd | 512 mu]

    __shared__ float rs[NM];
    __shared__ float wrow[8];
    __shared__ float red[12];              // 4 waves x {g,d,mu}

    int tid = threadIdx.x, bid = blockIdx.x;
    int rl = tid >> 5, lane = tid & 31;
    int row = bid*8 + rl;
    const float* Arow = A + (size_t)row*NM;
    int ca = 4*tid;            // own chunk A: elements ca..ca+3
    int cb = 1024 + 4*tid;     // own chunk B

    for (int i=tid; i<NM/4; i+=256)
        ((float4*)rs)[i] = ((const float4*)rg)[i];
    __syncthreads();

    float sa[4]={0,0,0,0}, sb[4]={0,0,0,0};   // own s chunks
    float pr=0.f, xr=0.f;                     // own-row p/x (tid<8)
    float gp=1.f, ap=1.f;

    for (int iter=0; iter<NIT; ++iter) {
        int par = iter & 1;
        float* wb = wbuf + par*NM;
        float* pa = pbuf + par*1024;
        // ---- w_own = A_own * r, 32 lanes per row ----
        float acc=0.f;
        #pragma unroll 8
        for (int c=lane*4; c<NM; c+=128) {
            float4 a = *(const float4*)(Arow + c);
            float4 u = *(const float4*)(rs + c);
            acc += a.x*u.x + a.y*u.y + a.z*u.z + a.w*u.w;
        }
        #pragma unroll
        for (int off=1; off<32; off<<=1) acc += __shfl_xor(acc, off);
        if (lane == 0) {
            wrow[rl] = acc;
            __hip_atomic_store(wb + row, acc, __ATOMIC_RELAXED, __HIP_MEMORY_SCOPE_AGENT);
        }
        float rrow = (tid<8) ? rs[bid*8+tid] : 0.f;   // stable own-row r
        __syncthreads();   // (A) wrow ready; all w stores drained (vmcnt0)
        // ---- pre-barrier block partials (own 8 rows) + flag release ----
        if (tid == 0) {
            float gb=0.f, db=0.f, mb=0.f;
            #pragma unroll
            for (int j=0;j<8;j++) {
                float rv = rs[bid*8+j];
                gb = fmaf(rv,rv,gb); db = fmaf(rv,wrow[j],db); mb += wrow[j];
            }
            st_f2_agent(pa + 2*bid, gb, db);
            st_f2_agent(pa + 512 + 2*bid, mb, 0.f);
            __hip_atomic_store(&flags[bid], iter+1, __ATOMIC_RELEASE, __HIP_MEMORY_SCOPE_AGENT);
        }
        // ---- poll all 256 flags (2 waves, 1 u64 each) ----
        if (tid < 128) {
            unsigned long long* f8 = (unsigned long long*)flags;
            int t = iter+1;
            for (;;) {
                unsigned long long v = __hip_atomic_load(&f8[tid], __ATOMIC_RELAXED, __HIP_MEMORY_SCOPE_AGENT);
                int ok = ((int)(v & 0xffffffffu) >= t) & ((int)(v>>32) >= t);
                if (__all(ok)) break;
                __builtin_amdgcn_s_sleep(1);
            }
        }
        __syncthreads();   // (B)
        // ---- overlap: gather own w chunks || load+reduce 256 partials ----
        float2 wa0 = ld_f2_agent(wb + ca), wa1 = ld_f2_agent(wb + ca + 2);
        float2 wb0 = ld_f2_agent(wb + cb), wb1 = ld_f2_agent(wb + cb + 2);
        float2 gd  = ld_f2_agent(pa + 2*tid);
        float2 mu2 = ld_f2_agent(pa + 512 + 2*tid);
        float g = gd.x, d = gd.y, m = mu2.x;
        #pragma unroll
        for (int off=1; off<64; off<<=1) {
            g += __shfl_xor(g,off); d += __shfl_xor(d,off); m += __shfl_xor(m,off);
        }
        if ((tid&63)==0) { int wv_=tid>>6; red[wv_*3+0]=g; red[wv_*3+1]=d; red[wv_*3+2]=m; }
        __syncthreads();   // (C)
        g = red[0]+red[3]+red[6]+red[9];
        d = red[1]+red[4]+red[7]+red[10];
        m = (red[2]+red[5]+red[8]+red[11]) * (1.f/NM);   // mean(w)
        // ---- identical scalar recurrences everywhere ----
        float b, a;
        if (iter == 0) { b=0.f; a=g/d; }
        else { b = g/gp; a = g/(d - b*g/ap); }
        gp=g; ap=a;
        // ---- p/x for own rows ----
        if (tid < 8) {
            pr = (iter==0) ? rrow : fmaf(b, pr, rrow);
            xr = (iter==0) ? a*pr : fmaf(a, pr, xr);
        }
        // ---- s and r chunk updates (w~ = w - m), write rs b128 ----
        float wv[8] = {wa0.x,wa0.y,wa1.x,wa1.y, wb0.x,wb0.y,wb1.x,wb1.y};
        float4 r4a = *(const float4*)(rs + ca);
        float4 r4b = *(const float4*)(rs + cb);
        float rr[8] = {r4a.x,r4a.y,r4a.z,r4a.w, r4b.x,r4b.y,r4b.z,r4b.w};
        float nr[8];
        #pragma unroll
        for (int j=0;j<4;j++) {
            float wt = wv[j] - m;
            float sv = (iter==0) ? wt : fmaf(b, sa[j], wt);
            sa[j]=sv; nr[j] = fmaf(-a, sv, rr[j]);
        }
        #pragma unroll
        for (int j=0;j<4;j++) {
            float wt = wv[4+j] - m;
            float sv = (iter==0) ? wt : fmaf(b, sb[j], wt);
            sb[j]=sv; nr[4+j] = fmaf(-a, sv, rr[4+j]);
        }
        *(float4*)(rs + ca) = make_float4(nr[0],nr[1],nr[2],nr[3]);
        *(float4*)(rs + cb) = make_float4(nr[4],nr[5],nr[6],nr[7]);
        __syncthreads();   // (D)
    }
    if (tid < 8) xg[bid*8+tid] = xr;
}

// -------- assemble output: metal -> x, electrolyte -> q --------
__global__ void k_out(const float* __restrict__ q, const int* __restrict__ an,
                      const float* __restrict__ wsf, float* __restrict__ out) {
    int i = blockIdx.x*256 + threadIdx.x;
    if (i >= NA) return;
    if (an[i]==METAL_Z) {
        int p = ((const int*)wsf)[OFF_POSOF/4 + i];
        out[i] = wsf[OFF_VEC/4 + p];
    } else {
        out[i] = q[i];
    }
}

extern "C" void kernel_launch(void* const* d_in, const int* in_sizes, int n_in,
                              void* d_out, int out_size, void* d_ws, size_t ws_size,
                              hipStream_t stream) {
    (void)in_sizes; (void)n_in; (void)out_size; (void)ws_size;
    const float* pos  = (const float*)d_in[0];
    const float* cell = (const float*)d_in[1];
    const float* q    = (const float*)d_in[2];
    const float* Jraw = (const float*)d_in[3];
    const int*   an   = (const int*)d_in[4];
    float* wsf = (float*)d_ws;
    float* out = (float*)d_out;

    k_setup<<<1, 256, 0, stream>>>(pos, cell, Jraw, an, wsf);
    k_ktab<<<KHP/256, 256, 0, stream>>>(wsf);
    k_srsi<<<KHP, 256, 0, stream>>>(q, an, wsf);
    k_field<<<dim3(62, 8), 256, 0, stream>>>(wsf);
    k_bfinal<<<1, 1024, 0, stream>>>(wsf);
    k_abuild<<<528, 256, 0, stream>>>(wsf);
    k_cg<<<NBLK_CG, 256, 0, stream>>>(wsf);
    k_out<<<NA/256, 256, 0, stream>>>(q, an, wsf, out);
}

// Round 11
// 2499.696 us; speedup vs baseline: 1.1075x; 1.0415x over previous
//
#include <hip/hip_runtime.h>
#include <math.h>

// MetalWallQEQ: reciprocal-space Ewald QEQ for metal-wall charges.
// Round 11: single change vs r10 — removed the two in-loop __syncthreads()
// in k_abuild. Each wave's staging LDS quadrant is private, so within-wave
// lgkmcnt ordering suffices; barriers were serializing 4-wave convoys at
// 2 waves/SIMD occupancy (r10: measured 1322 vs 820 LDS-bound model).

#define NA 4096
#define NM 2048
#define METAL_Z 79
#define KH 7812          // (25^3-1)/2 half k-points
#define KHP 7936         // padded to 62*128 (pad entries have w=0)
#define KW  (KHP/4)      // 1984 k per wave in abuild
#define NIT 150          // fixed CG iterations (graph-friendly)
#define NBLK_CG 256      // persistent CG grid: 1 block/CU, co-resident
#define TWO_PI 6.283185307179586f

// ---- workspace byte offsets (total ~17.7 MB) ----
#define OFF_CONSTS 0        // [0..8]=invT(cell) row-major, [9]=pref=4pi/V, [10]=J
#define OFF_SUMS   256      // scratch
#define OFF_FLAGS  512      // 256 ints: CG barrier flags (zeroed per call)
#define OFF_KTAB   4096     // KHP * {gx,gy,gz,w} floats
#define OFF_FRAC   131072   // NA * {fx,fy,fz,0} fractional coords
#define OFF_MLIST  196608   // NM ints: metal position -> atom index
#define OFF_POSOF  204800   // NA ints: atom -> metal position (metal only)
#define OFF_SRW    221184   // KHP floats: w*Re S(k)
#define OFF_SIW    252928   // KHP floats: w*Im S(k)
#define OFF_BPART  284672   // 62*NM floats: field partials
#define OFF_B      792576   // NM floats (unused scratch)
#define OFF_VEC    800768   // x (2048), pad, r (at +4096)
#define OFF_WBUF   833536   // [parity][NM] w exchange (16KB)
#define OFF_PBUF   849920   // [parity][512 gd | 512 mu] partials (8KB)
#define OFF_A      917504   // NM*NM floats (A + J on diagonal)

__device__ __forceinline__ void sc_frac(float u, float& s, float& c) {
    // u is phase in REVOLUTIONS; v_sin/v_cos take revolutions directly.
    float t = u - floorf(u);
    s = __builtin_amdgcn_sinf(t);
    c = __builtin_amdgcn_cosf(t);
}

__device__ __forceinline__ float2 ld_f2_agent(const float* p) {
    unsigned long long v = __hip_atomic_load((unsigned long long*)p,
        __ATOMIC_RELAXED, __HIP_MEMORY_SCOPE_AGENT);
    union { unsigned long long u; float2 f; } cv; cv.u = v; return cv.f;
}
__device__ __forceinline__ void st_f2_agent(float* p, float a, float b) {
    union { unsigned long long u; float2 f; } cv; cv.f = make_float2(a, b);
    __hip_atomic_store((unsigned long long*)p, cv.u,
        __ATOMIC_RELAXED, __HIP_MEMORY_SCOPE_AGENT);
}

// -------- setup: cell inverse, fractional coords, metal scan, zero flags --------
__global__ void k_setup(const float* __restrict__ pos, const float* __restrict__ cell,
                        const float* __restrict__ Jraw, const int* __restrict__ an,
                        float* __restrict__ wsf) {
    int tid = threadIdx.x;
    __shared__ float sM[9];
    __shared__ int sc[256];
    if (tid == 0) {
        float c00=cell[0],c01=cell[1],c02=cell[2];
        float c10=cell[3],c11=cell[4],c12=cell[5];
        float c20=cell[6],c21=cell[7],c22=cell[8];
        float det = c00*(c11*c22-c12*c21) - c01*(c10*c22-c12*c20) + c02*(c10*c21-c11*c20);
        float i00 =  (c11*c22 - c12*c21)/det;
        float i01 = -(c01*c22 - c02*c21)/det;
        float i02 =  (c01*c12 - c02*c11)/det;
        float i10 = -(c10*c22 - c12*c20)/det;
        float i11 =  (c00*c22 - c02*c20)/det;
        float i12 = -(c00*c12 - c02*c10)/det;
        float i20 =  (c10*c21 - c11*c20)/det;
        float i21 = -(c00*c21 - c01*c20)/det;
        float i22 =  (c00*c11 - c01*c10)/det;
        sM[0]=i00; sM[1]=i10; sM[2]=i20;
        sM[3]=i01; sM[4]=i11; sM[5]=i21;
        sM[6]=i02; sM[7]=i12; sM[8]=i22;
        float vol = fabsf(det);
        for (int m=0;m<9;m++) wsf[OFF_CONSTS/4 + m] = sM[m];
        wsf[OFF_CONSTS/4 + 9]  = 12.566370614359172f / vol;   // 4pi/V
        wsf[OFF_CONSTS/4 + 10] = Jraw[0]*Jraw[0];
    }
    __syncthreads();
    float M0=sM[0],M1=sM[1],M2=sM[2],M3=sM[3],M4=sM[4],M5=sM[5],M6=sM[6],M7=sM[7],M8=sM[8];
    for (int i=tid; i<NA; i+=256) {
        float x=pos[3*i], y=pos[3*i+1], z=pos[3*i+2];
        wsf[OFF_FRAC/4 + 4*i+0] = M0*x + M1*y + M2*z;
        wsf[OFF_FRAC/4 + 4*i+1] = M3*x + M4*y + M5*z;
        wsf[OFF_FRAC/4 + 4*i+2] = M6*x + M7*y + M8*z;
        wsf[OFF_FRAC/4 + 4*i+3] = 0.f;
    }
    ((int*)wsf)[OFF_FLAGS/4 + tid] = 0;       // CG barrier flags
    if (tid < 4) wsf[OFF_SUMS/4 + tid] = 0.f;
    // metal prefix scan (deterministic ordering == np.where order)
    int cnt = 0;
    int base_i = tid*16;
    for (int j=0;j<16;j++) cnt += (an[base_i+j]==METAL_Z) ? 1 : 0;
    sc[tid] = cnt; __syncthreads();
    for (int off=1; off<256; off<<=1) {
        int v = (tid>=off) ? sc[tid-off] : 0;
        __syncthreads();
        sc[tid] += v;
        __syncthreads();
    }
    int base = sc[tid] - cnt;
    int* mlist = (int*)wsf + OFF_MLIST/4;
    int* posof = (int*)wsf + OFF_POSOF/4;
    for (int j=0;j<16;j++) {
        int i = base_i + j;
        if (an[i]==METAL_Z) { mlist[base] = i; posof[i] = base; base++; }
    }
}

// -------- k-table: integer triple + weight w = 2*pref*exp(-k2/2)/k2 --------
__global__ void k_ktab(float* __restrict__ wsf) {
    int k = blockIdx.x*256 + threadIdx.x;
    if (k >= KHP) return;
    float4 out;
    if (k < KH) {
        int gx = k/625 - 12;
        int rem = k%625;
        int gy = rem/25 - 12;
        int gz = rem%25 - 12;
        const float* M = wsf + OFF_CONSTS/4;
        float pref = M[9];
        float kx = TWO_PI*(gx*M[0] + gy*M[3] + gz*M[6]);
        float ky = TWO_PI*(gx*M[1] + gy*M[4] + gz*M[7]);
        float kz = TWO_PI*(gx*M[2] + gy*M[5] + gz*M[8]);
        float k2 = kx*kx + ky*ky + kz*kz;
        float kfac = __expf(-0.5f*k2) / k2;
        out = make_float4((float)gx, (float)gy, (float)gz, 2.f*pref*kfac);
    } else {
        out = make_float4(0.f, 0.f, 0.f, 0.f);
    }
    *(float4*)(wsf + OFF_KTAB/4 + 4*k) = out;
}

// -------- structure factors over electrolyte charges (metal q := 0) --------
__global__ void k_srsi(const float* __restrict__ q, const int* __restrict__ an,
                       float* __restrict__ wsf) {
    int k = blockIdx.x;
    int tid = threadIdx.x;
    float4 kt = *(const float4*)(wsf + OFF_KTAB/4 + 4*k);
    const float* frac = wsf + OFF_FRAC/4;
    float aR=0.f, aI=0.f;
    for (int i=tid; i<NA; i+=256) {
        float qa = (an[i]==METAL_Z) ? 0.f : q[i];
        float4 f = *(const float4*)(frac + 4*i);
        float u = kt.x*f.x + kt.y*f.y + kt.z*f.z;
        float s,c; sc_frac(u, s, c);
        aR += qa*c; aI += qa*s;
    }
    __shared__ float sR[256], sI[256];
    sR[tid]=aR; sI[tid]=aI; __syncthreads();
    for (int off=128; off>0; off>>=1) {
        if (tid<off) { sR[tid]+=sR[tid+off]; sI[tid]+=sI[tid+off]; }
        __syncthreads();
    }
    if (tid==0) {
        wsf[OFF_SRW/4 + k] = kt.w * sR[0];
        wsf[OFF_SIW/4 + k] = kt.w * sI[0];
    }
}

// -------- field at metal atoms (partial over k-chunks) --------
__global__ void k_field(float* __restrict__ wsf) {
    int kc = blockIdx.x;
    int m = blockIdx.y*256 + threadIdx.x;
    int atom = ((const int*)wsf)[OFF_MLIST/4 + m];
    float4 f = *(const float4*)(wsf + OFF_FRAC/4 + 4*atom);
    const float* kt = wsf + OFF_KTAB/4;
    const float* SrW = wsf + OFF_SRW/4;
    const float* SiW = wsf + OFF_SIW/4;
    float acc = 0.f;
    int k0 = kc*128;
    for (int j=0;j<128;j++) {
        int k = k0 + j;
        float4 g = *(const float4*)(kt + 4*k);
        float u = g.x*f.x + g.y*f.y + g.z*f.z;
        float s,c; sc_frac(u, s, c);
        acc = fmaf(c, SrW[k], fmaf(s, SiW[k], acc));
    }
    wsf[OFF_BPART/4 + kc*NM + m] = acc;
}

// -------- r0 = P*B = B - mean(B); B = -field (1 block x 1024) --------
__global__ void k_bfinal(float* __restrict__ wsf) {
    int tid = threadIdx.x;
    float b0 = 0.f, b1 = 0.f;
    for (int kc=0;kc<62;kc++) {
        b0 += wsf[OFF_BPART/4 + kc*NM + tid];
        b1 += wsf[OFF_BPART/4 + kc*NM + 1024 + tid];
    }
    b0 = -b0; b1 = -b1;
    __shared__ float sb[1024];
    sb[tid] = b0 + b1; __syncthreads();
    for (int off=512; off>0; off>>=1) {
        if (tid<off) sb[tid] += sb[tid+off];
        __syncthreads();
    }
    float mean = sb[0] * (1.f/NM);
    float* r = wsf + OFF_VEC/4 + 4096;
    r[tid]        = b0 - mean;
    r[1024 + tid] = b1 - mean;
}

// -------- A build: triangular 64x64 tiles, per-wave K-split, 8x8 acc --------
// 256 threads = 4 waves; wave w covers k in [w*KW,(w+1)*KW) with PRIVATE LDS
// staging quadrant -> no in-loop barriers needed (within-wave lgkmcnt order).
// Final: pairwise deterministic reduce (w0+w1)+(w2+w3), wave 0 stores + J.
__launch_bounds__(256)
__global__ void k_abuild(float* __restrict__ wsf) {
    __shared__ float S[8704];      // [0..8192) staging/reduce, [8192..) fi,fj
    int tid = threadIdx.x;
    int bid = blockIdx.x;
    int bi = (int)((sqrtf(8.f*bid + 1.f) - 1.f)*0.5f);
    while ((bi+1)*(bi+2)/2 <= bid) bi++;
    while (bi*(bi+1)/2 > bid) bi--;
    int bj = bid - bi*(bi+1)/2;

    const int* mlist = (const int*)wsf + OFF_MLIST/4;
    const float* frac = wsf + OFF_FRAC/4;
    const float* ktab = wsf + OFF_KTAB/4;
    float J = wsf[OFF_CONSTS/4 + 10];

    float4* fi = (float4*)(S + 8192);
    float4* fj = (float4*)(S + 8448);
    if (tid < 64)        fi[tid]    = *(const float4*)(frac + 4*mlist[bi*64 + tid]);
    else if (tid < 128)  fj[tid-64] = *(const float4*)(frac + 4*mlist[bj*64 + (tid-64)]);
    __syncthreads();

    int w = tid >> 6, lane = tid & 63;
    int ty = lane >> 3, tx = lane & 7;
    float4 fir = fi[lane], fjr = fj[lane];
    float* cw = S + w*2048;        // [8][64] w*cos_i   (wave-private quadrant)
    float* sw = cw + 512;          // [8][64] w*sin_i
    float* cj = cw + 1024;         // [8][64] cos_j
    float* sj = cw + 1536;         // [8][64] sin_j

    float acc[8][8] = {};

    for (int k0 = w*KW; k0 < (w+1)*KW; k0 += 8) {
        #pragma unroll
        for (int kk=0; kk<8; kk++) {
            float4 kt = *(const float4*)(ktab + 4*(k0+kk));
            float u = kt.x*fir.x + kt.y*fir.y + kt.z*fir.z;
            float s,c; sc_frac(u, s, c);
            cw[kk*64+lane] = kt.w*c; sw[kk*64+lane] = kt.w*s;
            u = kt.x*fjr.x + kt.y*fjr.y + kt.z*fjr.z;
            sc_frac(u, s, c);
            cj[kk*64+lane] = c; sj[kk*64+lane] = s;
        }
        // no __syncthreads(): staging quadrant is wave-private; in-wave
        // LDS ordering (lgkmcnt) is sufficient.
        #pragma unroll 2
        for (int kk=0; kk<8; kk++) {
            float4 a0 = *(const float4*)(cw + kk*64 + ty*8);
            float4 a1 = *(const float4*)(cw + kk*64 + ty*8 + 4);
            float4 s0 = *(const float4*)(sw + kk*64 + ty*8);
            float4 s1 = *(const float4*)(sw + kk*64 + ty*8 + 4);
            float4 b0 = *(const float4*)(cj + kk*64 + tx*8);
            float4 b1 = *(const float4*)(cj + kk*64 + tx*8 + 4);
            float4 t0 = *(const float4*)(sj + kk*64 + tx*8);
            float4 t1 = *(const float4*)(sj + kk*64 + tx*8 + 4);
            float aC[8] = {a0.x,a0.y,a0.z,a0.w, a1.x,a1.y,a1.z,a1.w};
            float aS[8] = {s0.x,s0.y,s0.z,s0.w, s1.x,s1.y,s1.z,s1.w};
            float bC[8] = {b0.x,b0.y,b0.z,b0.w, b1.x,b1.y,b1.z,b1.w};
            float bS[8] = {t0.x,t0.y,t0.z,t0.w, t1.x,t1.y,t1.z,t1.w};
            #pragma unroll
            for (int a=0;a<8;a++)
                #pragma unroll
                for (int b=0;b<8;b++)
                    acc[a][b] = fmaf(aC[a], bC[b], fmaf(aS[a], bS[b], acc[a][b]));
        }
    }

    // ---- deterministic pairwise reduce: (w0+w1) + (w2+w3) ----
    __syncthreads();
    if (w==1) {
        #pragma unroll
        for (int i=0;i<64;i++) S[i*64+lane] = acc[i>>3][i&7];
    } else if (w==3) {
        #pragma unroll
        for (int i=0;i<64;i++) S[4096 + i*64+lane] = acc[i>>3][i&7];
    }
    __syncthreads();
    if (w==0) {
        #pragma unroll
        for (int i=0;i<64;i++) acc[i>>3][i&7] += S[i*64+lane];
    } else if (w==2) {
        #pragma unroll
        for (int i=0;i<64;i++) acc[i>>3][i&7] += S[4096 + i*64+lane];
    }
    __syncthreads();
    if (w==2) {
        #pragma unroll
        for (int i=0;i<64;i++) S[i*64+lane] = acc[i>>3][i&7];
    }
    __syncthreads();
    if (w==0) {
        #pragma unroll
        for (int i=0;i<64;i++) acc[i>>3][i&7] += S[i*64+lane];
        float* A = wsf + OFF_A/4;
        int gi0 = bi*64 + ty*8, gj0 = bj*64 + tx*8;
        #pragma unroll
        for (int a=0;a<8;a++) {
            int gi = gi0 + a;
            #pragma unroll
            for (int b=0;b<8;b++) {
                int gj = gj0 + b;
                float v = acc[a][b] + ((gi==gj) ? J : 0.f);
                A[gi*NM + gj] = v;
                A[gj*NM + gi] = v;
            }
        }
    }
}

// -------- persistent projected CG (single RHS, 1 flag barrier/iter) --------
__launch_bounds__(256, 1)
__global__ void k_cg(float* __restrict__ wsf) {
    const float* A = wsf + OFF_A/4;
    float* vec = wsf + OFF_VEC/4;
    float* xg = vec;                       // solution q (metal order)
    const float* rg = vec + 4096;          // initial residual r0 = P*B
    int* flags = (int*)wsf + OFF_FLAGS/4;
    float* wbuf = wsf + OFF_WBUF/4;        // [parity][NM]
    float* pbuf = wsf + OFF_PBUF/4;        // [parity][512 gd | 512 mu]

    __shared__ float rs[NM];
    __shared__ float wrow[8];
    __shared__ float red[12];              // 4 waves x {g,d,mu}

    int tid = threadIdx.x, bid = blockIdx.x;
    int rl = tid >> 5, lane = tid & 31;
    int row = bid*8 + rl;
    const float* Arow = A + (size_t)row*NM;
    int ca = 4*tid;            // own chunk A: elements ca..ca+3
    int cb = 1024 + 4*tid;     // own chunk B

    for (int i=tid; i<NM/4; i+=256)
        ((float4*)rs)[i] = ((const float4*)rg)[i];
    __syncthreads();

    float sa[4]={0,0,0,0}, sb[4]={0,0,0,0};   // own s chunks
    float pr=0.f, xr=0.f;                     // own-row p/x (tid<8)
    float gp=1.f, ap=1.f;

    for (int iter=0; iter<NIT; ++iter) {
        int par = iter & 1;
        float* wb = wbuf + par*NM;
        float* pa = pbuf + par*1024;
        // ---- w_own = A_own * r, 32 lanes per row ----
        float acc=0.f;
        #pragma unroll 8
        for (int c=lane*4; c<NM; c+=128) {
            float4 a = *(const float4*)(Arow + c);
            float4 u = *(const float4*)(rs + c);
            acc += a.x*u.x + a.y*u.y + a.z*u.z + a.w*u.w;
        }
        #pragma unroll
        for (int off=1; off<32; off<<=1) acc += __shfl_xor(acc, off);
        if (lane == 0) {
            wrow[rl] = acc;
            __hip_atomic_store(wb + row, acc, __ATOMIC_RELAXED, __HIP_MEMORY_SCOPE_AGENT);
        }
        float rrow = (tid<8) ? rs[bid*8+tid] : 0.f;   // stable own-row r
        __syncthreads();   // (A) wrow ready; all w stores drained (vmcnt0)
        // ---- pre-barrier block partials (own 8 rows) + flag release ----
        if (tid == 0) {
            float gb=0.f, db=0.f, mb=0.f;
            #pragma unroll
            for (int j=0;j<8;j++) {
                float rv = rs[bid*8+j];
                gb = fmaf(rv,rv,gb); db = fmaf(rv,wrow[j],db); mb += wrow[j];
            }
            st_f2_agent(pa + 2*bid, gb, db);
            st_f2_agent(pa + 512 + 2*bid, mb, 0.f);
            __hip_atomic_store(&flags[bid], iter+1, __ATOMIC_RELEASE, __HIP_MEMORY_SCOPE_AGENT);
        }
        // ---- poll all 256 flags (2 waves, 1 u64 each) ----
        if (tid < 128) {
            unsigned long long* f8 = (unsigned long long*)flags;
            int t = iter+1;
            for (;;) {
                unsigned long long v = __hip_atomic_load(&f8[tid], __ATOMIC_RELAXED, __HIP_MEMORY_SCOPE_AGENT);
                int ok = ((int)(v & 0xffffffffu) >= t) & ((int)(v>>32) >= t);
                if (__all(ok)) break;
                __builtin_amdgcn_s_sleep(1);
            }
        }
        __syncthreads();   // (B)
        // ---- overlap: gather own w chunks || load+reduce 256 partials ----
        float2 wa0 = ld_f2_agent(wb + ca), wa1 = ld_f2_agent(wb + ca + 2);
        float2 wb0 = ld_f2_agent(wb + cb), wb1 = ld_f2_agent(wb + cb + 2);
        float2 gd  = ld_f2_agent(pa + 2*tid);
        float2 mu2 = ld_f2_agent(pa + 512 + 2*tid);
        float g = gd.x, d = gd.y, m = mu2.x;
        #pragma unroll
        for (int off=1; off<64; off<<=1) {
            g += __shfl_xor(g,off); d += __shfl_xor(d,off); m += __shfl_xor(m,off);
        }
        if ((tid&63)==0) { int wv_=tid>>6; red[wv_*3+0]=g; red[wv_*3+1]=d; red[wv_*3+2]=m; }
        __syncthreads();   // (C)
        g = red[0]+red[3]+red[6]+red[9];
        d = red[1]+red[4]+red[7]+red[10];
        m = (red[2]+red[5]+red[8]+red[11]) * (1.f/NM);   // mean(w)
        // ---- identical scalar recurrences everywhere ----
        float b, a;
        if (iter == 0) { b=0.f; a=g/d; }
        else { b = g/gp; a = g/(d - b*g/ap); }
        gp=g; ap=a;
        // ---- p/x for own rows ----
        if (tid < 8) {
            pr = (iter==0) ? rrow : fmaf(b, pr, rrow);
            xr = (iter==0) ? a*pr : fmaf(a, pr, xr);
        }
        // ---- s and r chunk updates (w~ = w - m), write rs b128 ----
        float wv[8] = {wa0.x,wa0.y,wa1.x,wa1.y, wb0.x,wb0.y,wb1.x,wb1.y};
        float4 r4a = *(const float4*)(rs + ca);
        float4 r4b = *(const float4*)(rs + cb);
        float rr[8] = {r4a.x,r4a.y,r4a.z,r4a.w, r4b.x,r4b.y,r4b.z,r4b.w};
        float nr[8];
        #pragma unroll
        for (int j=0;j<4;j++) {
            float wt = wv[j] - m;
            float sv = (iter==0) ? wt : fmaf(b, sa[j], wt);
            sa[j]=sv; nr[j] = fmaf(-a, sv, rr[j]);
        }
        #pragma unroll
        for (int j=0;j<4;j++) {
            float wt = wv[4+j] - m;
            float sv = (iter==0) ? wt : fmaf(b, sb[j], wt);
            sb[j]=sv; nr[4+j] = fmaf(-a, sv, rr[4+j]);
        }
        *(float4*)(rs + ca) = make_float4(nr[0],nr[1],nr[2],nr[3]);
        *(float4*)(rs + cb) = make_float4(nr[4],nr[5],nr[6],nr[7]);
        __syncthreads();   // (D)
    }
    if (tid < 8) xg[bid*8+tid] = xr;
}

// -------- assemble output: metal -> x, electrolyte -> q --------
__global__ void k_out(const float* __restrict__ q, const int* __restrict__ an,
                      const float* __restrict__ wsf, float* __restrict__ out) {
    int i = blockIdx.x*256 + threadIdx.x;
    if (i >= NA) return;
    if (an[i]==METAL_Z) {
        int p = ((const int*)wsf)[OFF_POSOF/4 + i];
        out[i] = wsf[OFF_VEC/4 + p];
    } else {
        out[i] = q[i];
    }
}

extern "C" void kernel_launch(void* const* d_in, const int* in_sizes, int n_in,
                              void* d_out, int out_size, void* d_ws, size_t ws_size,
                              hipStream_t stream) {
    (void)in_sizes; (void)n_in; (void)out_size; (void)ws_size;
    const float* pos  = (const float*)d_in[0];
    const float* cell = (const float*)d_in[1];
    const float* q    = (const float*)d_in[2];
    const float* Jraw = (const float*)d_in[3];
    const int*   an   = (const int*)d_in[4];
    float* wsf = (float*)d_ws;
    float* out = (float*)d_out;

    k_setup<<<1, 256, 0, stream>>>(pos, cell, Jraw, an, wsf);
    k_ktab<<<KHP/256, 256, 0, stream>>>(wsf);
    k_srsi<<<KHP, 256, 0, stream>>>(q, an, wsf);
    k_field<<<dim3(62, 8), 256, 0, stream>>>(wsf);
    k_bfinal<<<1, 1024, 0, stream>>>(wsf);
    k_abuild<<<528, 256, 0, stream>>>(wsf);
    k_cg<<<NBLK_CG, 256, 0, stream>>>(wsf);
    k_out<<<NA/256, 256, 0, stream>>>(q, an, wsf, out);
}

// Round 12
// 2307.846 us; speedup vs baseline: 1.1995x; 1.0831x over previous
//
#include <hip/hip_runtime.h>
#include <math.h>

// MetalWallQEQ: reciprocal-space Ewald QEQ for metal-wall charges.
// Round 12: CG sync-domain shrink — 64 blocks x 1024 threads (was 256x256).
// CG is latency-bound (r11: 8.2us/iter, VALUBusy 4.6%, work ~1.5us); fewer
// barrier participants + smaller skew should roughly halve the round-trip.
// abuild unchanged (tail-bound, 528 blocks @ 2.06/CU -> 3-round CUs).

#define NA 4096
#define NM 2048
#define METAL_Z 79
#define KH 7812          // (25^3-1)/2 half k-points
#define KHP 7936         // padded to 62*128 (pad entries have w=0)
#define KW  (KHP/4)      // 1984 k per wave in abuild
#define NIT 150          // fixed CG iterations (graph-friendly)
#define NBLK_CG 64       // CG grid: 64 blocks x 1024 threads
#define CGT 1024
#define TWO_PI 6.283185307179586f

// ---- workspace byte offsets (total ~17.7 MB) ----
#define OFF_CONSTS 0        // [0..8]=invT(cell) row-major, [9]=pref=4pi/V, [10]=J
#define OFF_SUMS   256      // scratch
#define OFF_FLAGS  512      // 256 ints: CG barrier flags (zeroed per call)
#define OFF_KTAB   4096     // KHP * {gx,gy,gz,w} floats
#define OFF_FRAC   131072   // NA * {fx,fy,fz,0} fractional coords
#define OFF_MLIST  196608   // NM ints: metal position -> atom index
#define OFF_POSOF  204800   // NA ints: atom -> metal position (metal only)
#define OFF_SRW    221184   // KHP floats: w*Re S(k)
#define OFF_SIW    252928   // KHP floats: w*Im S(k)
#define OFF_BPART  284672   // 62*NM floats: field partials
#define OFF_B      792576   // NM floats (unused scratch)
#define OFF_VEC    800768   // x (2048), pad, r (at +4096)
#define OFF_WBUF   833536   // [parity][NM] w exchange (16KB)
#define OFF_PBUF   849920   // [parity][512 gd | 512 mu] partials (8KB)
#define OFF_A      917504   // NM*NM floats (A + J on diagonal)

__device__ __forceinline__ void sc_frac(float u, float& s, float& c) {
    // u is phase in REVOLUTIONS; v_sin/v_cos take revolutions directly.
    float t = u - floorf(u);
    s = __builtin_amdgcn_sinf(t);
    c = __builtin_amdgcn_cosf(t);
}

__device__ __forceinline__ float2 ld_f2_agent(const float* p) {
    unsigned long long v = __hip_atomic_load((unsigned long long*)p,
        __ATOMIC_RELAXED, __HIP_MEMORY_SCOPE_AGENT);
    union { unsigned long long u; float2 f; } cv; cv.u = v; return cv.f;
}
__device__ __forceinline__ void st_f2_agent(float* p, float a, float b) {
    union { unsigned long long u; float2 f; } cv; cv.f = make_float2(a, b);
    __hip_atomic_store((unsigned long long*)p, cv.u,
        __ATOMIC_RELAXED, __HIP_MEMORY_SCOPE_AGENT);
}

// -------- setup: cell inverse, fractional coords, metal scan, zero flags --------
__global__ void k_setup(const float* __restrict__ pos, const float* __restrict__ cell,
                        const float* __restrict__ Jraw, const int* __restrict__ an,
                        float* __restrict__ wsf) {
    int tid = threadIdx.x;
    __shared__ float sM[9];
    __shared__ int sc[256];
    if (tid == 0) {
        float c00=cell[0],c01=cell[1],c02=cell[2];
        float c10=cell[3],c11=cell[4],c12=cell[5];
        float c20=cell[6],c21=cell[7],c22=cell[8];
        float det = c00*(c11*c22-c12*c21) - c01*(c10*c22-c12*c20) + c02*(c10*c21-c11*c20);
        float i00 =  (c11*c22 - c12*c21)/det;
        float i01 = -(c01*c22 - c02*c21)/det;
        float i02 =  (c01*c12 - c02*c11)/det;
        float i10 = -(c10*c22 - c12*c20)/det;
        float i11 =  (c00*c22 - c02*c20)/det;
        float i12 = -(c00*c12 - c02*c10)/det;
        float i20 =  (c10*c21 - c11*c20)/det;
        float i21 = -(c00*c21 - c01*c20)/det;
        float i22 =  (c00*c11 - c01*c10)/det;
        sM[0]=i00; sM[1]=i10; sM[2]=i20;
        sM[3]=i01; sM[4]=i11; sM[5]=i21;
        sM[6]=i02; sM[7]=i12; sM[8]=i22;
        float vol = fabsf(det);
        for (int m=0;m<9;m++) wsf[OFF_CONSTS/4 + m] = sM[m];
        wsf[OFF_CONSTS/4 + 9]  = 12.566370614359172f / vol;   // 4pi/V
        wsf[OFF_CONSTS/4 + 10] = Jraw[0]*Jraw[0];
    }
    __syncthreads();
    float M0=sM[0],M1=sM[1],M2=sM[2],M3=sM[3],M4=sM[4],M5=sM[5],M6=sM[6],M7=sM[7],M8=sM[8];
    for (int i=tid; i<NA; i+=256) {
        float x=pos[3*i], y=pos[3*i+1], z=pos[3*i+2];
        wsf[OFF_FRAC/4 + 4*i+0] = M0*x + M1*y + M2*z;
        wsf[OFF_FRAC/4 + 4*i+1] = M3*x + M4*y + M5*z;
        wsf[OFF_FRAC/4 + 4*i+2] = M6*x + M7*y + M8*z;
        wsf[OFF_FRAC/4 + 4*i+3] = 0.f;
    }
    ((int*)wsf)[OFF_FLAGS/4 + tid] = 0;       // CG barrier flags
    if (tid < 4) wsf[OFF_SUMS/4 + tid] = 0.f;
    // metal prefix scan (deterministic ordering == np.where order)
    int cnt = 0;
    int base_i = tid*16;
    for (int j=0;j<16;j++) cnt += (an[base_i+j]==METAL_Z) ? 1 : 0;
    sc[tid] = cnt; __syncthreads();
    for (int off=1; off<256; off<<=1) {
        int v = (tid>=off) ? sc[tid-off] : 0;
        __syncthreads();
        sc[tid] += v;
        __syncthreads();
    }
    int base = sc[tid] - cnt;
    int* mlist = (int*)wsf + OFF_MLIST/4;
    int* posof = (int*)wsf + OFF_POSOF/4;
    for (int j=0;j<16;j++) {
        int i = base_i + j;
        if (an[i]==METAL_Z) { mlist[base] = i; posof[i] = base; base++; }
    }
}

// -------- k-table: integer triple + weight w = 2*pref*exp(-k2/2)/k2 --------
__global__ void k_ktab(float* __restrict__ wsf) {
    int k = blockIdx.x*256 + threadIdx.x;
    if (k >= KHP) return;
    float4 out;
    if (k < KH) {
        int gx = k/625 - 12;
        int rem = k%625;
        int gy = rem/25 - 12;
        int gz = rem%25 - 12;
        const float* M = wsf + OFF_CONSTS/4;
        float pref = M[9];
        float kx = TWO_PI*(gx*M[0] + gy*M[3] + gz*M[6]);
        float ky = TWO_PI*(gx*M[1] + gy*M[4] + gz*M[7]);
        float kz = TWO_PI*(gx*M[2] + gy*M[5] + gz*M[8]);
        float k2 = kx*kx + ky*ky + kz*kz;
        float kfac = __expf(-0.5f*k2) / k2;
        out = make_float4((float)gx, (float)gy, (float)gz, 2.f*pref*kfac);
    } else {
        out = make_float4(0.f, 0.f, 0.f, 0.f);
    }
    *(float4*)(wsf + OFF_KTAB/4 + 4*k) = out;
}

// -------- structure factors over electrolyte charges (metal q := 0) --------
__global__ void k_srsi(const float* __restrict__ q, const int* __restrict__ an,
                       float* __restrict__ wsf) {
    int k = blockIdx.x;
    int tid = threadIdx.x;
    float4 kt = *(const float4*)(wsf + OFF_KTAB/4 + 4*k);
    const float* frac = wsf + OFF_FRAC/4;
    float aR=0.f, aI=0.f;
    for (int i=tid; i<NA; i+=256) {
        float qa = (an[i]==METAL_Z) ? 0.f : q[i];
        float4 f = *(const float4*)(frac + 4*i);
        float u = kt.x*f.x + kt.y*f.y + kt.z*f.z;
        float s,c; sc_frac(u, s, c);
        aR += qa*c; aI += qa*s;
    }
    __shared__ float sR[256], sI[256];
    sR[tid]=aR; sI[tid]=aI; __syncthreads();
    for (int off=128; off>0; off>>=1) {
        if (tid<off) { sR[tid]+=sR[tid+off]; sI[tid]+=sI[tid+off]; }
        __syncthreads();
    }
    if (tid==0) {
        wsf[OFF_SRW/4 + k] = kt.w * sR[0];
        wsf[OFF_SIW/4 + k] = kt.w * sI[0];
    }
}

// -------- field at metal atoms (partial over k-chunks) --------
__global__ void k_field(float* __restrict__ wsf) {
    int kc = blockIdx.x;
    int m = blockIdx.y*256 + threadIdx.x;
    int atom = ((const int*)wsf)[OFF_MLIST/4 + m];
    float4 f = *(const float4*)(wsf + OFF_FRAC/4 + 4*atom);
    const float* kt = wsf + OFF_KTAB/4;
    const float* SrW = wsf + OFF_SRW/4;
    const float* SiW = wsf + OFF_SIW/4;
    float acc = 0.f;
    int k0 = kc*128;
    for (int j=0;j<128;j++) {
        int k = k0 + j;
        float4 g = *(const float4*)(kt + 4*k);
        float u = g.x*f.x + g.y*f.y + g.z*f.z;
        float s,c; sc_frac(u, s, c);
        acc = fmaf(c, SrW[k], fmaf(s, SiW[k], acc));
    }
    wsf[OFF_BPART/4 + kc*NM + m] = acc;
}

// -------- r0 = P*B = B - mean(B); B = -field (1 block x 1024) --------
__global__ void k_bfinal(float* __restrict__ wsf) {
    int tid = threadIdx.x;
    float b0 = 0.f, b1 = 0.f;
    for (int kc=0;kc<62;kc++) {
        b0 += wsf[OFF_BPART/4 + kc*NM + tid];
        b1 += wsf[OFF_BPART/4 + kc*NM + 1024 + tid];
    }
    b0 = -b0; b1 = -b1;
    __shared__ float sb[1024];
    sb[tid] = b0 + b1; __syncthreads();
    for (int off=512; off>0; off>>=1) {
        if (tid<off) sb[tid] += sb[tid+off];
        __syncthreads();
    }
    float mean = sb[0] * (1.f/NM);
    float* r = wsf + OFF_VEC/4 + 4096;
    r[tid]        = b0 - mean;
    r[1024 + tid] = b1 - mean;
}

// -------- A build: triangular 64x64 tiles, per-wave K-split, 8x8 acc --------
// (unchanged from round 11)
__launch_bounds__(256)
__global__ void k_abuild(float* __restrict__ wsf) {
    __shared__ float S[8704];      // [0..8192) staging/reduce, [8192..) fi,fj
    int tid = threadIdx.x;
    int bid = blockIdx.x;
    int bi = (int)((sqrtf(8.f*bid + 1.f) - 1.f)*0.5f);
    while ((bi+1)*(bi+2)/2 <= bid) bi++;
    while (bi*(bi+1)/2 > bid) bi--;
    int bj = bid - bi*(bi+1)/2;

    const int* mlist = (const int*)wsf + OFF_MLIST/4;
    const float* frac = wsf + OFF_FRAC/4;
    const float* ktab = wsf + OFF_KTAB/4;
    float J = wsf[OFF_CONSTS/4 + 10];

    float4* fi = (float4*)(S + 8192);
    float4* fj = (float4*)(S + 8448);
    if (tid < 64)        fi[tid]    = *(const float4*)(frac + 4*mlist[bi*64 + tid]);
    else if (tid < 128)  fj[tid-64] = *(const float4*)(frac + 4*mlist[bj*64 + (tid-64)]);
    __syncthreads();

    int w = tid >> 6, lane = tid & 63;
    int ty = lane >> 3, tx = lane & 7;
    float4 fir = fi[lane], fjr = fj[lane];
    float* cw = S + w*2048;        // wave-private staging quadrant
    float* sw = cw + 512;
    float* cj = cw + 1024;
    float* sj = cw + 1536;

    float acc[8][8] = {};

    for (int k0 = w*KW; k0 < (w+1)*KW; k0 += 8) {
        #pragma unroll
        for (int kk=0; kk<8; kk++) {
            float4 kt = *(const float4*)(ktab + 4*(k0+kk));
            float u = kt.x*fir.x + kt.y*fir.y + kt.z*fir.z;
            float s,c; sc_frac(u, s, c);
            cw[kk*64+lane] = kt.w*c; sw[kk*64+lane] = kt.w*s;
            u = kt.x*fjr.x + kt.y*fjr.y + kt.z*fjr.z;
            sc_frac(u, s, c);
            cj[kk*64+lane] = c; sj[kk*64+lane] = s;
        }
        // wave-private staging: no cross-wave barrier needed
        #pragma unroll 2
        for (int kk=0; kk<8; kk++) {
            float4 a0 = *(const float4*)(cw + kk*64 + ty*8);
            float4 a1 = *(const float4*)(cw + kk*64 + ty*8 + 4);
            float4 s0 = *(const float4*)(sw + kk*64 + ty*8);
            float4 s1 = *(const float4*)(sw + kk*64 + ty*8 + 4);
            float4 b0 = *(const float4*)(cj + kk*64 + tx*8);
            float4 b1 = *(const float4*)(cj + kk*64 + tx*8 + 4);
            float4 t0 = *(const float4*)(sj + kk*64 + tx*8);
            float4 t1 = *(const float4*)(sj + kk*64 + tx*8 + 4);
            float aC[8] = {a0.x,a0.y,a0.z,a0.w, a1.x,a1.y,a1.z,a1.w};
            float aS[8] = {s0.x,s0.y,s0.z,s0.w, s1.x,s1.y,s1.z,s1.w};
            float bC[8] = {b0.x,b0.y,b0.z,b0.w, b1.x,b1.y,b1.z,b1.w};
            float bS[8] = {t0.x,t0.y,t0.z,t0.w, t1.x,t1.y,t1.z,t1.w};
            #pragma unroll
            for (int a=0;a<8;a++)
                #pragma unroll
                for (int b=0;b<8;b++)
                    acc[a][b] = fmaf(aC[a], bC[b], fmaf(aS[a], bS[b], acc[a][b]));
        }
    }

    // ---- deterministic pairwise reduce: (w0+w1) + (w2+w3) ----
    __syncthreads();
    if (w==1) {
        #pragma unroll
        for (int i=0;i<64;i++) S[i*64+lane] = acc[i>>3][i&7];
    } else if (w==3) {
        #pragma unroll
        for (int i=0;i<64;i++) S[4096 + i*64+lane] = acc[i>>3][i&7];
    }
    __syncthreads();
    if (w==0) {
        #pragma unroll
        for (int i=0;i<64;i++) acc[i>>3][i&7] += S[i*64+lane];
    } else if (w==2) {
        #pragma unroll
        for (int i=0;i<64;i++) acc[i>>3][i&7] += S[4096 + i*64+lane];
    }
    __syncthreads();
    if (w==2) {
        #pragma unroll
        for (int i=0;i<64;i++) S[i*64+lane] = acc[i>>3][i&7];
    }
    __syncthreads();
    if (w==0) {
        #pragma unroll
        for (int i=0;i<64;i++) acc[i>>3][i&7] += S[i*64+lane];
        float* A = wsf + OFF_A/4;
        int gi0 = bi*64 + ty*8, gj0 = bj*64 + tx*8;
        #pragma unroll
        for (int a=0;a<8;a++) {
            int gi = gi0 + a;
            #pragma unroll
            for (int b=0;b<8;b++) {
                int gj = gj0 + b;
                float v = acc[a][b] + ((gi==gj) ? J : 0.f);
                A[gi*NM + gj] = v;
                A[gj*NM + gi] = v;
            }
        }
    }
}

// -------- persistent projected CG: 64 blocks x 1024 threads --------
// Block owns rows [bid*32,bid*32+32) (32 lanes/row). Thread owns one float2
// chunk {2t,2t+1} of the full vectors. r replicated in LDS per block.
// 1 flag barrier/iter; 64 flags polled by wave 0 (32 u64).
__launch_bounds__(CGT, 1)
__global__ void k_cg(float* __restrict__ wsf) {
    const float* A = wsf + OFF_A/4;
    float* vec = wsf + OFF_VEC/4;
    float* xg = vec;                       // solution q (metal order)
    const float* rg = vec + 4096;          // initial residual r0 = P*B
    int* flags = (int*)wsf + OFF_FLAGS/4;
    float* wbuf = wsf + OFF_WBUF/4;        // [parity][NM]
    float* pbuf = wsf + OFF_PBUF/4;        // [parity][512 gd | 512 mu]

    __shared__ float rs[NM];
    __shared__ float wrow[32];
    __shared__ float red[4];

    int tid = threadIdx.x, bid = blockIdx.x;
    int rl = tid >> 5, lane = tid & 31;    // 32 rows x 32 lanes
    int row = bid*32 + rl;
    const float* Arow = A + (size_t)row*NM;
    int ca = 2*tid;                        // own float2 chunk

    ((float2*)rs)[tid] = ((const float2*)rg)[tid];
    __syncthreads();

    float s0=0.f, s1=0.f;                  // own s chunk
    float pr=0.f, xr=0.f;                  // own-row p/x (tid<32)
    float gp=1.f, ap=1.f;

    for (int iter=0; iter<NIT; ++iter) {
        int par = iter & 1;
        float* wb = wbuf + par*NM;
        float* pa = pbuf + par*1024;
        // ---- w_own = A_own * r, 32 lanes per row ----
        float acc=0.f;
        #pragma unroll 8
        for (int c=lane*4; c<NM; c+=128) {
            float4 a = *(const float4*)(Arow + c);
            float4 u = *(const float4*)(rs + c);
            acc += a.x*u.x + a.y*u.y + a.z*u.z + a.w*u.w;
        }
        #pragma unroll
        for (int off=1; off<32; off<<=1) acc += __shfl_xor(acc, off);
        if (lane == 0) {
            wrow[rl] = acc;
            __hip_atomic_store(wb + row, acc, __ATOMIC_RELAXED, __HIP_MEMORY_SCOPE_AGENT);
        }
        float rrow = (tid<32) ? rs[bid*32+tid] : 0.f;   // current own-row r
        __syncthreads();   // (A) wrow ready; all w stores drained
        // ---- pre-barrier block partials (own 32 rows) + flag release ----
        if (tid == 0) {
            float gb=0.f, db=0.f, mb=0.f;
            #pragma unroll
            for (int j=0;j<32;j++) {
                float rv = rs[bid*32+j];
                gb = fmaf(rv,rv,gb); db = fmaf(rv,wrow[j],db); mb += wrow[j];
            }
            st_f2_agent(pa + 2*bid, gb, db);
            st_f2_agent(pa + 512 + 2*bid, mb, 0.f);
            __hip_atomic_store(&flags[bid], iter+1, __ATOMIC_RELEASE, __HIP_MEMORY_SCOPE_AGENT);
        }
        // ---- poll 64 flags (wave 0: 32 u64 on lanes 0..31) ----
        if (tid < 64) {
            unsigned long long* f8 = (unsigned long long*)flags;
            int t = iter+1;
            for (;;) {
                int ok = 1;
                if (tid < 32) {
                    unsigned long long v = __hip_atomic_load(&f8[tid], __ATOMIC_RELAXED, __HIP_MEMORY_SCOPE_AGENT);
                    ok = ((int)(v & 0xffffffffu) >= t) & ((int)(v>>32) >= t);
                }
                if (__all(ok)) break;
                __builtin_amdgcn_s_sleep(1);
            }
        }
        __syncthreads();   // (B)
        // ---- overlap: gather own w chunk || wave-0 reduces 64 partials ----
        float2 wv2 = ld_f2_agent(wb + ca);
        if (tid < 64) {
            float2 gd  = ld_f2_agent(pa + 2*tid);
            float2 mu2 = ld_f2_agent(pa + 512 + 2*tid);
            float g = gd.x, d = gd.y, m = mu2.x;
            #pragma unroll
            for (int off=1; off<64; off<<=1) {
                g += __shfl_xor(g,off); d += __shfl_xor(d,off); m += __shfl_xor(m,off);
            }
            if (tid==0) { red[0]=g; red[1]=d; red[2]=m; }
        }
        __syncthreads();   // (C)
        float g = red[0], d = red[1];
        float m = red[2] * (1.f/NM);       // mean(w)
        // ---- identical scalar recurrences everywhere ----
        float b, a;
        if (iter == 0) { b=0.f; a=g/d; }
        else { b = g/gp; a = g/(d - b*g/ap); }
        gp=g; ap=a;
        // ---- p/x for own rows ----
        if (tid < 32) {
            pr = (iter==0) ? rrow : fmaf(b, pr, rrow);
            xr = (iter==0) ? a*pr : fmaf(a, pr, xr);
        }
        // ---- s and r chunk updates (w~ = w - m), float2 write ----
        float wt0 = wv2.x - m, wt1 = wv2.y - m;
        s0 = (iter==0) ? wt0 : fmaf(b, s0, wt0);
        s1 = (iter==0) ? wt1 : fmaf(b, s1, wt1);
        float2 rv2 = *(const float2*)(rs + ca);
        *(float2*)(rs + ca) = make_float2(fmaf(-a, s0, rv2.x), fmaf(-a, s1, rv2.y));
        __syncthreads();   // (D)
    }
    if (tid < 32) xg[bid*32+tid] = xr;
}

// -------- assemble output: metal -> x, electrolyte -> q --------
__global__ void k_out(const float* __restrict__ q, const int* __restrict__ an,
                      const float* __restrict__ wsf, float* __restrict__ out) {
    int i = blockIdx.x*256 + threadIdx.x;
    if (i >= NA) return;
    if (an[i]==METAL_Z) {
        int p = ((const int*)wsf)[OFF_POSOF/4 + i];
        out[i] = wsf[OFF_VEC/4 + p];
    } else {
        out[i] = q[i];
    }
}

extern "C" void kernel_launch(void* const* d_in, const int* in_sizes, int n_in,
                              void* d_out, int out_size, void* d_ws, size_t ws_size,
                              hipStream_t stream) {
    (void)in_sizes; (void)n_in; (void)out_size; (void)ws_size;
    const float* pos  = (const float*)d_in[0];
    const float* cell = (const float*)d_in[1];
    const float* q    = (const float*)d_in[2];
    const float* Jraw = (const float*)d_in[3];
    const int*   an   = (const int*)d_in[4];
    float* wsf = (float*)d_ws;
    float* out = (float*)d_out;

    k_setup<<<1, 256, 0, stream>>>(pos, cell, Jraw, an, wsf);
    k_ktab<<<KHP/256, 256, 0, stream>>>(wsf);
    k_srsi<<<KHP, 256, 0, stream>>>(q, an, wsf);
    k_field<<<dim3(62, 8), 256, 0, stream>>>(wsf);
    k_bfinal<<<1, 1024, 0, stream>>>(wsf);
    k_abuild<<<528, 256, 0, stream>>>(wsf);
    k_cg<<<NBLK_CG, CGT, 0, stream>>>(wsf);
    k_out<<<NA/256, 256, 0, stream>>>(q, an, wsf, out);
}

// Round 14
// 2111.477 us; speedup vs baseline: 1.3111x; 1.0930x over previous
//
#include <hip/hip_runtime.h>
#include <math.h>

// MetalWallQEQ: reciprocal-space Ewald QEQ for metal-wall charges.
// Round 13 (resubmit; r13 bench was an infra failure): MFMA A-build.
// A = G.G^T with G[i][2k]=sqrt(w)cos(k.ri), [2k+1]=sqrt(w)sin(k.ri);
// split-bf16 (hi+lo, ~2^-18 rel) via 3x mfma_f32_16x16x32_bf16 into fp32 acc.
// 64x64 tiles, KC=32 k-chunks in LDS (padded rows, 38.9KB -> 4 blocks/CU),
// 2x2 fragments/wave. CG unchanged (r12: 64x1024 projected CG).

#define NA 4096
#define NM 2048
#define METAL_Z 79
#define KH 7812          // (25^3-1)/2 half k-points
#define KHP 7936         // padded to 62*128 (pad entries have w=0)
#define NIT 150          // fixed CG iterations (graph-friendly)
#define NBLK_CG 64       // CG grid: 64 blocks x 1024 threads
#define CGT 1024
#define TWO_PI 6.283185307179586f

// ---- workspace byte offsets (total ~17.7 MB) ----
#define OFF_CONSTS 0        // [0..8]=invT(cell) row-major, [9]=pref=4pi/V, [10]=J
#define OFF_SUMS   256      // scratch
#define OFF_FLAGS  512      // 256 ints: CG barrier flags (zeroed per call)
#define OFF_KTAB   4096     // KHP * {gx,gy,gz,w} floats
#define OFF_FRAC   131072   // NA * {fx,fy,fz,0} fractional coords
#define OFF_MLIST  196608   // NM ints: metal position -> atom index
#define OFF_POSOF  204800   // NA ints: atom -> metal position (metal only)
#define OFF_SRW    221184   // KHP floats: w*Re S(k)
#define OFF_SIW    252928   // KHP floats: w*Im S(k)
#define OFF_BPART  284672   // 62*NM floats: field partials
#define OFF_B      792576   // NM floats (unused scratch)
#define OFF_VEC    800768   // x (2048), pad, r (at +4096)
#define OFF_WBUF   833536   // [parity][NM] w exchange (16KB)
#define OFF_PBUF   849920   // [parity][512 gd | 512 mu] partials (8KB)
#define OFF_A      917504   // NM*NM floats (A + J on diagonal)

typedef short bf16x8 __attribute__((ext_vector_type(8)));
typedef float f32x4 __attribute__((ext_vector_type(4)));

__device__ __forceinline__ void sc_frac(float u, float& s, float& c) {
    // u is phase in REVOLUTIONS; v_sin/v_cos take revolutions directly.
    float t = u - floorf(u);
    s = __builtin_amdgcn_sinf(t);
    c = __builtin_amdgcn_cosf(t);
}

__device__ __forceinline__ unsigned short bf16rne(float x) {
    unsigned u = __float_as_uint(x);
    unsigned r = u + 0x7fffu + ((u >> 16) & 1u);
    return (unsigned short)(r >> 16);
}

__device__ __forceinline__ float2 ld_f2_agent(const float* p) {
    unsigned long long v = __hip_atomic_load((unsigned long long*)p,
        __ATOMIC_RELAXED, __HIP_MEMORY_SCOPE_AGENT);
    union { unsigned long long u; float2 f; } cv; cv.u = v; return cv.f;
}
__device__ __forceinline__ void st_f2_agent(float* p, float a, float b) {
    union { unsigned long long u; float2 f; } cv; cv.f = make_float2(a, b);
    __hip_atomic_store((unsigned long long*)p, cv.u,
        __ATOMIC_RELAXED, __HIP_MEMORY_SCOPE_AGENT);
}

// -------- setup: cell inverse, fractional coords, metal scan, zero flags --------
__global__ void k_setup(const float* __restrict__ pos, const float* __restrict__ cell,
                        const float* __restrict__ Jraw, const int* __restrict__ an,
                        float* __restrict__ wsf) {
    int tid = threadIdx.x;
    __shared__ float sM[9];
    __shared__ int sc[256];
    if (tid == 0) {
        float c00=cell[0],c01=cell[1],c02=cell[2];
        float c10=cell[3],c11=cell[4],c12=cell[5];
        float c20=cell[6],c21=cell[7],c22=cell[8];
        float det = c00*(c11*c22-c12*c21) - c01*(c10*c22-c12*c20) + c02*(c10*c21-c11*c20);
        float i00 =  (c11*c22 - c12*c21)/det;
        float i01 = -(c01*c22 - c02*c21)/det;
        float i02 =  (c01*c12 - c02*c11)/det;
        float i10 = -(c10*c22 - c12*c20)/det;
        float i11 =  (c00*c22 - c02*c20)/det;
        float i12 = -(c00*c12 - c02*c10)/det;
        float i20 =  (c10*c21 - c11*c20)/det;
        float i21 = -(c00*c21 - c01*c20)/det;
        float i22 =  (c00*c11 - c01*c10)/det;
        sM[0]=i00; sM[1]=i10; sM[2]=i20;
        sM[3]=i01; sM[4]=i11; sM[5]=i21;
        sM[6]=i02; sM[7]=i12; sM[8]=i22;
        float vol = fabsf(det);
        for (int m=0;m<9;m++) wsf[OFF_CONSTS/4 + m] = sM[m];
        wsf[OFF_CONSTS/4 + 9]  = 12.566370614359172f / vol;   // 4pi/V
        wsf[OFF_CONSTS/4 + 10] = Jraw[0]*Jraw[0];
    }
    __syncthreads();
    float M0=sM[0],M1=sM[1],M2=sM[2],M3=sM[3],M4=sM[4],M5=sM[5],M6=sM[6],M7=sM[7],M8=sM[8];
    for (int i=tid; i<NA; i+=256) {
        float x=pos[3*i], y=pos[3*i+1], z=pos[3*i+2];
        wsf[OFF_FRAC/4 + 4*i+0] = M0*x + M1*y + M2*z;
        wsf[OFF_FRAC/4 + 4*i+1] = M3*x + M4*y + M5*z;
        wsf[OFF_FRAC/4 + 4*i+2] = M6*x + M7*y + M8*z;
        wsf[OFF_FRAC/4 + 4*i+3] = 0.f;
    }
    ((int*)wsf)[OFF_FLAGS/4 + tid] = 0;       // CG barrier flags
    if (tid < 4) wsf[OFF_SUMS/4 + tid] = 0.f;
    // metal prefix scan (deterministic ordering == np.where order)
    int cnt = 0;
    int base_i = tid*16;
    for (int j=0;j<16;j++) cnt += (an[base_i+j]==METAL_Z) ? 1 : 0;
    sc[tid] = cnt; __syncthreads();
    for (int off=1; off<256; off<<=1) {
        int v = (tid>=off) ? sc[tid-off] : 0;
        __syncthreads();
        sc[tid] += v;
        __syncthreads();
    }
    int base = sc[tid] - cnt;
    int* mlist = (int*)wsf + OFF_MLIST/4;
    int* posof = (int*)wsf + OFF_POSOF/4;
    for (int j=0;j<16;j++) {
        int i = base_i + j;
        if (an[i]==METAL_Z) { mlist[base] = i; posof[i] = base; base++; }
    }
}

// -------- k-table: integer triple + weight w = 2*pref*exp(-k2/2)/k2 --------
__global__ void k_ktab(float* __restrict__ wsf) {
    int k = blockIdx.x*256 + threadIdx.x;
    if (k >= KHP) return;
    float4 out;
    if (k < KH) {
        int gx = k/625 - 12;
        int rem = k%625;
        int gy = rem/25 - 12;
        int gz = rem%25 - 12;
        const float* M = wsf + OFF_CONSTS/4;
        float pref = M[9];
        float kx = TWO_PI*(gx*M[0] + gy*M[3] + gz*M[6]);
        float ky = TWO_PI*(gx*M[1] + gy*M[4] + gz*M[7]);
        float kz = TWO_PI*(gx*M[2] + gy*M[5] + gz*M[8]);
        float k2 = kx*kx + ky*ky + kz*kz;
        float kfac = __expf(-0.5f*k2) / k2;
        out = make_float4((float)gx, (float)gy, (float)gz, 2.f*pref*kfac);
    } else {
        out = make_float4(0.f, 0.f, 0.f, 0.f);
    }
    *(float4*)(wsf + OFF_KTAB/4 + 4*k) = out;
}

// -------- structure factors over electrolyte charges (metal q := 0) --------
__global__ void k_srsi(const float* __restrict__ q, const int* __restrict__ an,
                       float* __restrict__ wsf) {
    int k = blockIdx.x;
    int tid = threadIdx.x;
    float4 kt = *(const float4*)(wsf + OFF_KTAB/4 + 4*k);
    const float* frac = wsf + OFF_FRAC/4;
    float aR=0.f, aI=0.f;
    for (int i=tid; i<NA; i+=256) {
        float qa = (an[i]==METAL_Z) ? 0.f : q[i];
        float4 f = *(const float4*)(frac + 4*i);
        float u = kt.x*f.x + kt.y*f.y + kt.z*f.z;
        float s,c; sc_frac(u, s, c);
        aR += qa*c; aI += qa*s;
    }
    __shared__ float sR[256], sI[256];
    sR[tid]=aR; sI[tid]=aI; __syncthreads();
    for (int off=128; off>0; off>>=1) {
        if (tid<off) { sR[tid]+=sR[tid+off]; sI[tid]+=sI[tid+off]; }
        __syncthreads();
    }
    if (tid==0) {
        wsf[OFF_SRW/4 + k] = kt.w * sR[0];
        wsf[OFF_SIW/4 + k] = kt.w * sI[0];
    }
}

// -------- field at metal atoms (partial over k-chunks) --------
__global__ void k_field(float* __restrict__ wsf) {
    int kc = blockIdx.x;
    int m = blockIdx.y*256 + threadIdx.x;
    int atom = ((const int*)wsf)[OFF_MLIST/4 + m];
    float4 f = *(const float4*)(wsf + OFF_FRAC/4 + 4*atom);
    const float* kt = wsf + OFF_KTAB/4;
    const float* SrW = wsf + OFF_SRW/4;
    const float* SiW = wsf + OFF_SIW/4;
    float acc = 0.f;
    int k0 = kc*128;
    for (int j=0;j<128;j++) {
        int k = k0 + j;
        float4 g = *(const float4*)(kt + 4*k);
        float u = g.x*f.x + g.y*f.y + g.z*f.z;
        float s,c; sc_frac(u, s, c);
        acc = fmaf(c, SrW[k], fmaf(s, SiW[k], acc));
    }
    wsf[OFF_BPART/4 + kc*NM + m] = acc;
}

// -------- r0 = P*B = B - mean(B); B = -field (1 block x 1024) --------
__global__ void k_bfinal(float* __restrict__ wsf) {
    int tid = threadIdx.x;
    float b0 = 0.f, b1 = 0.f;
    for (int kc=0;kc<62;kc++) {
        b0 += wsf[OFF_BPART/4 + kc*NM + tid];
        b1 += wsf[OFF_BPART/4 + kc*NM + 1024 + tid];
    }
    b0 = -b0; b1 = -b1;
    __shared__ float sb[1024];
    sb[tid] = b0 + b1; __syncthreads();
    for (int off=512; off>0; off>>=1) {
        if (tid<off) sb[tid] += sb[tid+off];
        __syncthreads();
    }
    float mean = sb[0] * (1.f/NM);
    float* r = wsf + OFF_VEC/4 + 4096;
    r[tid]        = b0 - mean;
    r[1024 + tid] = b1 - mean;
}

// -------- A build: MFMA split-bf16 Gram, triangular 64x64 tiles --------
// G[a][2k]=sqrt(w)cos(k.ra), G[a][2k+1]=sqrt(w)sin(k.ra); A = G.G^T.
// Per chunk: stage 32 k (64 bf16 cols) of U=G(tile bi) and V=G(tile bj) as
// hi/lo bf16 into padded LDS rows [64][72]; 3 MFMA per fragment-k-step:
// UhVh + UhVl + UlVh. Wave w: 2x2 fragment block. Diagonal tiles: V:=U.
__launch_bounds__(256)
__global__ void k_abuild(float* __restrict__ wsf) {
    __shared__ unsigned short UH[64*72], UL[64*72], VH[64*72], VL[64*72];
    __shared__ float4 FIJ[128];
    int tid = threadIdx.x;
    int bid = blockIdx.x;
    int bi = (int)((sqrtf(8.f*bid + 1.f) - 1.f)*0.5f);
    while ((bi+1)*(bi+2)/2 <= bid) bi++;
    while (bi*(bi+1)/2 > bid) bi--;
    int bj = bid - bi*(bi+1)/2;
    bool diag = (bi == bj);

    const int* mlist = (const int*)wsf + OFF_MLIST/4;
    const float* frac = wsf + OFF_FRAC/4;
    const float* ktab = wsf + OFF_KTAB/4;
    float J = wsf[OFF_CONSTS/4 + 10];

    if (tid < 64)        FIJ[tid]    = *(const float4*)(frac + 4*mlist[bi*64 + tid]);
    else if (tid < 128)  FIJ[tid]    = *(const float4*)(frac + 4*mlist[bj*64 + (tid-64)]);
    __syncthreads();

    int a = tid >> 2;              // staging atom 0..63
    int kq = tid & 3;
    float4 fia = FIJ[a];
    float4 fja = FIJ[64 + a];
    unsigned* uhw = (unsigned*)&UH[a*72];
    unsigned* ulw = (unsigned*)&UL[a*72];
    unsigned* vhw = (unsigned*)&VH[a*72];
    unsigned* vlw = (unsigned*)&VL[a*72];

    int lane = tid & 63, w = tid >> 6;
    int fr0 = (w & 1) * 2, fc0 = (w >> 1) * 2;
    int lr = lane & 15, lkb = (lane >> 4) * 8;
    int ra0 = (fr0*16 + lr)*72, ra1 = ra0 + 16*72;
    int rb0 = (fc0*16 + lr)*72, rb1 = rb0 + 16*72;
    const unsigned short* VHp = diag ? UH : VH;
    const unsigned short* VLp = diag ? UL : VL;

    f32x4 acc00 = {0.f,0.f,0.f,0.f}, acc01 = acc00, acc10 = acc00, acc11 = acc00;

    for (int kbase = 0; kbase < KHP; kbase += 32) {
        __syncthreads();           // prior MFMA reads done before overwrite
        #pragma unroll
        for (int j = 0; j < 8; j++) {
            int kl = kq*8 + j;
            float4 kt = *(const float4*)(ktab + 4*(kbase + kl));
            float rw = sqrtf(kt.w);
            float u = kt.x*fia.x + kt.y*fia.y + kt.z*fia.z;
            float s, c; sc_frac(u, s, c);
            float gc = rw*c, gs = rw*s;
            unsigned short hc = bf16rne(gc);
            float hcf = __uint_as_float(((unsigned)hc) << 16);
            unsigned short lc = bf16rne(gc - hcf);
            unsigned short hs = bf16rne(gs);
            float hsf = __uint_as_float(((unsigned)hs) << 16);
            unsigned short ls = bf16rne(gs - hsf);
            uhw[kl] = (unsigned)hc | ((unsigned)hs << 16);
            ulw[kl] = (unsigned)lc | ((unsigned)ls << 16);
            if (!diag) {
                u = kt.x*fja.x + kt.y*fja.y + kt.z*fja.z;
                sc_frac(u, s, c);
                gc = rw*c; gs = rw*s;
                hc = bf16rne(gc);
                hcf = __uint_as_float(((unsigned)hc) << 16);
                lc = bf16rne(gc - hcf);
                hs = bf16rne(gs);
                hsf = __uint_as_float(((unsigned)hs) << 16);
                ls = bf16rne(gs - hsf);
                vhw[kl] = (unsigned)hc | ((unsigned)hs << 16);
                vlw[kl] = (unsigned)lc | ((unsigned)ls << 16);
            }
        }
        __syncthreads();
        #pragma unroll
        for (int ks = 0; ks < 2; ks++) {
            int co = ks*32 + lkb;
            bf16x8 ah0 = *(const bf16x8*)&UH[ra0 + co];
            bf16x8 al0 = *(const bf16x8*)&UL[ra0 + co];
            bf16x8 ah1 = *(const bf16x8*)&UH[ra1 + co];
            bf16x8 al1 = *(const bf16x8*)&UL[ra1 + co];
            bf16x8 bh0 = *(const bf16x8*)&VHp[rb0 + co];
            bf16x8 bl0 = *(const bf16x8*)&VLp[rb0 + co];
            bf16x8 bh1 = *(const bf16x8*)&VHp[rb1 + co];
            bf16x8 bl1 = *(const bf16x8*)&VLp[rb1 + co];
            acc00 = __builtin_amdgcn_mfma_f32_16x16x32_bf16(ah0, bh0, acc00, 0,0,0);
            acc00 = __builtin_amdgcn_mfma_f32_16x16x32_bf16(ah0, bl0, acc00, 0,0,0);
            acc00 = __builtin_amdgcn_mfma_f32_16x16x32_bf16(al0, bh0, acc00, 0,0,0);
            acc01 = __builtin_amdgcn_mfma_f32_16x16x32_bf16(ah0, bh1, acc01, 0,0,0);
            acc01 = __builtin_amdgcn_mfma_f32_16x16x32_bf16(ah0, bl1, acc01, 0,0,0);
            acc01 = __builtin_amdgcn_mfma_f32_16x16x32_bf16(al0, bh1, acc01, 0,0,0);
            acc10 = __builtin_amdgcn_mfma_f32_16x16x32_bf16(ah1, bh0, acc10, 0,0,0);
            acc10 = __builtin_amdgcn_mfma_f32_16x16x32_bf16(ah1, bl0, acc10, 0,0,0);
            acc10 = __builtin_amdgcn_mfma_f32_16x16x32_bf16(al1, bh0, acc10, 0,0,0);
            acc11 = __builtin_amdgcn_mfma_f32_16x16x32_bf16(ah1, bh1, acc11, 0,0,0);
            acc11 = __builtin_amdgcn_mfma_f32_16x16x32_bf16(ah1, bl1, acc11, 0,0,0);
            acc11 = __builtin_amdgcn_mfma_f32_16x16x32_bf16(al1, bh1, acc11, 0,0,0);
        }
    }

    // ---- write C fragments: col=lane&15, row=(lane>>4)*4+reg (m89 layout) ----
    float* A = wsf + OFF_A/4;
    int rbase = (lane >> 4) * 4;
    #pragma unroll
    for (int fi_ = 0; fi_ < 2; fi_++) {
        int fr = fr0 + fi_;
        #pragma unroll
        for (int fj_ = 0; fj_ < 2; fj_++) {
            int fc = fc0 + fj_;
            int gj = bj*64 + fc*16 + lr;
            f32x4 av = (fi_==0) ? ((fj_==0) ? acc00 : acc01)
                                : ((fj_==0) ? acc10 : acc11);
            #pragma unroll
            for (int r = 0; r < 4; r++) {
                int gi = bi*64 + fr*16 + rbase + r;
                float v = av[r] + ((gi == gj) ? J : 0.f);
                A[(size_t)gi*NM + gj] = v;
                A[(size_t)gj*NM + gi] = v;
            }
        }
    }
}

// -------- persistent projected CG: 64 blocks x 1024 threads (r12) --------
__launch_bounds__(CGT, 1)
__global__ void k_cg(float* __restrict__ wsf) {
    const float* A = wsf + OFF_A/4;
    float* vec = wsf + OFF_VEC/4;
    float* xg = vec;                       // solution q (metal order)
    const float* rg = vec + 4096;          // initial residual r0 = P*B
    int* flags = (int*)wsf + OFF_FLAGS/4;
    float* wbuf = wsf + OFF_WBUF/4;        // [parity][NM]
    float* pbuf = wsf + OFF_PBUF/4;        // [parity][512 gd | 512 mu]

    __shared__ float rs[NM];
    __shared__ float wrow[32];
    __shared__ float red[4];

    int tid = threadIdx.x, bid = blockIdx.x;
    int rl = tid >> 5, lane = tid & 31;    // 32 rows x 32 lanes
    int row = bid*32 + rl;
    const float* Arow = A + (size_t)row*NM;
    int ca = 2*tid;                        // own float2 chunk

    ((float2*)rs)[tid] = ((const float2*)rg)[tid];
    __syncthreads();

    float s0=0.f, s1=0.f;                  // own s chunk
    float pr=0.f, xr=0.f;                  // own-row p/x (tid<32)
    float gp=1.f, ap=1.f;

    for (int iter=0; iter<NIT; ++iter) {
        int par = iter & 1;
        float* wb = wbuf + par*NM;
        float* pa = pbuf + par*1024;
        // ---- w_own = A_own * r, 32 lanes per row ----
        float acc=0.f;
        #pragma unroll 8
        for (int c=lane*4; c<NM; c+=128) {
            float4 a = *(const float4*)(Arow + c);
            float4 u = *(const float4*)(rs + c);
            acc += a.x*u.x + a.y*u.y + a.z*u.z + a.w*u.w;
        }
        #pragma unroll
        for (int off=1; off<32; off<<=1) acc += __shfl_xor(acc, off);
        if (lane == 0) {
            wrow[rl] = acc;
            __hip_atomic_store(wb + row, acc, __ATOMIC_RELAXED, __HIP_MEMORY_SCOPE_AGENT);
        }
        float rrow = (tid<32) ? rs[bid*32+tid] : 0.f;   // current own-row r
        __syncthreads();   // (A) wrow ready; all w stores drained
        // ---- pre-barrier block partials (own 32 rows) + flag release ----
        if (tid == 0) {
            float gb=0.f, db=0.f, mb=0.f;
            #pragma unroll
            for (int j=0;j<32;j++) {
                float rv = rs[bid*32+j];
                gb = fmaf(rv,rv,gb); db = fmaf(rv,wrow[j],db); mb += wrow[j];
            }
            st_f2_agent(pa + 2*bid, gb, db);
            st_f2_agent(pa + 512 + 2*bid, mb, 0.f);
            __hip_atomic_store(&flags[bid], iter+1, __ATOMIC_RELEASE, __HIP_MEMORY_SCOPE_AGENT);
        }
        // ---- poll 64 flags (wave 0: 32 u64 on lanes 0..31) ----
        if (tid < 64) {
            unsigned long long* f8 = (unsigned long long*)flags;
            int t = iter+1;
            for (;;) {
                int ok = 1;
                if (tid < 32) {
                    unsigned long long v = __hip_atomic_load(&f8[tid], __ATOMIC_RELAXED, __HIP_MEMORY_SCOPE_AGENT);
                    ok = ((int)(v & 0xffffffffu) >= t) & ((int)(v>>32) >= t);
                }
                if (__all(ok)) break;
                __builtin_amdgcn_s_sleep(1);
            }
        }
        __syncthreads();   // (B)
        // ---- overlap: gather own w chunk || wave-0 reduces 64 partials ----
        float2 wv2 = ld_f2_agent(wb + ca);
        if (tid < 64) {
            float2 gd  = ld_f2_agent(pa + 2*tid);
            float2 mu2 = ld_f2_agent(pa + 512 + 2*tid);
            float g = gd.x, d = gd.y, m = mu2.x;
            #pragma unroll
            for (int off=1; off<64; off<<=1) {
                g += __shfl_xor(g,off); d += __shfl_xor(d,off); m += __shfl_xor(m,off);
            }
            if (tid==0) { red[0]=g; red[1]=d; red[2]=m; }
        }
        __syncthreads();   // (C)
        float g = red[0], d = red[1];
        float m = red[2] * (1.f/NM);       // mean(w)
        // ---- identical scalar recurrences everywhere ----
        float b, a;
        if (iter == 0) { b=0.f; a=g/d; }
        else { b = g/gp; a = g/(d - b*g/ap); }
        gp=g; ap=a;
        // ---- p/x for own rows ----
        if (tid < 32) {
            pr = (iter==0) ? rrow : fmaf(b, pr, rrow);
            xr = (iter==0) ? a*pr : fmaf(a, pr, xr);
        }
        // ---- s and r chunk updates (w~ = w - m), float2 write ----
        float wt0 = wv2.x - m, wt1 = wv2.y - m;
        s0 = (iter==0) ? wt0 : fmaf(b, s0, wt0);
        s1 = (iter==0) ? wt1 : fmaf(b, s1, wt1);
        float2 rv2 = *(const float2*)(rs + ca);
        *(float2*)(rs + ca) = make_float2(fmaf(-a, s0, rv2.x), fmaf(-a, s1, rv2.y));
        __syncthreads();   // (D)
    }
    if (tid < 32) xg[bid*32+tid] = xr;
}

// -------- assemble output: metal -> x, electrolyte -> q --------
__global__ void k_out(const float* __restrict__ q, const int* __restrict__ an,
                      const float* __restrict__ wsf, float* __restrict__ out) {
    int i = blockIdx.x*256 + threadIdx.x;
    if (i >= NA) return;
    if (an[i]==METAL_Z) {
        int p = ((const int*)wsf)[OFF_POSOF/4 + i];
        out[i] = wsf[OFF_VEC/4 + p];
    } else {
        out[i] = q[i];
    }
}

extern "C" void kernel_launch(void* const* d_in, const int* in_sizes, int n_in,
                              void* d_out, int out_size, void* d_ws, size_t ws_size,
                              hipStream_t stream) {
    (void)in_sizes; (void)n_in; (void)out_size; (void)ws_size;
    const float* pos  = (const float*)d_in[0];
    const float* cell = (const float*)d_in[1];
    const float* q    = (const float*)d_in[2];
    const float* Jraw = (const float*)d_in[3];
    const int*   an   = (const int*)d_in[4];
    float* wsf = (float*)d_ws;
    float* out = (float*)d_out;

    k_setup<<<1, 256, 0, stream>>>(pos, cell, Jraw, an, wsf);
    k_ktab<<<KHP/256, 256, 0, stream>>>(wsf);
    k_srsi<<<KHP, 256, 0, stream>>>(q, an, wsf);
    k_field<<<dim3(62, 8), 256, 0, stream>>>(wsf);
    k_bfinal<<<1, 1024, 0, stream>>>(wsf);
    k_abuild<<<528, 256, 0, stream>>>(wsf);
    k_cg<<<NBLK_CG, CGT, 0, stream>>>(wsf);
    k_out<<<NA/256, 256, 0, stream>>>(q, an, wsf, out);
}

// Round 15
// 1632.173 us; speedup vs baseline: 1.6961x; 1.2937x over previous
//
#include <hip/hip_runtime.h>
#include <math.h>

// MetalWallQEQ: reciprocal-space Ewald QEQ for metal-wall charges.
// Round 15: precompute G (split-bf16 cos/sin matrix, 130MB ws) ONCE via
// k_gbuild (r14 recomputed it per tile-pair: 538M sincos = 500us VALU floor +
// 1.3e8 LDS write conflicts). k_abuild_g = pure Gram GEMM: 128x128 triangular
// tiles, reg-staged loads w/ pre-swizzled source + linear LDS + swizzled
// frag reads. Host falls back to r14 abuild if ws_size < 155.2 MB.

#define NA 4096
#define NM 2048
#define METAL_Z 79
#define KH 7812          // (25^3-1)/2 half k-points
#define KHP 7936         // padded to 62*128 (pad entries have w=0)
#define NIT 150          // fixed CG iterations (graph-friendly)
#define NBLK_CG 64       // CG grid: 64 blocks x 1024 threads
#define CGT 1024
#define TWO_PI 6.283185307179586f

// ---- workspace byte offsets ----
#define OFF_CONSTS 0        // [0..8]=invT(cell) row-major, [9]=pref=4pi/V, [10]=J
#define OFF_SUMS   256      // scratch
#define OFF_FLAGS  512      // 256 ints: CG barrier flags (zeroed per call)
#define OFF_KTAB   4096     // KHP * {gx,gy,gz,w} floats
#define OFF_FRAC   131072   // NA * {fx,fy,fz,0} fractional coords
#define OFF_MLIST  196608   // NM ints: metal position -> atom index
#define OFF_POSOF  204800   // NA ints: atom -> metal position (metal only)
#define OFF_SRW    221184   // KHP floats: w*Re S(k)
#define OFF_SIW    252928   // KHP floats: w*Im S(k)
#define OFF_BPART  284672   // 62*NM floats: field partials
#define OFF_B      792576   // NM floats (unused scratch)
#define OFF_VEC    800768   // x (2048), pad, r (at +4096)
#define OFF_WBUF   833536   // [parity][NM] w exchange (16KB)
#define OFF_PBUF   849920   // [parity][512 gd | 512 mu] partials (8KB)
#define OFF_A      917504   // NM*NM floats (A + J on diagonal)
#define OFF_GHI    25165824u   // 2048*7936 uints (bf16 cos|sin hi)  ~65MB
#define OFF_GLO    90177536u   // 2048*7936 uints (bf16 cos|sin lo)  ~65MB
#define G_END      155189248u  // required ws bytes for the G path

typedef short bf16x8 __attribute__((ext_vector_type(8)));
typedef float f32x4 __attribute__((ext_vector_type(4)));

__device__ __forceinline__ void sc_frac(float u, float& s, float& c) {
    float t = u - floorf(u);
    s = __builtin_amdgcn_sinf(t);
    c = __builtin_amdgcn_cosf(t);
}

__device__ __forceinline__ unsigned short bf16rne(float x) {
    unsigned u = __float_as_uint(x);
    unsigned r = u + 0x7fffu + ((u >> 16) & 1u);
    return (unsigned short)(r >> 16);
}

__device__ __forceinline__ float2 ld_f2_agent(const float* p) {
    unsigned long long v = __hip_atomic_load((unsigned long long*)p,
        __ATOMIC_RELAXED, __HIP_MEMORY_SCOPE_AGENT);
    union { unsigned long long u; float2 f; } cv; cv.u = v; return cv.f;
}
__device__ __forceinline__ void st_f2_agent(float* p, float a, float b) {
    union { unsigned long long u; float2 f; } cv; cv.f = make_float2(a, b);
    __hip_atomic_store((unsigned long long*)p, cv.u,
        __ATOMIC_RELAXED, __HIP_MEMORY_SCOPE_AGENT);
}

// -------- setup: cell inverse, fractional coords, metal scan, zero flags --------
__global__ void k_setup(const float* __restrict__ pos, const float* __restrict__ cell,
                        const float* __restrict__ Jraw, const int* __restrict__ an,
                        float* __restrict__ wsf) {
    int tid = threadIdx.x;
    __shared__ float sM[9];
    __shared__ int sc[256];
    if (tid == 0) {
        float c00=cell[0],c01=cell[1],c02=cell[2];
        float c10=cell[3],c11=cell[4],c12=cell[5];
        float c20=cell[6],c21=cell[7],c22=cell[8];
        float det = c00*(c11*c22-c12*c21) - c01*(c10*c22-c12*c20) + c02*(c10*c21-c11*c20);
        float i00 =  (c11*c22 - c12*c21)/det;
        float i01 = -(c01*c22 - c02*c21)/det;
        float i02 =  (c01*c12 - c02*c11)/det;
        float i10 = -(c10*c22 - c12*c20)/det;
        float i11 =  (c00*c22 - c02*c20)/det;
        float i12 = -(c00*c12 - c02*c10)/det;
        float i20 =  (c10*c21 - c11*c20)/det;
        float i21 = -(c00*c21 - c01*c20)/det;
        float i22 =  (c00*c11 - c01*c10)/det;
        sM[0]=i00; sM[1]=i10; sM[2]=i20;
        sM[3]=i01; sM[4]=i11; sM[5]=i21;
        sM[6]=i02; sM[7]=i12; sM[8]=i22;
        float vol = fabsf(det);
        for (int m=0;m<9;m++) wsf[OFF_CONSTS/4 + m] = sM[m];
        wsf[OFF_CONSTS/4 + 9]  = 12.566370614359172f / vol;   // 4pi/V
        wsf[OFF_CONSTS/4 + 10] = Jraw[0]*Jraw[0];
    }
    __syncthreads();
    float M0=sM[0],M1=sM[1],M2=sM[2],M3=sM[3],M4=sM[4],M5=sM[5],M6=sM[6],M7=sM[7],M8=sM[8];
    for (int i=tid; i<NA; i+=256) {
        float x=pos[3*i], y=pos[3*i+1], z=pos[3*i+2];
        wsf[OFF_FRAC/4 + 4*i+0] = M0*x + M1*y + M2*z;
        wsf[OFF_FRAC/4 + 4*i+1] = M3*x + M4*y + M5*z;
        wsf[OFF_FRAC/4 + 4*i+2] = M6*x + M7*y + M8*z;
        wsf[OFF_FRAC/4 + 4*i+3] = 0.f;
    }
    ((int*)wsf)[OFF_FLAGS/4 + tid] = 0;       // CG barrier flags
    if (tid < 4) wsf[OFF_SUMS/4 + tid] = 0.f;
    // metal prefix scan (deterministic ordering == np.where order)
    int cnt = 0;
    int base_i = tid*16;
    for (int j=0;j<16;j++) cnt += (an[base_i+j]==METAL_Z) ? 1 : 0;
    sc[tid] = cnt; __syncthreads();
    for (int off=1; off<256; off<<=1) {
        int v = (tid>=off) ? sc[tid-off] : 0;
        __syncthreads();
        sc[tid] += v;
        __syncthreads();
    }
    int base = sc[tid] - cnt;
    int* mlist = (int*)wsf + OFF_MLIST/4;
    int* posof = (int*)wsf + OFF_POSOF/4;
    for (int j=0;j<16;j++) {
        int i = base_i + j;
        if (an[i]==METAL_Z) { mlist[base] = i; posof[i] = base; base++; }
    }
}

// -------- k-table: integer triple + weight w = 2*pref*exp(-k2/2)/k2 --------
__global__ void k_ktab(float* __restrict__ wsf) {
    int k = blockIdx.x*256 + threadIdx.x;
    if (k >= KHP) return;
    float4 out;
    if (k < KH) {
        int gx = k/625 - 12;
        int rem = k%625;
        int gy = rem/25 - 12;
        int gz = rem%25 - 12;
        const float* M = wsf + OFF_CONSTS/4;
        float pref = M[9];
        float kx = TWO_PI*(gx*M[0] + gy*M[3] + gz*M[6]);
        float ky = TWO_PI*(gx*M[1] + gy*M[4] + gz*M[7]);
        float kz = TWO_PI*(gx*M[2] + gy*M[5] + gz*M[8]);
        float k2 = kx*kx + ky*ky + kz*kz;
        float kfac = __expf(-0.5f*k2) / k2;
        out = make_float4((float)gx, (float)gy, (float)gz, 2.f*pref*kfac);
    } else {
        out = make_float4(0.f, 0.f, 0.f, 0.f);
    }
    *(float4*)(wsf + OFF_KTAB/4 + 4*k) = out;
}

// -------- G precompute: row m (metal order), col k: packed bf16 hi/lo --------
__global__ void k_gbuild(const float* __restrict__ wsf, unsigned* __restrict__ ghi,
                         unsigned* __restrict__ glo) {
    int k = blockIdx.x*256 + threadIdx.x;   // 31*256 = 7936
    int m = blockIdx.y;                     // 2048
    int atom = ((const int*)wsf)[OFF_MLIST/4 + m];
    float4 f = *(const float4*)(wsf + OFF_FRAC/4 + 4*atom);
    float4 kt = *(const float4*)(wsf + OFF_KTAB/4 + 4*k);
    float rw = sqrtf(kt.w);
    float u = kt.x*f.x + kt.y*f.y + kt.z*f.z;
    float s, c; sc_frac(u, s, c);
    float gc = rw*c, gs = rw*s;
    unsigned short hc = bf16rne(gc);
    float hcf = __uint_as_float(((unsigned)hc) << 16);
    unsigned short lc = bf16rne(gc - hcf);
    unsigned short hs = bf16rne(gs);
    float hsf = __uint_as_float(((unsigned)hs) << 16);
    unsigned short ls = bf16rne(gs - hsf);
    size_t off = (size_t)m*KHP + k;
    ghi[off] = (unsigned)hc | ((unsigned)hs << 16);
    glo[off] = (unsigned)lc | ((unsigned)ls << 16);
}

// -------- structure factors over electrolyte charges (metal q := 0) --------
__global__ void k_srsi(const float* __restrict__ q, const int* __restrict__ an,
                       float* __restrict__ wsf) {
    int k = blockIdx.x;
    int tid = threadIdx.x;
    float4 kt = *(const float4*)(wsf + OFF_KTAB/4 + 4*k);
    const float* frac = wsf + OFF_FRAC/4;
    float aR=0.f, aI=0.f;
    for (int i=tid; i<NA; i+=256) {
        float qa = (an[i]==METAL_Z) ? 0.f : q[i];
        float4 f = *(const float4*)(frac + 4*i);
        float u = kt.x*f.x + kt.y*f.y + kt.z*f.z;
        float s,c; sc_frac(u, s, c);
        aR += qa*c; aI += qa*s;
    }
    __shared__ float sR[256], sI[256];
    sR[tid]=aR; sI[tid]=aI; __syncthreads();
    for (int off=128; off>0; off>>=1) {
        if (tid<off) { sR[tid]+=sR[tid+off]; sI[tid]+=sI[tid+off]; }
        __syncthreads();
    }
    if (tid==0) {
        wsf[OFF_SRW/4 + k] = kt.w * sR[0];
        wsf[OFF_SIW/4 + k] = kt.w * sI[0];
    }
}

// -------- field at metal atoms (partial over k-chunks) --------
__global__ void k_field(float* __restrict__ wsf) {
    int kc = blockIdx.x;
    int m = blockIdx.y*256 + threadIdx.x;
    int atom = ((const int*)wsf)[OFF_MLIST/4 + m];
    float4 f = *(const float4*)(wsf + OFF_FRAC/4 + 4*atom);
    const float* kt = wsf + OFF_KTAB/4;
    const float* SrW = wsf + OFF_SRW/4;
    const float* SiW = wsf + OFF_SIW/4;
    float acc = 0.f;
    int k0 = kc*128;
    for (int j=0;j<128;j++) {
        int k = k0 + j;
        float4 g = *(const float4*)(kt + 4*k);
        float u = g.x*f.x + g.y*f.y + g.z*f.z;
        float s,c; sc_frac(u, s, c);
        acc = fmaf(c, SrW[k], fmaf(s, SiW[k], acc));
    }
    wsf[OFF_BPART/4 + kc*NM + m] = acc;
}

// -------- r0 = P*B = B - mean(B); B = -field (1 block x 1024) --------
__global__ void k_bfinal(float* __restrict__ wsf) {
    int tid = threadIdx.x;
    float b0 = 0.f, b1 = 0.f;
    for (int kc=0;kc<62;kc++) {
        b0 += wsf[OFF_BPART/4 + kc*NM + tid];
        b1 += wsf[OFF_BPART/4 + kc*NM + 1024 + tid];
    }
    b0 = -b0; b1 = -b1;
    __shared__ float sb[1024];
    sb[tid] = b0 + b1; __syncthreads();
    for (int off=512; off>0; off>>=1) {
        if (tid<off) sb[tid] += sb[tid+off];
        __syncthreads();
    }
    float mean = sb[0] * (1.f/NM);
    float* r = wsf + OFF_VEC/4 + 4096;
    r[tid]        = b0 - mean;
    r[1024 + tid] = b1 - mean;
}

// -------- A build (G path): 128x128 triangular Gram GEMM from precomputed G --------
// LDS: 4 regions [128 rows][32 uints] (UH UL VH VL). Staging: reg-staged uint4
// with pre-swizzled source chunk (c_lds holds global chunk c_lds ^ (row&7));
// frag reads apply the same XOR. 4x4 16x16 frags/wave, 3 split-MFMA each.
__launch_bounds__(256)
__global__ void k_abuild_g(float* __restrict__ wsf, const unsigned* __restrict__ ghi,
                           const unsigned* __restrict__ glo) {
    __shared__ unsigned Sh[16384];     // 64 KB
    int tid = threadIdx.x;
    int bid = blockIdx.x;
    int bi = (int)((sqrtf(8.f*bid + 1.f) - 1.f)*0.5f);
    while ((bi+1)*(bi+2)/2 <= bid) bi++;
    while (bi*(bi+1)/2 > bid) bi--;
    int bj = bid - bi*(bi+1)/2;
    bool diag = (bi == bj);
    float J = wsf[OFF_CONSTS/4 + 10];

    int w = tid >> 6, lane = tid & 63;
    // staging role: non-diag wave w -> matrix w over 128 rows;
    // diag: waves {0,2} -> UH halves, {1,3} -> UL halves.
    int mat   = diag ? (w & 1) : w;
    int tb    = (diag ? bi : (w < 2 ? bi : bj)) * 128;
    int rbase = diag ? ((w >> 1) * 64) : 0;
    int nld   = diag ? 8 : 16;
    const unsigned* gsrc = (mat & 1) ? glo : ghi;
    int lrow8 = lane >> 3;
    int gcsw  = (lane & 7) ^ (lrow8 & 7);     // swizzled source chunk
    unsigned* lb = &Sh[mat*4096 + rbase*32];
    const unsigned* gb0 = gsrc + (size_t)(tb + rbase)*KHP + gcsw*4;

    // fragment roles: wave quadrant (wr,wc)
    int wr = w & 1, wc = w >> 1;
    int lr = lane & 15, g4 = lane >> 4;
    const unsigned short* UHs = (const unsigned short*)&Sh[0];
    const unsigned short* ULs = (const unsigned short*)&Sh[4096];
    const unsigned short* VHs = diag ? UHs : (const unsigned short*)&Sh[8192];
    const unsigned short* VLs = diag ? ULs : (const unsigned short*)&Sh[12288];

    f32x4 acc[4][4];
    #pragma unroll
    for (int i=0;i<4;i++)
        #pragma unroll
        for (int j=0;j<4;j++) acc[i][j] = (f32x4){0.f,0.f,0.f,0.f};

    for (int kc = 0; kc < KHP/32; ++kc) {      // 248 chunks of 32 k-points
        __syncthreads();                        // prior MFMA reads complete
        const unsigned* gb = gb0 + kc*32;
        #pragma unroll
        for (int i = 0; i < 16; ++i) {
            if (i < nld) {
                uint4 v = *(const uint4*)(gb + (size_t)(i*8 + lrow8)*KHP);
                *(uint4*)&lb[i*256 + lane*4] = v;
            }
        }
        __syncthreads();
        #pragma unroll
        for (int ks = 0; ks < 2; ++ks) {
            int cA = ks*4 + g4;
            bf16x8 ah[4], al[4], bh[4], bl[4];
            #pragma unroll
            for (int fi=0; fi<4; fi++) {
                int r = wr*64 + fi*16 + lr;
                int o = r*64 + ((cA ^ (r&7)) << 3);
                ah[fi] = *(const bf16x8*)&UHs[o];
                al[fi] = *(const bf16x8*)&ULs[o];
            }
            #pragma unroll
            for (int fj=0; fj<4; fj++) {
                int r = wc*64 + fj*16 + lr;
                int o = r*64 + ((cA ^ (r&7)) << 3);
                bh[fj] = *(const bf16x8*)&VHs[o];
                bl[fj] = *(const bf16x8*)&VLs[o];
            }
            #pragma unroll
            for (int fi=0; fi<4; fi++)
                #pragma unroll
                for (int fj=0; fj<4; fj++) {
                    acc[fi][fj] = __builtin_amdgcn_mfma_f32_16x16x32_bf16(ah[fi], bh[fj], acc[fi][fj], 0,0,0);
                    acc[fi][fj] = __builtin_amdgcn_mfma_f32_16x16x32_bf16(ah[fi], bl[fj], acc[fi][fj], 0,0,0);
                    acc[fi][fj] = __builtin_amdgcn_mfma_f32_16x16x32_bf16(al[fi], bh[fj], acc[fi][fj], 0,0,0);
                }
        }
    }

    // C write: col=lane&15, row=(lane>>4)*4+reg (m89 layout); symmetric + J
    float* A = wsf + OFF_A/4;
    int rb4 = g4 * 4;
    #pragma unroll
    for (int fi=0; fi<4; fi++) {
        #pragma unroll
        for (int fj=0; fj<4; fj++) {
            int gj = bj*128 + wc*64 + fj*16 + lr;
            #pragma unroll
            for (int r=0; r<4; r++) {
                int gi = bi*128 + wr*64 + fi*16 + rb4 + r;
                float v = acc[fi][fj][r] + ((gi==gj)?J:0.f);
                A[(size_t)gi*NM + gj] = v;
                A[(size_t)gj*NM + gi] = v;
            }
        }
    }
}

// -------- A build (fallback, r14): MFMA split-bf16, in-kernel sincos --------
__launch_bounds__(256)
__global__ void k_abuild(float* __restrict__ wsf) {
    __shared__ unsigned short UH[64*72], UL[64*72], VH[64*72], VL[64*72];
    __shared__ float4 FIJ[128];
    int tid = threadIdx.x;
    int bid = blockIdx.x;
    int bi = (int)((sqrtf(8.f*bid + 1.f) - 1.f)*0.5f);
    while ((bi+1)*(bi+2)/2 <= bid) bi++;
    while (bi*(bi+1)/2 > bid) bi--;
    int bj = bid - bi*(bi+1)/2;
    bool diag = (bi == bj);

    const int* mlist = (const int*)wsf + OFF_MLIST/4;
    const float* frac = wsf + OFF_FRAC/4;
    const float* ktab = wsf + OFF_KTAB/4;
    float J = wsf[OFF_CONSTS/4 + 10];

    if (tid < 64)        FIJ[tid]    = *(const float4*)(frac + 4*mlist[bi*64 + tid]);
    else if (tid < 128)  FIJ[tid]    = *(const float4*)(frac + 4*mlist[bj*64 + (tid-64)]);
    __syncthreads();

    int a = tid >> 2;
    int kq = tid & 3;
    float4 fia = FIJ[a];
    float4 fja = FIJ[64 + a];
    unsigned* uhw = (unsigned*)&UH[a*72];
    unsigned* ulw = (unsigned*)&UL[a*72];
    unsigned* vhw = (unsigned*)&VH[a*72];
    unsigned* vlw = (unsigned*)&VL[a*72];

    int lane = tid & 63, w = tid >> 6;
    int fr0 = (w & 1) * 2, fc0 = (w >> 1) * 2;
    int lr = lane & 15, lkb = (lane >> 4) * 8;
    int ra0 = (fr0*16 + lr)*72, ra1 = ra0 + 16*72;
    int rb0 = (fc0*16 + lr)*72, rb1 = rb0 + 16*72;
    const unsigned short* VHp = diag ? UH : VH;
    const unsigned short* VLp = diag ? UL : VL;

    f32x4 acc00 = {0.f,0.f,0.f,0.f}, acc01 = acc00, acc10 = acc00, acc11 = acc00;

    for (int kbase = 0; kbase < KHP; kbase += 32) {
        __syncthreads();
        #pragma unroll
        for (int j = 0; j < 8; j++) {
            int kl = kq*8 + j;
            float4 kt = *(const float4*)(ktab + 4*(kbase + kl));
            float rw = sqrtf(kt.w);
            float u = kt.x*fia.x + kt.y*fia.y + kt.z*fia.z;
            float s, c; sc_frac(u, s, c);
            float gc = rw*c, gs = rw*s;
            unsigned short hc = bf16rne(gc);
            float hcf = __uint_as_float(((unsigned)hc) << 16);
            unsigned short lc = bf16rne(gc - hcf);
            unsigned short hs = bf16rne(gs);
            float hsf = __uint_as_float(((unsigned)hs) << 16);
            unsigned short ls = bf16rne(gs - hsf);
            uhw[kl] = (unsigned)hc | ((unsigned)hs << 16);
            ulw[kl] = (unsigned)lc | ((unsigned)ls << 16);
            if (!diag) {
                u = kt.x*fja.x + kt.y*fja.y + kt.z*fja.z;
                sc_frac(u, s, c);
                gc = rw*c; gs = rw*s;
                hc = bf16rne(gc);
                hcf = __uint_as_float(((unsigned)hc) << 16);
                lc = bf16rne(gc - hcf);
                hs = bf16rne(gs);
                hsf = __uint_as_float(((unsigned)hs) << 16);
                ls = bf16rne(gs - hsf);
                vhw[kl] = (unsigned)hc | ((unsigned)hs << 16);
                vlw[kl] = (unsigned)lc | ((unsigned)ls << 16);
            }
        }
        __syncthreads();
        #pragma unroll
        for (int ks = 0; ks < 2; ks++) {
            int co = ks*32 + lkb;
            bf16x8 ah0 = *(const bf16x8*)&UH[ra0 + co];
            bf16x8 al0 = *(const bf16x8*)&UL[ra0 + co];
            bf16x8 ah1 = *(const bf16x8*)&UH[ra1 + co];
            bf16x8 al1 = *(const bf16x8*)&UL[ra1 + co];
            bf16x8 bh0 = *(const bf16x8*)&VHp[rb0 + co];
            bf16x8 bl0 = *(const bf16x8*)&VLp[rb0 + co];
            bf16x8 bh1 = *(const bf16x8*)&VHp[rb1 + co];
            bf16x8 bl1 = *(const bf16x8*)&VLp[rb1 + co];
            acc00 = __builtin_amdgcn_mfma_f32_16x16x32_bf16(ah0, bh0, acc00, 0,0,0);
            acc00 = __builtin_amdgcn_mfma_f32_16x16x32_bf16(ah0, bl0, acc00, 0,0,0);
            acc00 = __builtin_amdgcn_mfma_f32_16x16x32_bf16(al0, bh0, acc00, 0,0,0);
            acc01 = __builtin_amdgcn_mfma_f32_16x16x32_bf16(ah0, bh1, acc01, 0,0,0);
            acc01 = __builtin_amdgcn_mfma_f32_16x16x32_bf16(ah0, bl1, acc01, 0,0,0);
            acc01 = __builtin_amdgcn_mfma_f32_16x16x32_bf16(al0, bh1, acc01, 0,0,0);
            acc10 = __builtin_amdgcn_mfma_f32_16x16x32_bf16(ah1, bh0, acc10, 0,0,0);
            acc10 = __builtin_amdgcn_mfma_f32_16x16x32_bf16(ah1, bl0, acc10, 0,0,0);
            acc10 = __builtin_amdgcn_mfma_f32_16x16x32_bf16(al1, bh0, acc10, 0,0,0);
            acc11 = __builtin_amdgcn_mfma_f32_16x16x32_bf16(ah1, bh1, acc11, 0,0,0);
            acc11 = __builtin_amdgcn_mfma_f32_16x16x32_bf16(ah1, bl1, acc11, 0,0,0);
            acc11 = __builtin_amdgcn_mfma_f32_16x16x32_bf16(al1, bh1, acc11, 0,0,0);
        }
    }

    float* A = wsf + OFF_A/4;
    int rbase = (lane >> 4) * 4;
    #pragma unroll
    for (int fi_ = 0; fi_ < 2; fi_++) {
        int fr = fr0 + fi_;
        #pragma unroll
        for (int fj_ = 0; fj_ < 2; fj_++) {
            int fc = fc0 + fj_;
            int gj = bj*64 + fc*16 + lr;
            f32x4 av = (fi_==0) ? ((fj_==0) ? acc00 : acc01)
                                : ((fj_==0) ? acc10 : acc11);
            #pragma unroll
            for (int r = 0; r < 4; r++) {
                int gi = bi*64 + fr*16 + rbase + r;
                float v = av[r] + ((gi == gj) ? J : 0.f);
                A[(size_t)gi*NM + gj] = v;
                A[(size_t)gj*NM + gi] = v;
            }
        }
    }
}

// -------- persistent projected CG: 64 blocks x 1024 threads (r12) --------
__launch_bounds__(CGT, 1)
__global__ void k_cg(float* __restrict__ wsf) {
    const float* A = wsf + OFF_A/4;
    float* vec = wsf + OFF_VEC/4;
    float* xg = vec;
    const float* rg = vec + 4096;
    int* flags = (int*)wsf + OFF_FLAGS/4;
    float* wbuf = wsf + OFF_WBUF/4;
    float* pbuf = wsf + OFF_PBUF/4;

    __shared__ float rs[NM];
    __shared__ float wrow[32];
    __shared__ float red[4];

    int tid = threadIdx.x, bid = blockIdx.x;
    int rl = tid >> 5, lane = tid & 31;
    int row = bid*32 + rl;
    const float* Arow = A + (size_t)row*NM;
    int ca = 2*tid;

    ((float2*)rs)[tid] = ((const float2*)rg)[tid];
    __syncthreads();

    float s0=0.f, s1=0.f;
    float pr=0.f, xr=0.f;
    float gp=1.f, ap=1.f;

    for (int iter=0; iter<NIT; ++iter) {
        int par = iter & 1;
        float* wb = wbuf + par*NM;
        float* pa = pbuf + par*1024;
        float acc=0.f;
        #pragma unroll 8
        for (int c=lane*4; c<NM; c+=128) {
            float4 a = *(const float4*)(Arow + c);
            float4 u = *(const float4*)(rs + c);
            acc += a.x*u.x + a.y*u.y + a.z*u.z + a.w*u.w;
        }
        #pragma unroll
        for (int off=1; off<32; off<<=1) acc += __shfl_xor(acc, off);
        if (lane == 0) {
            wrow[rl] = acc;
            __hip_atomic_store(wb + row, acc, __ATOMIC_RELAXED, __HIP_MEMORY_SCOPE_AGENT);
        }
        float rrow = (tid<32) ? rs[bid*32+tid] : 0.f;
        __syncthreads();   // (A)
        if (tid == 0) {
            float gb=0.f, db=0.f, mb=0.f;
            #pragma unroll
            for (int j=0;j<32;j++) {
                float rv = rs[bid*32+j];
                gb = fmaf(rv,rv,gb); db = fmaf(rv,wrow[j],db); mb += wrow[j];
            }
            st_f2_agent(pa + 2*bid, gb, db);
            st_f2_agent(pa + 512 + 2*bid, mb, 0.f);
            __hip_atomic_store(&flags[bid], iter+1, __ATOMIC_RELEASE, __HIP_MEMORY_SCOPE_AGENT);
        }
        if (tid < 64) {
            unsigned long long* f8 = (unsigned long long*)flags;
            int t = iter+1;
            for (;;) {
                int ok = 1;
                if (tid < 32) {
                    unsigned long long v = __hip_atomic_load(&f8[tid], __ATOMIC_RELAXED, __HIP_MEMORY_SCOPE_AGENT);
                    ok = ((int)(v & 0xffffffffu) >= t) & ((int)(v>>32) >= t);
                }
                if (__all(ok)) break;
                __builtin_amdgcn_s_sleep(1);
            }
        }
        __syncthreads();   // (B)
        float2 wv2 = ld_f2_agent(wb + ca);
        if (tid < 64) {
            float2 gd  = ld_f2_agent(pa + 2*tid);
            float2 mu2 = ld_f2_agent(pa + 512 + 2*tid);
            float g = gd.x, d = gd.y, m = mu2.x;
            #pragma unroll
            for (int off=1; off<64; off<<=1) {
                g += __shfl_xor(g,off); d += __shfl_xor(d,off); m += __shfl_xor(m,off);
            }
            if (tid==0) { red[0]=g; red[1]=d; red[2]=m; }
        }
        __syncthreads();   // (C)
        float g = red[0], d = red[1];
        float m = red[2] * (1.f/NM);
        float b, a;
        if (iter == 0) { b=0.f; a=g/d; }
        else { b = g/gp; a = g/(d - b*g/ap); }
        gp=g; ap=a;
        if (tid < 32) {
            pr = (iter==0) ? rrow : fmaf(b, pr, rrow);
            xr = (iter==0) ? a*pr : fmaf(a, pr, xr);
        }
        float wt0 = wv2.x - m, wt1 = wv2.y - m;
        s0 = (iter==0) ? wt0 : fmaf(b, s0, wt0);
        s1 = (iter==0) ? wt1 : fmaf(b, s1, wt1);
        float2 rv2 = *(const float2*)(rs + ca);
        *(float2*)(rs + ca) = make_float2(fmaf(-a, s0, rv2.x), fmaf(-a, s1, rv2.y));
        __syncthreads();   // (D)
    }
    if (tid < 32) xg[bid*32+tid] = xr;
}

// -------- assemble output: metal -> x, electrolyte -> q --------
__global__ void k_out(const float* __restrict__ q, const int* __restrict__ an,
                      const float* __restrict__ wsf, float* __restrict__ out) {
    int i = blockIdx.x*256 + threadIdx.x;
    if (i >= NA) return;
    if (an[i]==METAL_Z) {
        int p = ((const int*)wsf)[OFF_POSOF/4 + i];
        out[i] = wsf[OFF_VEC/4 + p];
    } else {
        out[i] = q[i];
    }
}

extern "C" void kernel_launch(void* const* d_in, const int* in_sizes, int n_in,
                              void* d_out, int out_size, void* d_ws, size_t ws_size,
                              hipStream_t stream) {
    (void)in_sizes; (void)n_in; (void)out_size;
    const float* pos  = (const float*)d_in[0];
    const float* cell = (const float*)d_in[1];
    const float* q    = (const float*)d_in[2];
    const float* Jraw = (const float*)d_in[3];
    const int*   an   = (const int*)d_in[4];
    float* wsf = (float*)d_ws;
    float* out = (float*)d_out;
    unsigned* ghi = (unsigned*)((char*)d_ws + OFF_GHI);
    unsigned* glo = (unsigned*)((char*)d_ws + OFF_GLO);
    bool bigws = (ws_size >= (size_t)G_END);

    k_setup<<<1, 256, 0, stream>>>(pos, cell, Jraw, an, wsf);
    k_ktab<<<KHP/256, 256, 0, stream>>>(wsf);
    if (bigws) k_gbuild<<<dim3(31, 2048), 256, 0, stream>>>(wsf, ghi, glo);
    k_srsi<<<KHP, 256, 0, stream>>>(q, an, wsf);
    k_field<<<dim3(62, 8), 256, 0, stream>>>(wsf);
    k_bfinal<<<1, 1024, 0, stream>>>(wsf);
    if (bigws) k_abuild_g<<<136, 256, 0, stream>>>(wsf, ghi, glo);
    else       k_abuild<<<528, 256, 0, stream>>>(wsf);
    k_cg<<<NBLK_CG, CGT, 0, stream>>>(wsf);
    k_out<<<NA/256, 256, 0, stream>>>(q, an, wsf, out);
}

// Round 16
// 1579.117 us; speedup vs baseline: 1.7531x; 1.0336x over previous
//
#include <hip/hip_runtime.h>
#include <math.h>

// MetalWallQEQ: reciprocal-space Ewald QEQ for metal-wall charges.
// Round 16: CG data-carried sync — (w,epoch) packed in one u64 per row;
// consumers poll their OWN entries directly (no flag indirection round-trip).
// Partials (g,d,m) tagged the same way. Tags zeroed each call in k_setup.
// NIT stays 150 for clean attribution; absmax must stay EXACTLY 0.01757812.

#define NA 4096
#define NM 2048
#define METAL_Z 79
#define KH 7812          // (25^3-1)/2 half k-points
#define KHP 7936         // padded to 62*128 (pad entries have w=0)
#define NIT 150          // fixed CG iterations (graph-friendly)
#define NBLK_CG 64       // CG grid: 64 blocks x 1024 threads
#define CGT 1024
#define TWO_PI 6.283185307179586f

// ---- workspace byte offsets ----
#define OFF_CONSTS 0        // [0..8]=invT(cell) row-major, [9]=pref=4pi/V, [10]=J
#define OFF_SUMS   256      // scratch
#define OFF_FLAGS  512      // (legacy, zeroed)
#define OFF_KTAB   4096     // KHP * {gx,gy,gz,w} floats
#define OFF_FRAC   131072   // NA * {fx,fy,fz,0} fractional coords
#define OFF_MLIST  196608   // NM ints: metal position -> atom index
#define OFF_POSOF  204800   // NA ints: atom -> metal position (metal only)
#define OFF_SRW    221184   // KHP floats: w*Re S(k)
#define OFF_SIW    252928   // KHP floats: w*Im S(k)
#define OFF_BPART  284672   // 62*NM floats: field partials
#define OFF_B      792576   // NM floats (unused scratch)
#define OFF_VEC    800768   // x (2048), pad, r (at +4096)
#define OFF_WBUF   833536   // [parity][NM] u64 (w | tag<<32)  32KB
#define OFF_PBUF   866304   // [parity][3*64] u64 tagged partials  3KB
#define OFF_A      917504   // NM*NM floats (A + J on diagonal)
#define OFF_GHI    25165824u   // 2048*7936 uints (bf16 cos|sin hi)  ~65MB
#define OFF_GLO    90177536u   // 2048*7936 uints (bf16 cos|sin lo)  ~65MB
#define G_END      155189248u  // required ws bytes for the G path

typedef short bf16x8 __attribute__((ext_vector_type(8)));
typedef float f32x4 __attribute__((ext_vector_type(4)));

__device__ __forceinline__ void sc_frac(float u, float& s, float& c) {
    float t = u - floorf(u);
    s = __builtin_amdgcn_sinf(t);
    c = __builtin_amdgcn_cosf(t);
}

__device__ __forceinline__ unsigned short bf16rne(float x) {
    unsigned u = __float_as_uint(x);
    unsigned r = u + 0x7fffu + ((u >> 16) & 1u);
    return (unsigned short)(r >> 16);
}

__device__ __forceinline__ unsigned long long pack_wt(float w, int tag) {
    return (unsigned long long)__float_as_uint(w) | ((unsigned long long)(unsigned)tag << 32);
}
__device__ __forceinline__ float lo_f(unsigned long long v) {
    return __uint_as_float((unsigned)v);
}

// -------- setup: cell inverse, fractional coords, metal scan, zero tags --------
__global__ void k_setup(const float* __restrict__ pos, const float* __restrict__ cell,
                        const float* __restrict__ Jraw, const int* __restrict__ an,
                        float* __restrict__ wsf) {
    int tid = threadIdx.x;
    __shared__ float sM[9];
    __shared__ int sc[256];
    if (tid == 0) {
        float c00=cell[0],c01=cell[1],c02=cell[2];
        float c10=cell[3],c11=cell[4],c12=cell[5];
        float c20=cell[6],c21=cell[7],c22=cell[8];
        float det = c00*(c11*c22-c12*c21) - c01*(c10*c22-c12*c20) + c02*(c10*c21-c11*c20);
        float i00 =  (c11*c22 - c12*c21)/det;
        float i01 = -(c01*c22 - c02*c21)/det;
        float i02 =  (c01*c12 - c02*c11)/det;
        float i10 = -(c10*c22 - c12*c20)/det;
        float i11 =  (c00*c22 - c02*c20)/det;
        float i12 = -(c00*c12 - c02*c10)/det;
        float i20 =  (c10*c21 - c11*c20)/det;
        float i21 = -(c00*c21 - c01*c20)/det;
        float i22 =  (c00*c11 - c01*c10)/det;
        sM[0]=i00; sM[1]=i10; sM[2]=i20;
        sM[3]=i01; sM[4]=i11; sM[5]=i21;
        sM[6]=i02; sM[7]=i12; sM[8]=i22;
        float vol = fabsf(det);
        for (int m=0;m<9;m++) wsf[OFF_CONSTS/4 + m] = sM[m];
        wsf[OFF_CONSTS/4 + 9]  = 12.566370614359172f / vol;   // 4pi/V
        wsf[OFF_CONSTS/4 + 10] = Jraw[0]*Jraw[0];
    }
    __syncthreads();
    float M0=sM[0],M1=sM[1],M2=sM[2],M3=sM[3],M4=sM[4],M5=sM[5],M6=sM[6],M7=sM[7],M8=sM[8];
    for (int i=tid; i<NA; i+=256) {
        float x=pos[3*i], y=pos[3*i+1], z=pos[3*i+2];
        wsf[OFF_FRAC/4 + 4*i+0] = M0*x + M1*y + M2*z;
        wsf[OFF_FRAC/4 + 4*i+1] = M3*x + M4*y + M5*z;
        wsf[OFF_FRAC/4 + 4*i+2] = M6*x + M7*y + M8*z;
        wsf[OFF_FRAC/4 + 4*i+3] = 0.f;
    }
    ((int*)wsf)[OFF_FLAGS/4 + tid] = 0;
    if (tid < 4) wsf[OFF_SUMS/4 + tid] = 0.f;
    // zero CG sync tags: wbuf (4096 u64) + pbuf (384 u64), contiguous
    unsigned long long* tz = (unsigned long long*)((char*)wsf + OFF_WBUF);
    for (int i=tid; i<4480; i+=256) tz[i] = 0ull;
    // metal prefix scan (deterministic ordering == np.where order)
    int cnt = 0;
    int base_i = tid*16;
    for (int j=0;j<16;j++) cnt += (an[base_i+j]==METAL_Z) ? 1 : 0;
    sc[tid] = cnt; __syncthreads();
    for (int off=1; off<256; off<<=1) {
        int v = (tid>=off) ? sc[tid-off] : 0;
        __syncthreads();
        sc[tid] += v;
        __syncthreads();
    }
    int base = sc[tid] - cnt;
    int* mlist = (int*)wsf + OFF_MLIST/4;
    int* posof = (int*)wsf + OFF_POSOF/4;
    for (int j=0;j<16;j++) {
        int i = base_i + j;
        if (an[i]==METAL_Z) { mlist[base] = i; posof[i] = base; base++; }
    }
}

// -------- k-table: integer triple + weight w = 2*pref*exp(-k2/2)/k2 --------
__global__ void k_ktab(float* __restrict__ wsf) {
    int k = blockIdx.x*256 + threadIdx.x;
    if (k >= KHP) return;
    float4 out;
    if (k < KH) {
        int gx = k/625 - 12;
        int rem = k%625;
        int gy = rem/25 - 12;
        int gz = rem%25 - 12;
        const float* M = wsf + OFF_CONSTS/4;
        float pref = M[9];
        float kx = TWO_PI*(gx*M[0] + gy*M[3] + gz*M[6]);
        float ky = TWO_PI*(gx*M[1] + gy*M[4] + gz*M[7]);
        float kz = TWO_PI*(gx*M[2] + gy*M[5] + gz*M[8]);
        float k2 = kx*kx + ky*ky + kz*kz;
        float kfac = __expf(-0.5f*k2) / k2;
        out = make_float4((float)gx, (float)gy, (float)gz, 2.f*pref*kfac);
    } else {
        out = make_float4(0.f, 0.f, 0.f, 0.f);
    }
    *(float4*)(wsf + OFF_KTAB/4 + 4*k) = out;
}

// -------- G precompute: row m (metal order), col k: packed bf16 hi/lo --------
__global__ void k_gbuild(const float* __restrict__ wsf, unsigned* __restrict__ ghi,
                         unsigned* __restrict__ glo) {
    int k = blockIdx.x*256 + threadIdx.x;   // 31*256 = 7936
    int m = blockIdx.y;                     // 2048
    int atom = ((const int*)wsf)[OFF_MLIST/4 + m];
    float4 f = *(const float4*)(wsf + OFF_FRAC/4 + 4*atom);
    float4 kt = *(const float4*)(wsf + OFF_KTAB/4 + 4*k);
    float rw = sqrtf(kt.w);
    float u = kt.x*f.x + kt.y*f.y + kt.z*f.z;
    float s, c; sc_frac(u, s, c);
    float gc = rw*c, gs = rw*s;
    unsigned short hc = bf16rne(gc);
    float hcf = __uint_as_float(((unsigned)hc) << 16);
    unsigned short lc = bf16rne(gc - hcf);
    unsigned short hs = bf16rne(gs);
    float hsf = __uint_as_float(((unsigned)hs) << 16);
    unsigned short ls = bf16rne(gs - hsf);
    size_t off = (size_t)m*KHP + k;
    ghi[off] = (unsigned)hc | ((unsigned)hs << 16);
    glo[off] = (unsigned)lc | ((unsigned)ls << 16);
}

// -------- structure factors over electrolyte charges (metal q := 0) --------
__global__ void k_srsi(const float* __restrict__ q, const int* __restrict__ an,
                       float* __restrict__ wsf) {
    int k = blockIdx.x;
    int tid = threadIdx.x;
    float4 kt = *(const float4*)(wsf + OFF_KTAB/4 + 4*k);
    const float* frac = wsf + OFF_FRAC/4;
    float aR=0.f, aI=0.f;
    for (int i=tid; i<NA; i+=256) {
        float qa = (an[i]==METAL_Z) ? 0.f : q[i];
        float4 f = *(const float4*)(frac + 4*i);
        float u = kt.x*f.x + kt.y*f.y + kt.z*f.z;
        float s,c; sc_frac(u, s, c);
        aR += qa*c; aI += qa*s;
    }
    __shared__ float sR[256], sI[256];
    sR[tid]=aR; sI[tid]=aI; __syncthreads();
    for (int off=128; off>0; off>>=1) {
        if (tid<off) { sR[tid]+=sR[tid+off]; sI[tid]+=sI[tid+off]; }
        __syncthreads();
    }
    if (tid==0) {
        wsf[OFF_SRW/4 + k] = kt.w * sR[0];
        wsf[OFF_SIW/4 + k] = kt.w * sI[0];
    }
}

// -------- field at metal atoms (partial over k-chunks) --------
__global__ void k_field(float* __restrict__ wsf) {
    int kc = blockIdx.x;
    int m = blockIdx.y*256 + threadIdx.x;
    int atom = ((const int*)wsf)[OFF_MLIST/4 + m];
    float4 f = *(const float4*)(wsf + OFF_FRAC/4 + 4*atom);
    const float* kt = wsf + OFF_KTAB/4;
    const float* SrW = wsf + OFF_SRW/4;
    const float* SiW = wsf + OFF_SIW/4;
    float acc = 0.f;
    int k0 = kc*128;
    for (int j=0;j<128;j++) {
        int k = k0 + j;
        float4 g = *(const float4*)(kt + 4*k);
        float u = g.x*f.x + g.y*f.y + g.z*f.z;
        float s,c; sc_frac(u, s, c);
        acc = fmaf(c, SrW[k], fmaf(s, SiW[k], acc));
    }
    wsf[OFF_BPART/4 + kc*NM + m] = acc;
}

// -------- r0 = P*B = B - mean(B); B = -field (1 block x 1024) --------
__global__ void k_bfinal(float* __restrict__ wsf) {
    int tid = threadIdx.x;
    float b0 = 0.f, b1 = 0.f;
    for (int kc=0;kc<62;kc++) {
        b0 += wsf[OFF_BPART/4 + kc*NM + tid];
        b1 += wsf[OFF_BPART/4 + kc*NM + 1024 + tid];
    }
    b0 = -b0; b1 = -b1;
    __shared__ float sb[1024];
    sb[tid] = b0 + b1; __syncthreads();
    for (int off=512; off>0; off>>=1) {
        if (tid<off) sb[tid] += sb[tid+off];
        __syncthreads();
    }
    float mean = sb[0] * (1.f/NM);
    float* r = wsf + OFF_VEC/4 + 4096;
    r[tid]        = b0 - mean;
    r[1024 + tid] = b1 - mean;
}

// -------- A build (G path): 128x128 triangular Gram GEMM from precomputed G --------
__launch_bounds__(256)
__global__ void k_abuild_g(float* __restrict__ wsf, const unsigned* __restrict__ ghi,
                           const unsigned* __restrict__ glo) {
    __shared__ unsigned Sh[16384];     // 64 KB
    int tid = threadIdx.x;
    int bid = blockIdx.x;
    int bi = (int)((sqrtf(8.f*bid + 1.f) - 1.f)*0.5f);
    while ((bi+1)*(bi+2)/2 <= bid) bi++;
    while (bi*(bi+1)/2 > bid) bi--;
    int bj = bid - bi*(bi+1)/2;
    bool diag = (bi == bj);
    float J = wsf[OFF_CONSTS/4 + 10];

    int w = tid >> 6, lane = tid & 63;
    int mat   = diag ? (w & 1) : w;
    int tb    = (diag ? bi : (w < 2 ? bi : bj)) * 128;
    int rbase = diag ? ((w >> 1) * 64) : 0;
    int nld   = diag ? 8 : 16;
    const unsigned* gsrc = (mat & 1) ? glo : ghi;
    int lrow8 = lane >> 3;
    int gcsw  = (lane & 7) ^ (lrow8 & 7);     // swizzled source chunk
    unsigned* lb = &Sh[mat*4096 + rbase*32];
    const unsigned* gb0 = gsrc + (size_t)(tb + rbase)*KHP + gcsw*4;

    int wr = w & 1, wc = w >> 1;
    int lr = lane & 15, g4 = lane >> 4;
    const unsigned short* UHs = (const unsigned short*)&Sh[0];
    const unsigned short* ULs = (const unsigned short*)&Sh[4096];
    const unsigned short* VHs = diag ? UHs : (const unsigned short*)&Sh[8192];
    const unsigned short* VLs = diag ? ULs : (const unsigned short*)&Sh[12288];

    f32x4 acc[4][4];
    #pragma unroll
    for (int i=0;i<4;i++)
        #pragma unroll
        for (int j=0;j<4;j++) acc[i][j] = (f32x4){0.f,0.f,0.f,0.f};

    for (int kc = 0; kc < KHP/32; ++kc) {
        __syncthreads();
        const unsigned* gb = gb0 + kc*32;
        #pragma unroll
        for (int i = 0; i < 16; ++i) {
            if (i < nld) {
                uint4 v = *(const uint4*)(gb + (size_t)(i*8 + lrow8)*KHP);
                *(uint4*)&lb[i*256 + lane*4] = v;
            }
        }
        __syncthreads();
        #pragma unroll
        for (int ks = 0; ks < 2; ++ks) {
            int cA = ks*4 + g4;
            bf16x8 ah[4], al[4], bh[4], bl[4];
            #pragma unroll
            for (int fi=0; fi<4; fi++) {
                int r = wr*64 + fi*16 + lr;
                int o = r*64 + ((cA ^ (r&7)) << 3);
                ah[fi] = *(const bf16x8*)&UHs[o];
                al[fi] = *(const bf16x8*)&ULs[o];
            }
            #pragma unroll
            for (int fj=0; fj<4; fj++) {
                int r = wc*64 + fj*16 + lr;
                int o = r*64 + ((cA ^ (r&7)) << 3);
                bh[fj] = *(const bf16x8*)&VHs[o];
                bl[fj] = *(const bf16x8*)&VLs[o];
            }
            #pragma unroll
            for (int fi=0; fi<4; fi++)
                #pragma unroll
                for (int fj=0; fj<4; fj++) {
                    acc[fi][fj] = __builtin_amdgcn_mfma_f32_16x16x32_bf16(ah[fi], bh[fj], acc[fi][fj], 0,0,0);
                    acc[fi][fj] = __builtin_amdgcn_mfma_f32_16x16x32_bf16(ah[fi], bl[fj], acc[fi][fj], 0,0,0);
                    acc[fi][fj] = __builtin_amdgcn_mfma_f32_16x16x32_bf16(al[fi], bh[fj], acc[fi][fj], 0,0,0);
                }
        }
    }

    float* A = wsf + OFF_A/4;
    int rb4 = g4 * 4;
    #pragma unroll
    for (int fi=0; fi<4; fi++) {
        #pragma unroll
        for (int fj=0; fj<4; fj++) {
            int gj = bj*128 + wc*64 + fj*16 + lr;
            #pragma unroll
            for (int r=0; r<4; r++) {
                int gi = bi*128 + wr*64 + fi*16 + rb4 + r;
                float v = acc[fi][fj][r] + ((gi==gj)?J:0.f);
                A[(size_t)gi*NM + gj] = v;
                A[(size_t)gj*NM + gi] = v;
            }
        }
    }
}

// -------- persistent projected CG: 64x1024, data-carried (w,tag) sync --------
__launch_bounds__(CGT, 1)
__global__ void k_cg(float* __restrict__ wsf) {
    const float* A = wsf + OFF_A/4;
    float* vec = wsf + OFF_VEC/4;
    float* xg = vec;
    const float* rg = vec + 4096;
    unsigned long long* wbufg = (unsigned long long*)((char*)wsf + OFF_WBUF);
    unsigned long long* pbufg = (unsigned long long*)((char*)wsf + OFF_PBUF);

    __shared__ float rs[NM];
    __shared__ float wrow[32];
    __shared__ float red[4];

    int tid = threadIdx.x, bid = blockIdx.x;
    int rl = tid >> 5, lane = tid & 31;
    int row = bid*32 + rl;
    const float* Arow = A + (size_t)row*NM;
    int ca = 2*tid;

    ((float2*)rs)[tid] = ((const float2*)rg)[tid];
    __syncthreads();

    float s0=0.f, s1=0.f;
    float pr=0.f, xr=0.f;
    float gp=1.f, ap=1.f;

    for (int iter=0; iter<NIT; ++iter) {
        int t = iter + 1;
        unsigned long long* wb = wbufg + (iter&1)*2048;
        unsigned long long* pb = pbufg + (iter&1)*192;
        // ---- w_own = A_own * r, 32 lanes per row ----
        float acc=0.f;
        #pragma unroll 8
        for (int c=lane*4; c<NM; c+=128) {
            float4 a = *(const float4*)(Arow + c);
            float4 u = *(const float4*)(rs + c);
            acc += a.x*u.x + a.y*u.y + a.z*u.z + a.w*u.w;
        }
        #pragma unroll
        for (int off=1; off<32; off<<=1) acc += __shfl_xor(acc, off);
        if (lane == 0) {
            wrow[rl] = acc;
            __hip_atomic_store(&wb[row], pack_wt(acc, t),
                               __ATOMIC_RELAXED, __HIP_MEMORY_SCOPE_AGENT);
        }
        float rrow = (tid<32) ? rs[bid*32+tid] : 0.f;
        __syncthreads();   // (A) wrow visible for partials
        // ---- tagged block partials ----
        if (tid == 0) {
            float gb=0.f, db=0.f, mb=0.f;
            #pragma unroll
            for (int j=0;j<32;j++) {
                float rv = rs[bid*32+j];
                gb = fmaf(rv,rv,gb); db = fmaf(rv,wrow[j],db); mb += wrow[j];
            }
            __hip_atomic_store(&pb[bid],       pack_wt(gb, t), __ATOMIC_RELAXED, __HIP_MEMORY_SCOPE_AGENT);
            __hip_atomic_store(&pb[64+bid],    pack_wt(db, t), __ATOMIC_RELAXED, __HIP_MEMORY_SCOPE_AGENT);
            __hip_atomic_store(&pb[128+bid],   pack_wt(mb, t), __ATOMIC_RELAXED, __HIP_MEMORY_SCOPE_AGENT);
        }
        // ---- data-carried poll: each thread waits for ITS entries ----
        float w0, w1;
        if (tid < 64) {
            unsigned long long e0,e1,eg,ed,em;
            for (;;) {
                e0 = __hip_atomic_load(&wb[ca],     __ATOMIC_RELAXED, __HIP_MEMORY_SCOPE_AGENT);
                e1 = __hip_atomic_load(&wb[ca+1],   __ATOMIC_RELAXED, __HIP_MEMORY_SCOPE_AGENT);
                eg = __hip_atomic_load(&pb[tid],    __ATOMIC_RELAXED, __HIP_MEMORY_SCOPE_AGENT);
                ed = __hip_atomic_load(&pb[64+tid], __ATOMIC_RELAXED, __HIP_MEMORY_SCOPE_AGENT);
                em = __hip_atomic_load(&pb[128+tid],__ATOMIC_RELAXED, __HIP_MEMORY_SCOPE_AGENT);
                int ok = ((int)(e0>>32)==t) & ((int)(e1>>32)==t)
                       & ((int)(eg>>32)==t) & ((int)(ed>>32)==t) & ((int)(em>>32)==t);
                if (__all(ok)) break;
                __builtin_amdgcn_s_sleep(1);
            }
            w0 = lo_f(e0); w1 = lo_f(e1);
            float g = lo_f(eg), d = lo_f(ed), m = lo_f(em);
            #pragma unroll
            for (int off=1; off<64; off<<=1) {
                g += __shfl_xor(g,off); d += __shfl_xor(d,off); m += __shfl_xor(m,off);
            }
            if (tid==0) { red[0]=g; red[1]=d; red[2]=m; }
        } else {
            unsigned long long e0,e1;
            for (;;) {
                e0 = __hip_atomic_load(&wb[ca],   __ATOMIC_RELAXED, __HIP_MEMORY_SCOPE_AGENT);
                e1 = __hip_atomic_load(&wb[ca+1], __ATOMIC_RELAXED, __HIP_MEMORY_SCOPE_AGENT);
                int ok = ((int)(e0>>32)==t) & ((int)(e1>>32)==t);
                if (__all(ok)) break;
                __builtin_amdgcn_s_sleep(1);
            }
            w0 = lo_f(e0); w1 = lo_f(e1);
        }
        __syncthreads();   // (C) scalars ready
        float g = red[0], d = red[1];
        float m = red[2] * (1.f/NM);
        float b, a;
        if (iter == 0) { b=0.f; a=g/d; }
        else { b = g/gp; a = g/(d - b*g/ap); }
        gp=g; ap=a;
        if (tid < 32) {
            pr = (iter==0) ? rrow : fmaf(b, pr, rrow);
            xr = (iter==0) ? a*pr : fmaf(a, pr, xr);
        }
        float wt0 = w0 - m, wt1 = w1 - m;
        s0 = (iter==0) ? wt0 : fmaf(b, s0, wt0);
        s1 = (iter==0) ? wt1 : fmaf(b, s1, wt1);
        float2 rv2 = *(const float2*)(rs + ca);
        *(float2*)(rs + ca) = make_float2(fmaf(-a, s0, rv2.x), fmaf(-a, s1, rv2.y));
        __syncthreads();   // (D) rs consistent for next matvec
    }
    if (tid < 32) xg[bid*32+tid] = xr;
}

// -------- assemble output: metal -> x, electrolyte -> q --------
__global__ void k_out(const float* __restrict__ q, const int* __restrict__ an,
                      const float* __restrict__ wsf, float* __restrict__ out) {
    int i = blockIdx.x*256 + threadIdx.x;
    if (i >= NA) return;
    if (an[i]==METAL_Z) {
        int p = ((const int*)wsf)[OFF_POSOF/4 + i];
        out[i] = wsf[OFF_VEC/4 + p];
    } else {
        out[i] = q[i];
    }
}

extern "C" void kernel_launch(void* const* d_in, const int* in_sizes, int n_in,
                              void* d_out, int out_size, void* d_ws, size_t ws_size,
                              hipStream_t stream) {
    (void)in_sizes; (void)n_in; (void)out_size;
    const float* pos  = (const float*)d_in[0];
    const float* cell = (const float*)d_in[1];
    const float* q    = (const float*)d_in[2];
    const float* Jraw = (const float*)d_in[3];
    const int*   an   = (const int*)d_in[4];
    float* wsf = (float*)d_ws;
    float* out = (float*)d_out;
    unsigned* ghi = (unsigned*)((char*)d_ws + OFF_GHI);
    unsigned* glo = (unsigned*)((char*)d_ws + OFF_GLO);

    k_setup<<<1, 256, 0, stream>>>(pos, cell, Jraw, an, wsf);
    k_ktab<<<KHP/256, 256, 0, stream>>>(wsf);
    k_gbuild<<<dim3(31, 2048), 256, 0, stream>>>(wsf, ghi, glo);
    k_srsi<<<KHP, 256, 0, stream>>>(q, an, wsf);
    k_field<<<dim3(62, 8), 256, 0, stream>>>(wsf);
    k_bfinal<<<1, 1024, 0, stream>>>(wsf);
    k_abuild_g<<<136, 256, 0, stream>>>(wsf, ghi, glo);
    k_cg<<<NBLK_CG, CGT, 0, stream>>>(wsf);
    k_out<<<NA/256, 256, 0, stream>>>(q, an, wsf, out);
}